// Round 4
// baseline (1547.235 us; speedup 1.0000x reference)
//
#include <hip/hip_runtime.h>
#include <stdint.h>

#define NREAL   20000
#define NNODES  20001
#define VN      20000
#define E_EDGES 320000
#define NEXP    80004

typedef unsigned short u16;
typedef unsigned int   u32;
typedef __bf16 bf16x8 __attribute__((ext_vector_type(8)));
typedef float  f32x4  __attribute__((ext_vector_type(4)));

__device__ __forceinline__ float bf2f(u16 v) {
    union { u32 u; float f; } x; x.u = ((u32)v) << 16; return x.f;
}
__device__ __forceinline__ u16 f2bf(float f) {
    union { float f; u32 u; } x; x.f = f;
    u32 r = (x.u + 0x7fffu + ((x.u >> 16) & 1u)) >> 16;
    return (u16)r;
}
__device__ __forceinline__ float4 ld4bf(const u16* p) {
    ushort4 u = *(const ushort4*)p;
    return make_float4(bf2f(u.x), bf2f(u.y), bf2f(u.z), bf2f(u.w));
}
__device__ __forceinline__ u32 enc_f(float f) {
    u32 u = __float_as_uint(f);
    return (u & 0x80000000u) ? ~u : (u | 0x80000000u);
}
__device__ __forceinline__ float dec_f(u32 u) {
    u32 v = (u & 0x80000000u) ? (u & 0x7fffffffu) : ~u;
    return __uint_as_float(v);
}

// ---------------- setup kernels ----------------

__global__ void hinit_kernel(const float* __restrict__ x, float* __restrict__ h,
                             u16* __restrict__ hb) {
    size_t i = (size_t)blockIdx.x * 256 + threadIdx.x;
    if (i >= (size_t)NNODES * 256) return;
    float v = (i < (size_t)NREAL * 256) ? x[i] : 0.0f;
    h[i] = v;
    hb[i] = f2bf(v);
}

__global__ void zero_csr_kernel(int* cnt, int* fill, int* ecnt) {
    int i = blockIdx.x * 256 + threadIdx.x;
    if (i < NREAL) { cnt[i] = 0; fill[i] = 0; }
    if (i < NNODES) ecnt[i] = 0;
}

__global__ void csr_count_kernel(const int* __restrict__ ei, int* __restrict__ cnt) {
    int e = blockIdx.x * 256 + threadIdx.x;
    if (e < E_EDGES) atomicAdd(&cnt[ei[E_EDGES + e]], 1);
}

__global__ void csr_scan_kernel(const int* __restrict__ cnt, int* __restrict__ indptr) {
    __shared__ int ssum[256];
    int t = threadIdx.x;
    int c0 = t * 79;
    int s = 0;
    for (int j = 0; j < 79; j++) {
        int i = c0 + j;
        if (i < NREAL) s += cnt[i];
    }
    ssum[t] = s;
    __syncthreads();
    for (int d2 = 1; d2 < 256; d2 <<= 1) {
        int v = (t >= d2) ? ssum[t - d2] : 0;
        __syncthreads();
        ssum[t] += v;
        __syncthreads();
    }
    int run = (t == 0) ? 0 : ssum[t - 1];
    for (int j = 0; j < 79; j++) {
        int i = c0 + j;
        if (i < NREAL) { indptr[i] = run; run += cnt[i]; }
    }
    if (t == 255) indptr[NREAL] = run;
}

__global__ void csr_scatter_kernel(const int* __restrict__ ei, const int* __restrict__ indptr,
                                   int* __restrict__ fill, int* __restrict__ srcs) {
    int e = blockIdx.x * 256 + threadIdx.x;
    if (e < E_EDGES) {
        int d = ei[E_EDGES + e];
        int pos = indptr[d] + atomicAdd(&fill[d], 1);
        srcs[pos] = ei[e];
    }
}

__global__ void exp_scatter_kernel(const int* __restrict__ eei, int* __restrict__ ecnt,
                                   int* __restrict__ esrcs) {
    int e = blockIdx.x * 256 + threadIdx.x;
    if (e < NEXP) {
        int d = eei[NEXP + e];
        int pos = atomicAdd(&ecnt[d], 1);
        esrcs[d * 4 + pos] = eei[e];
    }
}

// transpose + bf16-convert a (L=3, K, N) weight into per-layer N x K slabs
__global__ void wconv3_kernel(const float* __restrict__ W, u16* __restrict__ out,
                              int K, int N, int lstride_out) {
    int i = blockIdx.x * 256 + threadIdx.x;
    int per = K * N;
    if (i >= 3 * per) return;
    int l = i / per, r = i - l * per;
    int k = r / N, n = r - k * N;
    out[(size_t)l * lstride_out + (size_t)n * K + k] = f2bf(W[i]);
}

// concat qkv biases: bcat[l][0:768] = bqkv_loc[l], bcat[l][768:1536] = bqkv_exp[l]
__global__ void bcat_kernel(const float* __restrict__ bl, const float* __restrict__ be,
                            float* __restrict__ bcat) {
    int i = blockIdx.x * 256 + threadIdx.x;
    if (i >= 3 * 1536) return;
    int l = i / 1536, c = i - l * 1536;
    bcat[i] = (c < 768) ? bl[l * 768 + c] : be[l * 768 + c - 768];
}

// ---------------- GEMM: LDS-free, depth-3 register pipeline, XCD-pinned swizzle ----
// A: M x K bf16 row-major; Bt: Nout x K bf16 row-major (pre-transposed weight).
// Tile: 64 x 128, 4 waves; wave quadrant 32 x 64 (2 m-frags x 4 n-frags).
// 1-D grid: lin -> xcd = lin&7, sub = lin>>3; mtile = xcd + 8*(sub/nby), ntile = sub%nby.
// All N-tiles of one m-tile share lin%8 -> same XCD -> A-rows fetched into one L2 once.
// EPI: 0 bias->bf16; 1 bias->f32; 2 bias->gelu->bf16; 3 bias+resid->f32+bf16;
//      4 bias+resid->f32 (rows<NREAL only)

template <int EPI, int K>
__global__ __launch_bounds__(256, 3) void gemm_direct(
    const u16* __restrict__ A, const u16* __restrict__ Bt, const float* __restrict__ bias,
    u16* Cb, float* Cf, const float* resid, int M, int Nout, int nby) {
    constexpr int NK = K / 32;
    const int lin = blockIdx.x;
    const int xcd = lin & 7, sub = lin >> 3;
    const int mtile = xcd + 8 * (sub / nby);
    const int ntile = sub - (sub / nby) * nby;
    const int tm = mtile * 64, tn = ntile * 128;
    if (tm >= M) return;

    const int tid = threadIdx.x;
    const int w = tid >> 6, lane = tid & 63;
    const int lm = lane & 15, q = lane >> 4;
    const int mo = (w >> 1) * 32, no = (w & 1) * 64;

    f32x4 acc[2][4];
#pragma unroll
    for (int a = 0; a < 2; a++)
#pragma unroll
        for (int b = 0; b < 4; b++) acc[a][b] = (f32x4)0.0f;

    const u16* ap[2];
    const u16* bp[4];
#pragma unroll
    for (int t = 0; t < 2; t++) {
        int ar = tm + mo + t * 16 + lm;
        if (ar > M - 1) ar = M - 1;
        ap[t] = A + (size_t)ar * K + q * 8;
    }
#pragma unroll
    for (int n = 0; n < 4; n++) {
        int bc = tn + no + n * 16 + lm;   // Nout is a multiple of 128
        bp[n] = Bt + (size_t)bc * K + q * 8;
    }

    // depth-3 modulo-3 register pipeline: stages i+1, i+2 in flight during compute(i)
    bf16x8 sA[3][2], sB[3][4];
#pragma unroll
    for (int s = 0; s < 2; s++) {
#pragma unroll
        for (int t = 0; t < 2; t++) sA[s][t] = *(const bf16x8*)(ap[t] + s * 32);
#pragma unroll
        for (int n = 0; n < 4; n++) sB[s][n] = *(const bf16x8*)(bp[n] + s * 32);
    }
#pragma unroll
    for (int i = 0; i < NK; i++) {
        const int ld = (i + 2) % 3, cu = i % 3;
        if (i + 2 < NK) {
#pragma unroll
            for (int t = 0; t < 2; t++) sA[ld][t] = *(const bf16x8*)(ap[t] + (i + 2) * 32);
#pragma unroll
            for (int n = 0; n < 4; n++) sB[ld][n] = *(const bf16x8*)(bp[n] + (i + 2) * 32);
        }
#pragma unroll
        for (int mi = 0; mi < 2; mi++)
#pragma unroll
            for (int ni = 0; ni < 4; ni++)
                acc[mi][ni] = __builtin_amdgcn_mfma_f32_16x16x32_bf16(
                    sA[cu][mi], sB[cu][ni], acc[mi][ni], 0, 0, 0);
    }

#pragma unroll
    for (int mi = 0; mi < 2; mi++) {
#pragma unroll
        for (int r = 0; r < 4; r++) {
            int grow = tm + mo + mi * 16 + q * 4 + r;
            if (grow >= M) continue;
#pragma unroll
            for (int ni = 0; ni < 4; ni++) {
                int gcol = tn + no + ni * 16 + lm;
                float v = acc[mi][ni][r] + bias[gcol];
                size_t idx = (size_t)grow * Nout + gcol;
                if constexpr (EPI == 0) {
                    Cb[idx] = f2bf(v);
                } else if constexpr (EPI == 1) {
                    Cf[idx] = v;
                } else if constexpr (EPI == 2) {
                    float g = 0.5f * v * (1.0f + erff(v * 0.70710678118654752f));
                    Cb[idx] = f2bf(g);
                } else if constexpr (EPI == 3) {
                    float o = resid[idx] + v;
                    Cf[idx] = o;
                    Cb[idx] = f2bf(o);
                } else {
                    if (grow < NREAL) {
                        float o = resid[idx] + v;
                        Cf[idx] = o;
                    }
                }
            }
        }
    }
}

// ---------------- attention ----------------
// One wave per destination node. 4 head-groups of 16 lanes; each lane owns 4 dims.
// qkv rows have stride LD elems; q at +0, k at +256, v at +512 within the row block.
__global__ void attn_node_kernel(const u16* __restrict__ qkv, int LD,
                                 const int* __restrict__ indptr,
                                 const int* __restrict__ srcs, int fixed_deg, int add_vn,
                                 int n_nodes, u16* __restrict__ out) {
    int gw = (int)((blockIdx.x * (size_t)blockDim.x + threadIdx.x) >> 6);
    if (gw >= n_nodes) return;
    int lane = threadIdx.x & 63;
    int h = lane >> 4, t = lane & 15;
    int off = h * 64 + t * 4;
    float4 qv = ld4bf(qkv + (size_t)gw * LD + off);
    int beg, deg;
    if (fixed_deg) { beg = gw * fixed_deg; deg = fixed_deg; }
    else           { beg = indptr[gw]; deg = indptr[gw + 1] - beg; }
    int tot = deg + add_vn;
    float m = -1e30f, l = 0.0f;
    float ax = 0, ay = 0, az = 0, aw = 0;
    int e = 0;
    for (; e + 2 <= tot; e += 2) {
        int s0 = (e < deg) ? srcs[beg + e] : VN;
        int s1 = (e + 1 < deg) ? srcs[beg + e + 1] : VN;
        const u16* p0 = qkv + (size_t)s0 * LD + off;
        const u16* p1 = qkv + (size_t)s1 * LD + off;
        float4 k0 = ld4bf(p0 + 256);
        float4 k1 = ld4bf(p1 + 256);
        float4 v0 = ld4bf(p0 + 512);
        float4 v1 = ld4bf(p1 + 512);
        float pa = qv.x * k0.x + qv.y * k0.y + qv.z * k0.z + qv.w * k0.w;
        float pb = qv.x * k1.x + qv.y * k1.y + qv.z * k1.z + qv.w * k1.w;
        pa += __shfl_xor(pa, 1); pb += __shfl_xor(pb, 1);
        pa += __shfl_xor(pa, 2); pb += __shfl_xor(pb, 2);
        pa += __shfl_xor(pa, 4); pb += __shfl_xor(pb, 4);
        pa += __shfl_xor(pa, 8); pb += __shfl_xor(pb, 8);
        float sa = pa * 0.125f, sb = pb * 0.125f;
        float mn = fmaxf(m, fmaxf(sa, sb));
        float fold = __expf(m - mn);
        float e0 = __expf(sa - mn);
        float e1 = __expf(sb - mn);
        ax = ax * fold + v0.x * e0 + v1.x * e1;
        ay = ay * fold + v0.y * e0 + v1.y * e1;
        az = az * fold + v0.z * e0 + v1.z * e1;
        aw = aw * fold + v0.w * e0 + v1.w * e1;
        l = l * fold + e0 + e1;
        m = mn;
    }
    if (e < tot) {
        int s = (e < deg) ? srcs[beg + e] : VN;
        const u16* p = qkv + (size_t)s * LD + off;
        float4 kv = ld4bf(p + 256);
        float4 vv = ld4bf(p + 512);
        float p0 = qv.x * kv.x + qv.y * kv.y + qv.z * kv.z + qv.w * kv.w;
        p0 += __shfl_xor(p0, 1); p0 += __shfl_xor(p0, 2);
        p0 += __shfl_xor(p0, 4); p0 += __shfl_xor(p0, 8);
        float sc = p0 * 0.125f;
        float mn = fmaxf(m, sc);
        float fold = __expf(m - mn);
        float ee = __expf(sc - mn);
        ax = ax * fold + vv.x * ee;
        ay = ay * fold + vv.y * ee;
        az = az * fold + vv.z * ee;
        aw = aw * fold + vv.w * ee;
        l = l * fold + ee;
        m = mn;
    }
    float inv = 1.0f / (l + 1e-16f);
    ushort4 o;
    o.x = f2bf(ax * inv); o.y = f2bf(ay * inv);
    o.z = f2bf(az * inv); o.w = f2bf(aw * inv);
    *(ushort4*)(out + (size_t)gw * 256 + off) = o;
}

// virtual node (dst = VN, sources = all 20000 real nodes), dense 3-phase
__global__ void vn_zero_kernel(float* vnum, float* vden, u32* menc) {
    int t = threadIdx.x;
    vnum[t] = 0.0f;
    if (t < 4) { vden[t] = 0.0f; menc[t] = enc_f(-1e30f); }
}

__global__ void vn_score_kernel(const u16* __restrict__ qkv, int LD, float* __restrict__ svn,
                                u32* __restrict__ menc) {
    int lane = threadIdx.x & 63;
    int h = lane >> 4, t = lane & 15;
    int off = h * 64 + t * 4;
    float4 qv = ld4bf(qkv + (size_t)VN * LD + off);
    int wid = (int)((blockIdx.x * (size_t)blockDim.x + threadIdx.x) >> 6);
    int nw = (gridDim.x * blockDim.x) >> 6;
    float wmax = -1e30f;
    for (int i = wid; i < NREAL; i += nw) {
        float4 kv = ld4bf(qkv + (size_t)i * LD + 256 + off);
        float p = qv.x * kv.x + qv.y * kv.y + qv.z * kv.z + qv.w * kv.w;
        p += __shfl_xor(p, 1); p += __shfl_xor(p, 2);
        p += __shfl_xor(p, 4); p += __shfl_xor(p, 8);
        float sc = p * 0.125f;
        if (t == 0) svn[i * 4 + h] = sc;
        wmax = fmaxf(wmax, sc);
    }
    if (t == 0) atomicMax(&menc[h], enc_f(wmax));
}

__global__ void vn_accum_kernel(const u16* __restrict__ qkv, int LD,
                                const float* __restrict__ svn,
                                const u32* __restrict__ menc, float* __restrict__ vnum,
                                float* __restrict__ vden) {
    int lane = threadIdx.x & 63;
    int h = lane >> 4, t = lane & 15;
    int off = h * 64 + t * 4;
    float m = dec_f(menc[h]);
    int wid = (int)((blockIdx.x * (size_t)blockDim.x + threadIdx.x) >> 6);
    int nw = (gridDim.x * blockDim.x) >> 6;
    float ax = 0, ay = 0, az = 0, aw = 0, l = 0;
    for (int i = wid; i < NREAL; i += nw) {
        float e = __expf(svn[i * 4 + h] - m);
        float4 vv = ld4bf(qkv + (size_t)i * LD + 512 + off);
        ax += e * vv.x; ay += e * vv.y; az += e * vv.z; aw += e * vv.w;
        l += e;
    }
    atomicAdd(&vnum[off + 0], ax);
    atomicAdd(&vnum[off + 1], ay);
    atomicAdd(&vnum[off + 2], az);
    atomicAdd(&vnum[off + 3], aw);
    if (t == 0) atomicAdd(&vden[h], l);
}

__global__ void vn_final_kernel(const float* __restrict__ vnum, const float* __restrict__ vden,
                                u16* __restrict__ araw) {
    int lane = threadIdx.x;
    int h = lane >> 4;
    float inv = 1.0f / (vden[h] + 1e-16f);
    ushort4 o;
    o.x = f2bf(vnum[lane * 4 + 0] * inv);
    o.y = f2bf(vnum[lane * 4 + 1] * inv);
    o.z = f2bf(vnum[lane * 4 + 2] * inv);
    o.w = f2bf(vnum[lane * 4 + 3] * inv);
    *(ushort4*)(araw + (size_t)VN * 256 + lane * 4) = o;
}

// ---------------- layernorm (fused residual + loc + exp) ----------------
__global__ void ln_kernel(const float* hin, const float* __restrict__ aloc,
                          const float* __restrict__ aexp, const float* __restrict__ g,
                          const float* __restrict__ b, float* hout, u16* __restrict__ hb) {
    int row = blockIdx.x * 4 + (threadIdx.x >> 6);
    if (row >= NNODES) return;
    int lane = threadIdx.x & 63;
    size_t base = (size_t)row * 256 + lane * 4;
    float4 xv = *(const float4*)(hin + base);
    float4 av = *(const float4*)(aloc + base);
    float4 ev = *(const float4*)(aexp + base);
    xv.x += av.x + ev.x; xv.y += av.y + ev.y;
    xv.z += av.z + ev.z; xv.w += av.w + ev.w;
    float s = xv.x + xv.y + xv.z + xv.w;
#pragma unroll
    for (int o = 1; o < 64; o <<= 1) s += __shfl_xor(s, o);
    float mu = s * (1.0f / 256.0f);
    float dx = xv.x - mu, dy = xv.y - mu, dz = xv.z - mu, dw = xv.w - mu;
    float ss = dx * dx + dy * dy + dz * dz + dw * dw;
#pragma unroll
    for (int o = 1; o < 64; o <<= 1) ss += __shfl_xor(ss, o);
    float var = ss * (1.0f / 256.0f);
    float inv = 1.0f / sqrtf(var + 1e-5f);
    float4 gv = *(const float4*)(g + lane * 4);
    float4 bv = *(const float4*)(b + lane * 4);
    float4 y;
    y.x = dx * inv * gv.x + bv.x;
    y.y = dy * inv * gv.y + bv.y;
    y.z = dz * inv * gv.z + bv.z;
    y.w = dw * inv * gv.w + bv.w;
    *(float4*)(hout + base) = y;
    ushort4 o4;
    o4.x = f2bf(y.x); o4.y = f2bf(y.y); o4.z = f2bf(y.z); o4.w = f2bf(y.w);
    *(ushort4*)(hb + base) = o4;
}

// ---------------- host ----------------

extern "C" void kernel_launch(void* const* d_in, const int* in_sizes, int n_in,
                              void* d_out, int out_size, void* d_ws, size_t ws_size,
                              hipStream_t stream) {
    (void)in_sizes; (void)n_in; (void)out_size; (void)ws_size;
    const float* x        = (const float*)d_in[0];
    const int*   ei       = (const int*)d_in[1];
    const int*   eei      = (const int*)d_in[2];
    const float* Wqkv_loc = (const float*)d_in[3];
    const float* bqkv_loc = (const float*)d_in[4];
    const float* Wo_loc   = (const float*)d_in[5];
    const float* bo_loc   = (const float*)d_in[6];
    const float* Wqkv_exp = (const float*)d_in[7];
    const float* bqkv_exp = (const float*)d_in[8];
    const float* Wo_exp   = (const float*)d_in[9];
    const float* bo_exp   = (const float*)d_in[10];
    const float* ln_g     = (const float*)d_in[11];
    const float* ln_b     = (const float*)d_in[12];
    const float* W1       = (const float*)d_in[13];
    const float* b1       = (const float*)d_in[14];
    const float* W2       = (const float*)d_in[15];
    const float* b2       = (const float*)d_in[16];

    char* wsp = (char*)d_ws;
    size_t off = 0;
    auto carve = [&](size_t bytes) -> void* {
        void* p = wsp + off;
        off += (bytes + 255) & ~(size_t)255;
        return p;
    };
    float* h_f   = (float*)carve((size_t)NNODES * 256 * 4);
    u16*   h_b   = (u16*)carve((size_t)NNODES * 256 * 2);
    u16*   qkv   = (u16*)carve((size_t)NNODES * 1536 * 2);  // loc qkv | exp qkv per row
    u16*   araw  = (u16*)carve((size_t)NNODES * 256 * 2);
    float* aloc  = (float*)carve((size_t)NNODES * 256 * 4);
    float* aexp  = (float*)carve((size_t)NNODES * 256 * 4);  // aloc+aexp alias FFN mid (41MB)
    u16*   wbf   = (u16*)carve((size_t)3 * 1048576 * 2);
    float* bcat  = (float*)carve((size_t)3 * 1536 * 4);
    int*   cnt   = (int*)carve((size_t)NREAL * 4);
    int*   indptr= (int*)carve((size_t)(NREAL + 1) * 4);
    int*   fill  = (int*)carve((size_t)NREAL * 4);
    int*   srcs  = (int*)carve((size_t)E_EDGES * 4);
    int*   ecnt  = (int*)carve((size_t)NNODES * 4);
    int*   esrcs = (int*)carve((size_t)NNODES * 4 * 4);
    float* svn   = (float*)carve((size_t)NREAL * 4 * 4);
    u32*   menc  = (u32*)carve(4 * 4);
    float* vden  = (float*)carve(4 * 4);
    float* vnum  = (float*)carve(256 * 4);
    u16*   mid   = (u16*)aloc;  // 20001x1024 bf16 = exactly aloc+aexp

    hinit_kernel<<<(NNODES * 256 + 255) / 256, 256, 0, stream>>>(x, h_f, h_b);
    zero_csr_kernel<<<(NNODES + 255) / 256, 256, 0, stream>>>(cnt, fill, ecnt);
    csr_count_kernel<<<(E_EDGES + 255) / 256, 256, 0, stream>>>(ei, cnt);
    csr_scan_kernel<<<1, 256, 0, stream>>>(cnt, indptr);
    csr_scatter_kernel<<<(E_EDGES + 255) / 256, 256, 0, stream>>>(ei, indptr, fill, srcs);
    exp_scatter_kernel<<<(NEXP + 255) / 256, 256, 0, stream>>>(eei, ecnt, esrcs);

    // weight transpose+bf16 into per-layer slabs (u16 offsets within 1048576/layer):
    // [0] qkvcat^T (1536x256: rows 0-767 loc, 768-1535 exp)  [393216] WoL^T  [458752] WoE^T
    // [524288] W1^T (1024x256)  [786432] W2^T (256x1024)
    wconv3_kernel<<<(3 * 196608 + 255) / 256, 256, 0, stream>>>(Wqkv_loc, wbf + 0,      256, 768, 1048576);
    wconv3_kernel<<<(3 * 196608 + 255) / 256, 256, 0, stream>>>(Wqkv_exp, wbf + 196608, 256, 768, 1048576);
    wconv3_kernel<<<(3 * 65536  + 255) / 256, 256, 0, stream>>>(Wo_loc,   wbf + 393216, 256, 256, 1048576);
    wconv3_kernel<<<(3 * 65536  + 255) / 256, 256, 0, stream>>>(Wo_exp,   wbf + 458752, 256, 256, 1048576);
    wconv3_kernel<<<(3 * 262144 + 255) / 256, 256, 0, stream>>>(W1,       wbf + 524288, 256, 1024, 1048576);
    wconv3_kernel<<<(3 * 262144 + 255) / 256, 256, 0, stream>>>(W2,       wbf + 786432, 1024, 256, 1048576);
    bcat_kernel<<<18, 256, 0, stream>>>(bqkv_loc, bqkv_exp, bcat);

    const int NBX8 = ((NNODES + 63) / 64 + 7) & ~7;  // 320 m-tiles (padded to x8)

    for (int l = 0; l < 3; l++) {
        const u16* wqkvC = wbf + (size_t)l * 1048576 + 0;
        const u16* woL   = wbf + (size_t)l * 1048576 + 393216;
        const u16* woE   = wbf + (size_t)l * 1048576 + 458752;
        const u16* w1T   = wbf + (size_t)l * 1048576 + 524288;
        const u16* w2T   = wbf + (size_t)l * 1048576 + 786432;

        // fused qkv (loc|exp) GEMM: Nout = 1536
        gemm_direct<0, 256><<<NBX8 * 12, 256, 0, stream>>>(
            h_b, wqkvC, bcat + l * 1536, qkv, nullptr, nullptr, NNODES, 1536, 12);

        // local attention branch (qkv row stride 1536, loc block at +0)
        vn_zero_kernel<<<1, 256, 0, stream>>>(vnum, vden, menc);
        vn_score_kernel<<<80, 256, 0, stream>>>(qkv, 1536, svn, menc);
        vn_accum_kernel<<<80, 256, 0, stream>>>(qkv, 1536, svn, menc, vnum, vden);
        vn_final_kernel<<<1, 64, 0, stream>>>(vnum, vden, araw);
        attn_node_kernel<<<5000, 256, 0, stream>>>(qkv, 1536, indptr, srcs, 0, 1, NREAL, araw);
        gemm_direct<1, 256><<<NBX8 * 2, 256, 0, stream>>>(
            araw, woL, bo_loc + l * 256, nullptr, aloc, nullptr, NNODES, 256, 2);

        // expander attention branch (exp block at +768)
        attn_node_kernel<<<5001, 256, 0, stream>>>(qkv + 768, 1536, nullptr, esrcs, 4, 0, NNODES, araw);
        gemm_direct<1, 256><<<NBX8 * 2, 256, 0, stream>>>(
            araw, woE, bo_exp + l * 256, nullptr, aexp, nullptr, NNODES, 256, 2);

        // layernorm(res + loc + exp)
        ln_kernel<<<(NNODES + 3) / 4, 256, 0, stream>>>(
            h_f, aloc, aexp, ln_g + l * 256, ln_b + l * 256, h_f, h_b);

        // FFN: mid = gelu(h@W1+b1) [bf16, aliases aloc/aexp]; h += mid@W2+b2
        gemm_direct<2, 256><<<NBX8 * 8, 256, 0, stream>>>(
            h_b, w1T, b1 + l * 1024, mid, nullptr, nullptr, NNODES, 1024, 8);
        if (l < 2) {
            gemm_direct<3, 1024><<<NBX8 * 2, 256, 0, stream>>>(
                mid, w2T, b2 + l * 256, h_b, h_f, h_f, NNODES, 256, 2);
        } else {
            gemm_direct<4, 1024><<<NBX8 * 2, 256, 0, stream>>>(
                mid, w2T, b2 + l * 256, nullptr, (float*)d_out, h_f, NNODES, 256, 2);
        }
    }
}

// Round 5
// 1126.388 us; speedup vs baseline: 1.3736x; 1.3736x over previous
//
#include <hip/hip_runtime.h>
#include <stdint.h>

#define NREAL   20000
#define NNODES  20001
#define VN      20000
#define E_EDGES 320000
#define NEXP    80004
#define MPAD    20096   // rows padded to 157*128 for fragment-major buffers

typedef unsigned short u16;
typedef unsigned int   u32;
typedef __bf16 bf16x8 __attribute__((ext_vector_type(8)));
typedef float  f32x4  __attribute__((ext_vector_type(4)));

// fragment-major layout: element (row, col) of an LD-wide matrix lives at
// (row/16)*(16*LD) + (col/8)*128 + (row%16)*8 + (col%8).
// A wave's MFMA fragment (16 rows x 32 cols) is then 1024 contiguous bytes.
__device__ __host__ __forceinline__ size_t fmoff(int row, int col, int LD) {
    return (size_t)(row >> 4) * ((size_t)LD * 16) + (size_t)((col >> 3) * 128)
         + (size_t)((row & 15) * 8) + (size_t)(col & 7);
}

__device__ __forceinline__ float bf2f(u16 v) {
    union { u32 u; float f; } x; x.u = ((u32)v) << 16; return x.f;
}
__device__ __forceinline__ u16 f2bf(float f) {
    union { float f; u32 u; } x; x.f = f;
    u32 r = (x.u + 0x7fffu + ((x.u >> 16) & 1u)) >> 16;
    return (u16)r;
}
__device__ __forceinline__ float4 ld4bf(const u16* p) {
    ushort4 u = *(const ushort4*)p;
    return make_float4(bf2f(u.x), bf2f(u.y), bf2f(u.z), bf2f(u.w));
}
__device__ __forceinline__ u32 enc_f(float f) {
    u32 u = __float_as_uint(f);
    return (u & 0x80000000u) ? ~u : (u | 0x80000000u);
}
__device__ __forceinline__ float dec_f(u32 u) {
    u32 v = (u & 0x80000000u) ? (u & 0x7fffffffu) : ~u;
    return __uint_as_float(v);
}

// ---------------- setup kernels ----------------

__global__ void hinit_kernel(const float* __restrict__ x, float* __restrict__ h,
                             u16* __restrict__ hb) {
    size_t i = (size_t)blockIdx.x * 256 + threadIdx.x;
    if (i >= (size_t)NNODES * 256) return;
    int row = (int)(i >> 8), col = (int)(i & 255);
    float v = (i < (size_t)NREAL * 256) ? x[i] : 0.0f;
    h[i] = v;
    hb[fmoff(row, col, 256)] = f2bf(v);
}

__global__ void zero_csr_kernel(int* cnt, int* fill, int* ecnt) {
    int i = blockIdx.x * 256 + threadIdx.x;
    if (i < NREAL) { cnt[i] = 0; fill[i] = 0; }
    if (i < NNODES) ecnt[i] = 0;
}

__global__ void csr_count_kernel(const int* __restrict__ ei, int* __restrict__ cnt) {
    int e = blockIdx.x * 256 + threadIdx.x;
    if (e < E_EDGES) atomicAdd(&cnt[ei[E_EDGES + e]], 1);
}

__global__ void csr_scan_kernel(const int* __restrict__ cnt, int* __restrict__ indptr) {
    __shared__ int ssum[256];
    int t = threadIdx.x;
    int c0 = t * 79;
    int s = 0;
    for (int j = 0; j < 79; j++) {
        int i = c0 + j;
        if (i < NREAL) s += cnt[i];
    }
    ssum[t] = s;
    __syncthreads();
    for (int d2 = 1; d2 < 256; d2 <<= 1) {
        int v = (t >= d2) ? ssum[t - d2] : 0;
        __syncthreads();
        ssum[t] += v;
        __syncthreads();
    }
    int run = (t == 0) ? 0 : ssum[t - 1];
    for (int j = 0; j < 79; j++) {
        int i = c0 + j;
        if (i < NREAL) { indptr[i] = run; run += cnt[i]; }
    }
    if (t == 255) indptr[NREAL] = run;
}

__global__ void csr_scatter_kernel(const int* __restrict__ ei, const int* __restrict__ indptr,
                                   int* __restrict__ fill, int* __restrict__ srcs) {
    int e = blockIdx.x * 256 + threadIdx.x;
    if (e < E_EDGES) {
        int d = ei[E_EDGES + e];
        int pos = indptr[d] + atomicAdd(&fill[d], 1);
        srcs[pos] = ei[e];
    }
}

__global__ void exp_scatter_kernel(const int* __restrict__ eei, int* __restrict__ ecnt,
                                   int* __restrict__ esrcs) {
    int e = blockIdx.x * 256 + threadIdx.x;
    if (e < NEXP) {
        int d = eei[NEXP + e];
        int pos = atomicAdd(&ecnt[d], 1);
        esrcs[d * 4 + pos] = eei[e];
    }
}

// transpose + bf16 + fragment-major: (L,K,N) float -> per-layer FM(N x K) slabs
__global__ void wconv3_kernel(const float* __restrict__ W, u16* __restrict__ out,
                              int K, int N, int lstride_out) {
    int i = blockIdx.x * 256 + threadIdx.x;
    int per = K * N;
    if (i >= 3 * per) return;
    int l = i / per, r = i - l * per;
    int k = r / N, n = r - k * N;
    out[(size_t)l * lstride_out + fmoff(n, k, K)] = f2bf(W[i]);
}

__global__ void bcat_kernel(const float* __restrict__ bl, const float* __restrict__ be,
                            float* __restrict__ bcat) {
    int i = blockIdx.x * 256 + threadIdx.x;
    if (i >= 3 * 1536) return;
    int l = i / 1536, c = i - l * 1536;
    bcat[i] = (c < 768) ? bl[l * 768 + c] : be[l * 768 + c - 768];
}

// ---------------- GEMM: LDS-free, fragment-major coalesced loads ----------------
// A: FM(M x K); Bt: FM(Nout x K). Tile MT x 128, 4 waves; wave = (MT/2) x 64.
// Frag load per lane: 16B at panel_base + q*128 + lm*8 -> wave reads 1024
// contiguous bytes (16 lines) = fully coalesced, direct to VGPR. No LDS.
// XCD-pinned 1-D swizzle: all N-tiles of an m-tile land on one XCD.
// EPI: 0 bias->bf16 natural; 1 bias->f32 natural; 2 bias->gelu->bf16 FM;
//      3 bias+resid->f32 natural + bf16 FM; 4 bias+resid->f32 natural (rows<NREAL);
//      5 bias + accumulate into Cf (Cf += v + bias)

template <int EPI, int K, int MT, int OCC>
__global__ __launch_bounds__(256, OCC) void gemm_fm(
    const u16* __restrict__ A, const u16* __restrict__ Bt, const float* __restrict__ bias,
    u16* Cb, float* Cf, const float* resid, int M, int Nout, int nby) {
    constexpr int MFR = MT / 32;
    constexpr int NK = K / 32;
    const int lin = blockIdx.x;
    const int xcd = lin & 7, sub = lin >> 3;
    const int mtile = xcd + 8 * (sub / nby);
    const int ntile = sub - (sub / nby) * nby;
    const int tm = mtile * MT, tn = ntile * 128;
    if (tm >= M) return;

    const int tid = threadIdx.x;
    const int w = tid >> 6, lane = tid & 63;
    const int lm = lane & 15, q = lane >> 4;
    const int mo = (w >> 1) * (MT / 2), no = (w & 1) * 64;

    f32x4 acc[MFR][4];
#pragma unroll
    for (int a = 0; a < MFR; a++)
#pragma unroll
        for (int b = 0; b < 4; b++) acc[a][b] = (f32x4)0.0f;

    const u16* apf[MFR];
    const u16* bpf[4];
#pragma unroll
    for (int t = 0; t < MFR; t++) {
        int p = (tm + mo) / 16 + t;
        apf[t] = A + (size_t)p * (16 * K) + q * 128 + lm * 8;
    }
#pragma unroll
    for (int n = 0; n < 4; n++) {
        int c = (tn + no) / 16 + n;
        bpf[n] = Bt + (size_t)c * (16 * K) + q * 128 + lm * 8;
    }

    bf16x8 curA[MFR], curB[4], nxtA[MFR], nxtB[4];
#pragma unroll
    for (int t = 0; t < MFR; t++) curA[t] = *(const bf16x8*)(apf[t]);
#pragma unroll
    for (int n = 0; n < 4; n++) curB[n] = *(const bf16x8*)(bpf[n]);

#pragma unroll
    for (int i = 0; i < NK; i++) {
        if (i + 1 < NK) {
#pragma unroll
            for (int t = 0; t < MFR; t++) nxtA[t] = *(const bf16x8*)(apf[t] + (i + 1) * 512);
#pragma unroll
            for (int n = 0; n < 4; n++) nxtB[n] = *(const bf16x8*)(bpf[n] + (i + 1) * 512);
        }
#pragma unroll
        for (int mi = 0; mi < MFR; mi++)
#pragma unroll
            for (int ni = 0; ni < 4; ni++)
                acc[mi][ni] = __builtin_amdgcn_mfma_f32_16x16x32_bf16(
                    curA[mi], curB[ni], acc[mi][ni], 0, 0, 0);
        if (i + 1 < NK) {
#pragma unroll
            for (int t = 0; t < MFR; t++) curA[t] = nxtA[t];
#pragma unroll
            for (int n = 0; n < 4; n++) curB[n] = nxtB[n];
        }
    }

#pragma unroll
    for (int mi = 0; mi < MFR; mi++) {
#pragma unroll
        for (int r = 0; r < 4; r++) {
            int grow = tm + mo + mi * 16 + q * 4 + r;
            if (grow >= M) continue;
#pragma unroll
            for (int ni = 0; ni < 4; ni++) {
                int gcol = tn + no + ni * 16 + lm;
                float v = acc[mi][ni][r] + bias[gcol];
                size_t idx = (size_t)grow * Nout + gcol;
                if constexpr (EPI == 0) {
                    Cb[idx] = f2bf(v);
                } else if constexpr (EPI == 1) {
                    Cf[idx] = v;
                } else if constexpr (EPI == 2) {
                    float g = 0.5f * v * (1.0f + erff(v * 0.70710678118654752f));
                    Cb[fmoff(grow, gcol, Nout)] = f2bf(g);
                } else if constexpr (EPI == 3) {
                    float o = resid[idx] + v;
                    Cf[idx] = o;
                    Cb[fmoff(grow, gcol, Nout)] = f2bf(o);
                } else if constexpr (EPI == 4) {
                    if (grow < NREAL) {
                        float o = resid[idx] + v;
                        Cf[idx] = o;
                    }
                } else {
                    Cf[idx] = Cf[idx] + v;
                }
            }
        }
    }
}

// ---------------- attention ----------------
// One wave per destination node; 4 head-groups of 16 lanes; lane owns 4 dims.
// qkv natural layout (row stride LD); output araw in fragment-major (LD=256).
__global__ void attn_node_kernel(const u16* __restrict__ qkv, int LD,
                                 const int* __restrict__ indptr,
                                 const int* __restrict__ srcs, int fixed_deg, int add_vn,
                                 int n_nodes, u16* __restrict__ out) {
    int gw = (int)((blockIdx.x * (size_t)blockDim.x + threadIdx.x) >> 6);
    if (gw >= n_nodes) return;
    int lane = threadIdx.x & 63;
    int h = lane >> 4, t = lane & 15;
    int off = h * 64 + t * 4;
    float4 qv = ld4bf(qkv + (size_t)gw * LD + off);
    int beg, deg;
    if (fixed_deg) { beg = gw * fixed_deg; deg = fixed_deg; }
    else           { beg = indptr[gw]; deg = indptr[gw + 1] - beg; }
    int tot = deg + add_vn;
    float m = -1e30f, l = 0.0f;
    float ax = 0, ay = 0, az = 0, aw = 0;
    int e = 0;
    for (; e + 2 <= tot; e += 2) {
        int s0 = (e < deg) ? srcs[beg + e] : VN;
        int s1 = (e + 1 < deg) ? srcs[beg + e + 1] : VN;
        const u16* p0 = qkv + (size_t)s0 * LD + off;
        const u16* p1 = qkv + (size_t)s1 * LD + off;
        float4 k0 = ld4bf(p0 + 256);
        float4 k1 = ld4bf(p1 + 256);
        float4 v0 = ld4bf(p0 + 512);
        float4 v1 = ld4bf(p1 + 512);
        float pa = qv.x * k0.x + qv.y * k0.y + qv.z * k0.z + qv.w * k0.w;
        float pb = qv.x * k1.x + qv.y * k1.y + qv.z * k1.z + qv.w * k1.w;
        pa += __shfl_xor(pa, 1); pb += __shfl_xor(pb, 1);
        pa += __shfl_xor(pa, 2); pb += __shfl_xor(pb, 2);
        pa += __shfl_xor(pa, 4); pb += __shfl_xor(pb, 4);
        pa += __shfl_xor(pa, 8); pb += __shfl_xor(pb, 8);
        float sa = pa * 0.125f, sb = pb * 0.125f;
        float mn = fmaxf(m, fmaxf(sa, sb));
        float fold = __expf(m - mn);
        float e0 = __expf(sa - mn);
        float e1 = __expf(sb - mn);
        ax = ax * fold + v0.x * e0 + v1.x * e1;
        ay = ay * fold + v0.y * e0 + v1.y * e1;
        az = az * fold + v0.z * e0 + v1.z * e1;
        aw = aw * fold + v0.w * e0 + v1.w * e1;
        l = l * fold + e0 + e1;
        m = mn;
    }
    if (e < tot) {
        int s = (e < deg) ? srcs[beg + e] : VN;
        const u16* p = qkv + (size_t)s * LD + off;
        float4 kv = ld4bf(p + 256);
        float4 vv = ld4bf(p + 512);
        float p0 = qv.x * kv.x + qv.y * kv.y + qv.z * kv.z + qv.w * kv.w;
        p0 += __shfl_xor(p0, 1); p0 += __shfl_xor(p0, 2);
        p0 += __shfl_xor(p0, 4); p0 += __shfl_xor(p0, 8);
        float sc = p0 * 0.125f;
        float mn = fmaxf(m, sc);
        float fold = __expf(m - mn);
        float ee = __expf(sc - mn);
        ax = ax * fold + vv.x * ee;
        ay = ay * fold + vv.y * ee;
        az = az * fold + vv.z * ee;
        aw = aw * fold + vv.w * ee;
        l = l * fold + ee;
        m = mn;
    }
    float inv = 1.0f / (l + 1e-16f);
    ushort4 o;
    o.x = f2bf(ax * inv); o.y = f2bf(ay * inv);
    o.z = f2bf(az * inv); o.w = f2bf(aw * inv);
    *(ushort4*)(out + fmoff(gw, off, 256)) = o;
}

// virtual node (dst = VN), dense 3-phase
__global__ void vn_zero_kernel(float* vnum, float* vden, u32* menc) {
    int t = threadIdx.x;
    vnum[t] = 0.0f;
    if (t < 4) { vden[t] = 0.0f; menc[t] = enc_f(-1e30f); }
}

__global__ void vn_score_kernel(const u16* __restrict__ qkv, int LD, float* __restrict__ svn,
                                u32* __restrict__ menc) {
    int lane = threadIdx.x & 63;
    int h = lane >> 4, t = lane & 15;
    int off = h * 64 + t * 4;
    float4 qv = ld4bf(qkv + (size_t)VN * LD + off);
    int wid = (int)((blockIdx.x * (size_t)blockDim.x + threadIdx.x) >> 6);
    int nw = (gridDim.x * blockDim.x) >> 6;
    float wmax = -1e30f;
    for (int i = wid; i < NREAL; i += nw) {
        float4 kv = ld4bf(qkv + (size_t)i * LD + 256 + off);
        float p = qv.x * kv.x + qv.y * kv.y + qv.z * kv.z + qv.w * kv.w;
        p += __shfl_xor(p, 1); p += __shfl_xor(p, 2);
        p += __shfl_xor(p, 4); p += __shfl_xor(p, 8);
        float sc = p * 0.125f;
        if (t == 0) svn[i * 4 + h] = sc;
        wmax = fmaxf(wmax, sc);
    }
    if (t == 0) atomicMax(&menc[h], enc_f(wmax));
}

__global__ void vn_accum_kernel(const u16* __restrict__ qkv, int LD,
                                const float* __restrict__ svn,
                                const u32* __restrict__ menc, float* __restrict__ vnum,
                                float* __restrict__ vden) {
    int lane = threadIdx.x & 63;
    int h = lane >> 4, t = lane & 15;
    int off = h * 64 + t * 4;
    float m = dec_f(menc[h]);
    int wid = (int)((blockIdx.x * (size_t)blockDim.x + threadIdx.x) >> 6);
    int nw = (gridDim.x * blockDim.x) >> 6;
    float ax = 0, ay = 0, az = 0, aw = 0, l = 0;
    for (int i = wid; i < NREAL; i += nw) {
        float e = __expf(svn[i * 4 + h] - m);
        float4 vv = ld4bf(qkv + (size_t)i * LD + 512 + off);
        ax += e * vv.x; ay += e * vv.y; az += e * vv.z; aw += e * vv.w;
        l += e;
    }
    atomicAdd(&vnum[off + 0], ax);
    atomicAdd(&vnum[off + 1], ay);
    atomicAdd(&vnum[off + 2], az);
    atomicAdd(&vnum[off + 3], aw);
    if (t == 0) atomicAdd(&vden[h], l);
}

__global__ void vn_final_kernel(const float* __restrict__ vnum, const float* __restrict__ vden,
                                u16* __restrict__ araw) {
    int lane = threadIdx.x;
    int h = lane >> 4;
    float inv = 1.0f / (vden[h] + 1e-16f);
    ushort4 o;
    o.x = f2bf(vnum[lane * 4 + 0] * inv);
    o.y = f2bf(vnum[lane * 4 + 1] * inv);
    o.z = f2bf(vnum[lane * 4 + 2] * inv);
    o.w = f2bf(vnum[lane * 4 + 3] * inv);
    *(ushort4*)(araw + fmoff(VN, lane * 4, 256)) = o;
}

// ---------------- layernorm (fused residual + attn-sum), FM bf16 out ----------------
__global__ void ln_kernel(const float* hin, const float* __restrict__ asum,
                          const float* __restrict__ g, const float* __restrict__ b,
                          float* hout, u16* __restrict__ hb) {
    int row = blockIdx.x * 4 + (threadIdx.x >> 6);
    if (row >= NNODES) return;
    int lane = threadIdx.x & 63;
    size_t base = (size_t)row * 256 + lane * 4;
    float4 xv = *(const float4*)(hin + base);
    float4 av = *(const float4*)(asum + base);
    xv.x += av.x; xv.y += av.y; xv.z += av.z; xv.w += av.w;
    float s = xv.x + xv.y + xv.z + xv.w;
#pragma unroll
    for (int o = 1; o < 64; o <<= 1) s += __shfl_xor(s, o);
    float mu = s * (1.0f / 256.0f);
    float dx = xv.x - mu, dy = xv.y - mu, dz = xv.z - mu, dw = xv.w - mu;
    float ss = dx * dx + dy * dy + dz * dz + dw * dw;
#pragma unroll
    for (int o = 1; o < 64; o <<= 1) ss += __shfl_xor(ss, o);
    float var = ss * (1.0f / 256.0f);
    float inv = 1.0f / sqrtf(var + 1e-5f);
    float4 gv = *(const float4*)(g + lane * 4);
    float4 bv = *(const float4*)(b + lane * 4);
    float4 y;
    y.x = dx * inv * gv.x + bv.x;
    y.y = dy * inv * gv.y + bv.y;
    y.z = dz * inv * gv.z + bv.z;
    y.w = dw * inv * gv.w + bv.w;
    *(float4*)(hout + base) = y;
    ushort4 o4;
    o4.x = f2bf(y.x); o4.y = f2bf(y.y); o4.z = f2bf(y.z); o4.w = f2bf(y.w);
    *(ushort4*)(hb + fmoff(row, lane * 4, 256)) = o4;
}

// ---------------- host ----------------

extern "C" void kernel_launch(void* const* d_in, const int* in_sizes, int n_in,
                              void* d_out, int out_size, void* d_ws, size_t ws_size,
                              hipStream_t stream) {
    (void)in_sizes; (void)n_in; (void)out_size; (void)ws_size;
    const float* x        = (const float*)d_in[0];
    const int*   ei       = (const int*)d_in[1];
    const int*   eei      = (const int*)d_in[2];
    const float* Wqkv_loc = (const float*)d_in[3];
    const float* bqkv_loc = (const float*)d_in[4];
    const float* Wo_loc   = (const float*)d_in[5];
    const float* bo_loc   = (const float*)d_in[6];
    const float* Wqkv_exp = (const float*)d_in[7];
    const float* bqkv_exp = (const float*)d_in[8];
    const float* Wo_exp   = (const float*)d_in[9];
    const float* bo_exp   = (const float*)d_in[10];
    const float* ln_g     = (const float*)d_in[11];
    const float* ln_b     = (const float*)d_in[12];
    const float* W1       = (const float*)d_in[13];
    const float* b1       = (const float*)d_in[14];
    const float* W2       = (const float*)d_in[15];
    const float* b2       = (const float*)d_in[16];

    char* wsp = (char*)d_ws;
    size_t off = 0;
    auto carve = [&](size_t bytes) -> void* {
        void* p = wsp + off;
        off += (bytes + 255) & ~(size_t)255;
        return p;
    };
    float* h_f   = (float*)carve((size_t)NNODES * 256 * 4);
    u16*   h_b   = (u16*)carve((size_t)MPAD * 256 * 2);     // fragment-major
    u16*   qkv   = (u16*)carve((size_t)NNODES * 1536 * 2);  // natural; aliased by FM mid
    u16*   araw  = (u16*)carve((size_t)MPAD * 256 * 2);     // fragment-major
    float* aloc  = (float*)carve((size_t)NNODES * 256 * 4); // natural f32 (loc + exp sum)
    u16*   wbf   = (u16*)carve((size_t)3 * 1048576 * 2);    // fragment-major weights
    float* bcat  = (float*)carve((size_t)3 * 1536 * 4);
    int*   cnt   = (int*)carve((size_t)NREAL * 4);
    int*   indptr= (int*)carve((size_t)(NREAL + 1) * 4);
    int*   fill  = (int*)carve((size_t)NREAL * 4);
    int*   srcs  = (int*)carve((size_t)E_EDGES * 4);
    int*   ecnt  = (int*)carve((size_t)NNODES * 4);
    int*   esrcs = (int*)carve((size_t)NNODES * 4 * 4);
    float* svn   = (float*)carve((size_t)NREAL * 4 * 4);
    u32*   menc  = (u32*)carve(4 * 4);
    float* vden  = (float*)carve(4 * 4);
    float* vnum  = (float*)carve(256 * 4);
    u16*   mid   = (u16*)qkv;  // FM(MPAD x 1024) = 41.2 MB fits in qkv's 61.4 MB

    hinit_kernel<<<(NNODES * 256 + 255) / 256, 256, 0, stream>>>(x, h_f, h_b);
    zero_csr_kernel<<<(NNODES + 255) / 256, 256, 0, stream>>>(cnt, fill, ecnt);
    csr_count_kernel<<<(E_EDGES + 255) / 256, 256, 0, stream>>>(ei, cnt);
    csr_scan_kernel<<<1, 256, 0, stream>>>(cnt, indptr);
    csr_scatter_kernel<<<(E_EDGES + 255) / 256, 256, 0, stream>>>(ei, indptr, fill, srcs);
    exp_scatter_kernel<<<(NEXP + 255) / 256, 256, 0, stream>>>(eei, ecnt, esrcs);

    // fragment-major weight slabs, per-layer stride 1048576 u16:
    // [0] qkv-cat FM(1536x256) (loc cols 0-767 -> panels 0-47, exp -> offset 196608)
    // [393216] WoL FM(256x256)  [458752] WoE  [524288] W1 FM(1024x256)  [786432] W2 FM(256x1024)
    wconv3_kernel<<<(3 * 196608 + 255) / 256, 256, 0, stream>>>(Wqkv_loc, wbf + 0,      256, 768, 1048576);
    wconv3_kernel<<<(3 * 196608 + 255) / 256, 256, 0, stream>>>(Wqkv_exp, wbf + 196608, 256, 768, 1048576);
    wconv3_kernel<<<(3 * 65536  + 255) / 256, 256, 0, stream>>>(Wo_loc,   wbf + 393216, 256, 256, 1048576);
    wconv3_kernel<<<(3 * 65536  + 255) / 256, 256, 0, stream>>>(Wo_exp,   wbf + 458752, 256, 256, 1048576);
    wconv3_kernel<<<(3 * 262144 + 255) / 256, 256, 0, stream>>>(W1,       wbf + 524288, 256, 1024, 1048576);
    wconv3_kernel<<<(3 * 262144 + 255) / 256, 256, 0, stream>>>(W2,       wbf + 786432, 1024, 256, 1048576);
    bcat_kernel<<<18, 256, 0, stream>>>(bqkv_loc, bqkv_exp, bcat);

    const int NBM128 = 160;  // ceil(20001/128)=157, padded to x8
    const int NBM64  = 320;  // ceil(20001/64)=313, padded to x8

    for (int l = 0; l < 3; l++) {
        const u16* wqkvC = wbf + (size_t)l * 1048576 + 0;
        const u16* woL   = wbf + (size_t)l * 1048576 + 393216;
        const u16* woE   = wbf + (size_t)l * 1048576 + 458752;
        const u16* w1T   = wbf + (size_t)l * 1048576 + 524288;
        const u16* w2T   = wbf + (size_t)l * 1048576 + 786432;

        // fused qkv (loc|exp) GEMM: Nout = 1536, natural output
        gemm_fm<0, 256, 128, 3><<<NBM128 * 12, 256, 0, stream>>>(
            h_b, wqkvC, bcat + l * 1536, qkv, nullptr, nullptr, NNODES, 1536, 12);

        // local attention branch (qkv stride 1536, loc block at +0)
        vn_zero_kernel<<<1, 256, 0, stream>>>(vnum, vden, menc);
        vn_score_kernel<<<80, 256, 0, stream>>>(qkv, 1536, svn, menc);
        vn_accum_kernel<<<80, 256, 0, stream>>>(qkv, 1536, svn, menc, vnum, vden);
        vn_final_kernel<<<1, 64, 0, stream>>>(vnum, vden, araw);
        attn_node_kernel<<<5000, 256, 0, stream>>>(qkv, 1536, indptr, srcs, 0, 1, NREAL, araw);
        gemm_fm<1, 256, 64, 4><<<NBM64 * 2, 256, 0, stream>>>(
            araw, woL, bo_loc + l * 256, nullptr, aloc, nullptr, NNODES, 256, 2);

        // expander attention branch (exp block at +768); WoE accumulates into aloc
        attn_node_kernel<<<5001, 256, 0, stream>>>(qkv + 768, 1536, nullptr, esrcs, 4, 0, NNODES, araw);
        gemm_fm<5, 256, 64, 4><<<NBM64 * 2, 256, 0, stream>>>(
            araw, woE, bo_exp + l * 256, nullptr, aloc, nullptr, NNODES, 256, 2);

        // layernorm(res + attn-sum) -> h_f natural + h_b FM
        ln_kernel<<<(NNODES + 3) / 4, 256, 0, stream>>>(
            h_f, aloc, ln_g + l * 256, ln_b + l * 256, h_f, h_b);

        // FFN: mid = gelu(h@W1+b1) [FM bf16, aliases qkv]; h += mid@W2+b2
        gemm_fm<2, 256, 128, 3><<<NBM128 * 8, 256, 0, stream>>>(
            h_b, w1T, b1 + l * 1024, mid, nullptr, nullptr, NNODES, 1024, 8);
        if (l < 2) {
            gemm_fm<3, 1024, 64, 4><<<NBM64 * 2, 256, 0, stream>>>(
                mid, w2T, b2 + l * 256, h_b, h_f, h_f, NNODES, 256, 2);
        } else {
            gemm_fm<4, 1024, 64, 4><<<NBM64 * 2, 256, 0, stream>>>(
                mid, w2T, b2 + l * 256, nullptr, (float*)d_out, h_f, NNODES, 256, 2);
        }
    }
}

// Round 6
// 1082.407 us; speedup vs baseline: 1.4294x; 1.0406x over previous
//
#include <hip/hip_runtime.h>
#include <stdint.h>

#define NREAL   20000
#define NNODES  20001
#define VN      20000
#define E_EDGES 320000
#define NEXP    80004
#define MPAD    20096   // rows padded to 157*128 for fragment-major buffers

typedef unsigned short u16;
typedef unsigned int   u32;
typedef __bf16 bf16x8 __attribute__((ext_vector_type(8)));
typedef float  f32x4  __attribute__((ext_vector_type(4)));

// fragment-major layout: element (row, col) of an LD-wide matrix lives at
// (row/16)*(16*LD) + (col/8)*128 + (row%16)*8 + (col%8).
// A wave's MFMA fragment (16 rows x 32 cols) is then 1024 contiguous bytes.
__device__ __host__ __forceinline__ size_t fmoff(int row, int col, int LD) {
    return (size_t)(row >> 4) * ((size_t)LD * 16) + (size_t)((col >> 3) * 128)
         + (size_t)((row & 15) * 8) + (size_t)(col & 7);
}

__device__ __forceinline__ float bf2f(u16 v) {
    union { u32 u; float f; } x; x.u = ((u32)v) << 16; return x.f;
}
__device__ __forceinline__ u16 f2bf(float f) {
    union { float f; u32 u; } x; x.f = f;
    u32 r = (x.u + 0x7fffu + ((x.u >> 16) & 1u)) >> 16;
    return (u16)r;
}
__device__ __forceinline__ float4 ld4bf(const u16* p) {
    ushort4 u = *(const ushort4*)p;
    return make_float4(bf2f(u.x), bf2f(u.y), bf2f(u.z), bf2f(u.w));
}
__device__ __forceinline__ u32 enc_f(float f) {
    u32 u = __float_as_uint(f);
    return (u & 0x80000000u) ? ~u : (u | 0x80000000u);
}
__device__ __forceinline__ float dec_f(u32 u) {
    u32 v = (u & 0x80000000u) ? (u & 0x7fffffffu) : ~u;
    return __uint_as_float(v);
}

// ---------------- setup kernels ----------------

__global__ void hinit_kernel(const float* __restrict__ x, float* __restrict__ h,
                             u16* __restrict__ hb) {
    int idx = blockIdx.x * 256 + threadIdx.x;
    if (idx >= NNODES * 64) return;
    int row = idx >> 6, c0 = (idx & 63) * 4;
    float4 v = make_float4(0.f, 0.f, 0.f, 0.f);
    if (row < NREAL) v = *(const float4*)(x + (size_t)row * 256 + c0);
    *(float4*)(h + (size_t)row * 256 + c0) = v;
    ushort4 o;
    o.x = f2bf(v.x); o.y = f2bf(v.y); o.z = f2bf(v.z); o.w = f2bf(v.w);
    *(ushort4*)(hb + fmoff(row, c0, 256)) = o;
}

__global__ void zero_csr_kernel(int* cnt, int* fill, int* ecnt) {
    int i = blockIdx.x * 256 + threadIdx.x;
    if (i < NREAL) { cnt[i] = 0; fill[i] = 0; }
    if (i < NNODES) ecnt[i] = 0;
}

__global__ void csr_count_kernel(const int* __restrict__ ei, int* __restrict__ cnt) {
    int e = blockIdx.x * 256 + threadIdx.x;
    if (e < E_EDGES) atomicAdd(&cnt[ei[E_EDGES + e]], 1);
}

__global__ void csr_scan_kernel(const int* __restrict__ cnt, int* __restrict__ indptr) {
    __shared__ int ssum[256];
    int t = threadIdx.x;
    int c0 = t * 79;
    int s = 0;
    for (int j = 0; j < 79; j++) {
        int i = c0 + j;
        if (i < NREAL) s += cnt[i];
    }
    ssum[t] = s;
    __syncthreads();
    for (int d2 = 1; d2 < 256; d2 <<= 1) {
        int v = (t >= d2) ? ssum[t - d2] : 0;
        __syncthreads();
        ssum[t] += v;
        __syncthreads();
    }
    int run = (t == 0) ? 0 : ssum[t - 1];
    for (int j = 0; j < 79; j++) {
        int i = c0 + j;
        if (i < NREAL) { indptr[i] = run; run += cnt[i]; }
    }
    if (t == 255) indptr[NREAL] = run;
}

__global__ void csr_scatter_kernel(const int* __restrict__ ei, const int* __restrict__ indptr,
                                   int* __restrict__ fill, int* __restrict__ srcs) {
    int e = blockIdx.x * 256 + threadIdx.x;
    if (e < E_EDGES) {
        int d = ei[E_EDGES + e];
        int pos = indptr[d] + atomicAdd(&fill[d], 1);
        srcs[pos] = ei[e];
    }
}

__global__ void exp_scatter_kernel(const int* __restrict__ eei, int* __restrict__ ecnt,
                                   int* __restrict__ esrcs) {
    int e = blockIdx.x * 256 + threadIdx.x;
    if (e < NEXP) {
        int d = eei[NEXP + e];
        int pos = atomicAdd(&ecnt[d], 1);
        esrcs[d * 4 + pos] = eei[e];
    }
}

// transpose + bf16 + fragment-major: (L,K,N) float -> per-layer FM(N x K) slabs
__global__ void wconv3_kernel(const float* __restrict__ W, u16* __restrict__ out,
                              int K, int N, int lstride_out) {
    int i = blockIdx.x * 256 + threadIdx.x;
    int per = K * N;
    if (i >= 3 * per) return;
    int l = i / per, r = i - l * per;
    int k = r / N, n = r - k * N;
    out[(size_t)l * lstride_out + fmoff(n, k, K)] = f2bf(W[i]);
}

__global__ void bcat_kernel(const float* __restrict__ bl, const float* __restrict__ be,
                            float* __restrict__ bcat) {
    int i = blockIdx.x * 256 + threadIdx.x;
    if (i >= 3 * 1536) return;
    int l = i / 1536, c = i - l * 1536;
    bcat[i] = (c < 768) ? bl[l * 768 + c] : be[l * 768 + c - 768];
}

// ---------------- GEMM: LDS-free FM loads, transposed-accumulator epilogue ------
// A: FM(M x K); Bt: FM(Nout x K). Tile MT x 128, 4 waves; wave = (MT/2) x 64.
// mfma(weightFrag, actFrag, acc): D col(lane&15) = output ROW, D row(q*4+reg) =
// 4 CONSECUTIVE output cols -> per-fragment packed float4/ushort4 stores.
// XCD-pinned 1-D swizzle. EPI: 0 bias->bf16 natural; 1 bias->f32 natural;
// 2 bias->gelu->bf16 FM; 3 bias+resid->f32 natural + bf16 FM;
// 4 bias+resid->f32 natural (rows<NREAL); 5 bias + Cf += v

template <int EPI, int K, int MT, int OCC>
__global__ __launch_bounds__(256, OCC) void gemm_fm(
    const u16* __restrict__ A, const u16* __restrict__ Bt, const float* __restrict__ bias,
    u16* Cb, float* Cf, const float* resid, int M, int Nout, int nby) {
    constexpr int MFR = MT / 32;
    constexpr int NK = K / 32;
    const int lin = blockIdx.x;
    const int xcd = lin & 7, sub = lin >> 3;
    const int mtile = xcd + 8 * (sub / nby);
    const int ntile = sub - (sub / nby) * nby;
    const int tm = mtile * MT, tn = ntile * 128;
    if (tm >= M) return;

    const int tid = threadIdx.x;
    const int w = tid >> 6, lane = tid & 63;
    const int lm = lane & 15, q = lane >> 4;
    const int mo = (w >> 1) * (MT / 2), no = (w & 1) * 64;

    f32x4 acc[MFR][4];
#pragma unroll
    for (int a = 0; a < MFR; a++)
#pragma unroll
        for (int b = 0; b < 4; b++) acc[a][b] = (f32x4)0.0f;

    const u16* apf[MFR];
    const u16* bpf[4];
#pragma unroll
    for (int t = 0; t < MFR; t++) {
        int p = (tm + mo) / 16 + t;
        apf[t] = A + (size_t)p * (16 * K) + q * 128 + lm * 8;
    }
#pragma unroll
    for (int n = 0; n < 4; n++) {
        int c = (tn + no) / 16 + n;
        bpf[n] = Bt + (size_t)c * (16 * K) + q * 128 + lm * 8;
    }

    bf16x8 curA[MFR], curB[4], nxtA[MFR], nxtB[4];
#pragma unroll
    for (int t = 0; t < MFR; t++) curA[t] = *(const bf16x8*)(apf[t]);
#pragma unroll
    for (int n = 0; n < 4; n++) curB[n] = *(const bf16x8*)(bpf[n]);

#pragma unroll
    for (int i = 0; i < NK; i++) {
        if (i + 1 < NK) {
#pragma unroll
            for (int t = 0; t < MFR; t++) nxtA[t] = *(const bf16x8*)(apf[t] + (i + 1) * 512);
#pragma unroll
            for (int n = 0; n < 4; n++) nxtB[n] = *(const bf16x8*)(bpf[n] + (i + 1) * 512);
        }
#pragma unroll
        for (int mi = 0; mi < MFR; mi++)
#pragma unroll
            for (int ni = 0; ni < 4; ni++)
                acc[mi][ni] = __builtin_amdgcn_mfma_f32_16x16x32_bf16(
                    curB[ni], curA[mi], acc[mi][ni], 0, 0, 0);
        if (i + 1 < NK) {
#pragma unroll
            for (int t = 0; t < MFR; t++) curA[t] = nxtA[t];
#pragma unroll
            for (int n = 0; n < 4; n++) curB[n] = nxtB[n];
        }
    }

    // epilogue: lane owns rows (tm+mo+mi*16+lm), cols gcol0..gcol0+3
    float4 b4[4];
#pragma unroll
    for (int ni = 0; ni < 4; ni++)
        b4[ni] = *(const float4*)(bias + tn + no + ni * 16 + q * 4);

#pragma unroll
    for (int mi = 0; mi < MFR; mi++) {
        int grow = tm + mo + mi * 16 + lm;
        if constexpr (EPI == 4) { if (grow >= NREAL) continue; }
        else                    { if (grow >= M) continue; }
#pragma unroll
        for (int ni = 0; ni < 4; ni++) {
            int gcol = tn + no + ni * 16 + q * 4;
            float v0 = acc[mi][ni][0] + b4[ni].x;
            float v1 = acc[mi][ni][1] + b4[ni].y;
            float v2 = acc[mi][ni][2] + b4[ni].z;
            float v3 = acc[mi][ni][3] + b4[ni].w;
            size_t idx = (size_t)grow * Nout + gcol;
            if constexpr (EPI == 0) {
                ushort4 o;
                o.x = f2bf(v0); o.y = f2bf(v1); o.z = f2bf(v2); o.w = f2bf(v3);
                *(ushort4*)(Cb + idx) = o;
            } else if constexpr (EPI == 1) {
                *(float4*)(Cf + idx) = make_float4(v0, v1, v2, v3);
            } else if constexpr (EPI == 2) {
                // tanh-GELU (overflow-safe): g = 0.5 v (1 + (1 - 2/(e^{2u}+1)))
                float g0, g1, g2, g3;
                {
                    float u = 0.7978845608f * (v0 + 0.044715f * v0 * v0 * v0);
                    float th = 1.0f - 2.0f / (__expf(2.0f * u) + 1.0f);
                    g0 = 0.5f * v0 * (1.0f + th);
                }
                {
                    float u = 0.7978845608f * (v1 + 0.044715f * v1 * v1 * v1);
                    float th = 1.0f - 2.0f / (__expf(2.0f * u) + 1.0f);
                    g1 = 0.5f * v1 * (1.0f + th);
                }
                {
                    float u = 0.7978845608f * (v2 + 0.044715f * v2 * v2 * v2);
                    float th = 1.0f - 2.0f / (__expf(2.0f * u) + 1.0f);
                    g2 = 0.5f * v2 * (1.0f + th);
                }
                {
                    float u = 0.7978845608f * (v3 + 0.044715f * v3 * v3 * v3);
                    float th = 1.0f - 2.0f / (__expf(2.0f * u) + 1.0f);
                    g3 = 0.5f * v3 * (1.0f + th);
                }
                ushort4 o;
                o.x = f2bf(g0); o.y = f2bf(g1); o.z = f2bf(g2); o.w = f2bf(g3);
                *(ushort4*)(Cb + fmoff(grow, gcol, Nout)) = o;
            } else if constexpr (EPI == 3) {
                float4 rv = *(const float4*)(resid + idx);
                float o0 = rv.x + v0, o1 = rv.y + v1, o2 = rv.z + v2, o3 = rv.w + v3;
                *(float4*)(Cf + idx) = make_float4(o0, o1, o2, o3);
                ushort4 o;
                o.x = f2bf(o0); o.y = f2bf(o1); o.z = f2bf(o2); o.w = f2bf(o3);
                *(ushort4*)(Cb + fmoff(grow, gcol, Nout)) = o;
            } else if constexpr (EPI == 4) {
                float4 rv = *(const float4*)(resid + idx);
                *(float4*)(Cf + idx) = make_float4(rv.x + v0, rv.y + v1, rv.z + v2, rv.w + v3);
            } else {
                float4 old = *(const float4*)(Cf + idx);
                *(float4*)(Cf + idx) = make_float4(old.x + v0, old.y + v1, old.z + v2, old.w + v3);
            }
        }
    }
}

// ---------------- attention ----------------
// One wave per destination node; 4 head-groups of 16 lanes; lane owns 4 dims.
// qkv natural layout (row stride LD); output araw in fragment-major (LD=256).
// 4-way edge unroll: 8 K/V loads in flight per iteration.
__global__ void attn_node_kernel(const u16* __restrict__ qkv, int LD,
                                 const int* __restrict__ indptr,
                                 const int* __restrict__ srcs, int fixed_deg, int add_vn,
                                 int n_nodes, u16* __restrict__ out) {
    int gw = (int)((blockIdx.x * (size_t)blockDim.x + threadIdx.x) >> 6);
    if (gw >= n_nodes) return;
    int lane = threadIdx.x & 63;
    int h = lane >> 4, t = lane & 15;
    int off = h * 64 + t * 4;
    float4 qv = ld4bf(qkv + (size_t)gw * LD + off);
    int beg, deg;
    if (fixed_deg) { beg = gw * fixed_deg; deg = fixed_deg; }
    else           { beg = indptr[gw]; deg = indptr[gw + 1] - beg; }
    int tot = deg + add_vn;
    float m = -1e30f, l = 0.0f;
    float ax = 0, ay = 0, az = 0, aw = 0;
    int e = 0;
    for (; e + 4 <= tot; e += 4) {
        float4 kv[4], vv[4];
#pragma unroll
        for (int j = 0; j < 4; j++) {
            int s = (e + j < deg) ? srcs[beg + e + j] : VN;
            const u16* p = qkv + (size_t)s * LD + off;
            kv[j] = ld4bf(p + 256);
            vv[j] = ld4bf(p + 512);
        }
        float sc[4];
#pragma unroll
        for (int j = 0; j < 4; j++) {
            float p = qv.x * kv[j].x + qv.y * kv[j].y + qv.z * kv[j].z + qv.w * kv[j].w;
            p += __shfl_xor(p, 1); p += __shfl_xor(p, 2);
            p += __shfl_xor(p, 4); p += __shfl_xor(p, 8);
            sc[j] = p * 0.125f;
        }
        float mn = fmaxf(fmaxf(sc[0], sc[1]), fmaxf(sc[2], sc[3]));
        mn = fmaxf(m, mn);
        float fold = __expf(m - mn);
        ax *= fold; ay *= fold; az *= fold; aw *= fold; l *= fold;
#pragma unroll
        for (int j = 0; j < 4; j++) {
            float ee = __expf(sc[j] - mn);
            ax += vv[j].x * ee; ay += vv[j].y * ee;
            az += vv[j].z * ee; aw += vv[j].w * ee;
            l += ee;
        }
        m = mn;
    }
    for (; e < tot; e++) {
        int s = (e < deg) ? srcs[beg + e] : VN;
        const u16* p = qkv + (size_t)s * LD + off;
        float4 kv = ld4bf(p + 256);
        float4 vv = ld4bf(p + 512);
        float p0 = qv.x * kv.x + qv.y * kv.y + qv.z * kv.z + qv.w * kv.w;
        p0 += __shfl_xor(p0, 1); p0 += __shfl_xor(p0, 2);
        p0 += __shfl_xor(p0, 4); p0 += __shfl_xor(p0, 8);
        float sc = p0 * 0.125f;
        float mn = fmaxf(m, sc);
        float fold = __expf(m - mn);
        float ee = __expf(sc - mn);
        ax = ax * fold + vv.x * ee;
        ay = ay * fold + vv.y * ee;
        az = az * fold + vv.z * ee;
        aw = aw * fold + vv.w * ee;
        l = l * fold + ee;
        m = mn;
    }
    float inv = 1.0f / (l + 1e-16f);
    ushort4 o;
    o.x = f2bf(ax * inv); o.y = f2bf(ay * inv);
    o.z = f2bf(az * inv); o.w = f2bf(aw * inv);
    *(ushort4*)(out + fmoff(gw, off, 256)) = o;
}

// virtual node (dst = VN), dense 3-phase
__global__ void vn_zero_kernel(float* vnum, float* vden, u32* menc) {
    int t = threadIdx.x;
    vnum[t] = 0.0f;
    if (t < 4) { vden[t] = 0.0f; menc[t] = enc_f(-1e30f); }
}

__global__ void vn_score_kernel(const u16* __restrict__ qkv, int LD, float* __restrict__ svn,
                                u32* __restrict__ menc) {
    int lane = threadIdx.x & 63;
    int h = lane >> 4, t = lane & 15;
    int off = h * 64 + t * 4;
    float4 qv = ld4bf(qkv + (size_t)VN * LD + off);
    int wid = (int)((blockIdx.x * (size_t)blockDim.x + threadIdx.x) >> 6);
    int nw = (gridDim.x * blockDim.x) >> 6;
    float wmax = -1e30f;
    for (int i = wid; i < NREAL; i += nw) {
        float4 kv = ld4bf(qkv + (size_t)i * LD + 256 + off);
        float p = qv.x * kv.x + qv.y * kv.y + qv.z * kv.z + qv.w * kv.w;
        p += __shfl_xor(p, 1); p += __shfl_xor(p, 2);
        p += __shfl_xor(p, 4); p += __shfl_xor(p, 8);
        float sc = p * 0.125f;
        if (t == 0) svn[i * 4 + h] = sc;
        wmax = fmaxf(wmax, sc);
    }
    if (t == 0) atomicMax(&menc[h], enc_f(wmax));
}

__global__ void vn_accum_kernel(const u16* __restrict__ qkv, int LD,
                                const float* __restrict__ svn,
                                const u32* __restrict__ menc, float* __restrict__ vnum,
                                float* __restrict__ vden) {
    int lane = threadIdx.x & 63;
    int h = lane >> 4, t = lane & 15;
    int off = h * 64 + t * 4;
    float m = dec_f(menc[h]);
    int wid = (int)((blockIdx.x * (size_t)blockDim.x + threadIdx.x) >> 6);
    int nw = (gridDim.x * blockDim.x) >> 6;
    float ax = 0, ay = 0, az = 0, aw = 0, l = 0;
    for (int i = wid; i < NREAL; i += nw) {
        float e = __expf(svn[i * 4 + h] - m);
        float4 vv = ld4bf(qkv + (size_t)i * LD + 512 + off);
        ax += e * vv.x; ay += e * vv.y; az += e * vv.z; aw += e * vv.w;
        l += e;
    }
    atomicAdd(&vnum[off + 0], ax);
    atomicAdd(&vnum[off + 1], ay);
    atomicAdd(&vnum[off + 2], az);
    atomicAdd(&vnum[off + 3], aw);
    if (t == 0) atomicAdd(&vden[h], l);
}

__global__ void vn_final_kernel(const float* __restrict__ vnum, const float* __restrict__ vden,
                                u16* __restrict__ araw) {
    int lane = threadIdx.x;
    int h = lane >> 4;
    float inv = 1.0f / (vden[h] + 1e-16f);
    ushort4 o;
    o.x = f2bf(vnum[lane * 4 + 0] * inv);
    o.y = f2bf(vnum[lane * 4 + 1] * inv);
    o.z = f2bf(vnum[lane * 4 + 2] * inv);
    o.w = f2bf(vnum[lane * 4 + 3] * inv);
    *(ushort4*)(araw + fmoff(VN, lane * 4, 256)) = o;
}

// ---------------- layernorm (fused residual + attn-sum), FM bf16 out ----------------
__global__ void ln_kernel(const float* hin, const float* __restrict__ asum,
                          const float* __restrict__ g, const float* __restrict__ b,
                          float* hout, u16* __restrict__ hb) {
    int row = blockIdx.x * 4 + (threadIdx.x >> 6);
    if (row >= NNODES) return;
    int lane = threadIdx.x & 63;
    size_t base = (size_t)row * 256 + lane * 4;
    float4 xv = *(const float4*)(hin + base);
    float4 av = *(const float4*)(asum + base);
    xv.x += av.x; xv.y += av.y; xv.z += av.z; xv.w += av.w;
    float s = xv.x + xv.y + xv.z + xv.w;
#pragma unroll
    for (int o = 1; o < 64; o <<= 1) s += __shfl_xor(s, o);
    float mu = s * (1.0f / 256.0f);
    float dx = xv.x - mu, dy = xv.y - mu, dz = xv.z - mu, dw = xv.w - mu;
    float ss = dx * dx + dy * dy + dz * dz + dw * dw;
#pragma unroll
    for (int o = 1; o < 64; o <<= 1) ss += __shfl_xor(ss, o);
    float var = ss * (1.0f / 256.0f);
    float inv = 1.0f / sqrtf(var + 1e-5f);
    float4 gv = *(const float4*)(g + lane * 4);
    float4 bv = *(const float4*)(b + lane * 4);
    float4 y;
    y.x = dx * inv * gv.x + bv.x;
    y.y = dy * inv * gv.y + bv.y;
    y.z = dz * inv * gv.z + bv.z;
    y.w = dw * inv * gv.w + bv.w;
    *(float4*)(hout + base) = y;
    ushort4 o4;
    o4.x = f2bf(y.x); o4.y = f2bf(y.y); o4.z = f2bf(y.z); o4.w = f2bf(y.w);
    *(ushort4*)(hb + fmoff(row, lane * 4, 256)) = o4;
}

// ---------------- host ----------------

extern "C" void kernel_launch(void* const* d_in, const int* in_sizes, int n_in,
                              void* d_out, int out_size, void* d_ws, size_t ws_size,
                              hipStream_t stream) {
    (void)in_sizes; (void)n_in; (void)out_size; (void)ws_size;
    const float* x        = (const float*)d_in[0];
    const int*   ei       = (const int*)d_in[1];
    const int*   eei      = (const int*)d_in[2];
    const float* Wqkv_loc = (const float*)d_in[3];
    const float* bqkv_loc = (const float*)d_in[4];
    const float* Wo_loc   = (const float*)d_in[5];
    const float* bo_loc   = (const float*)d_in[6];
    const float* Wqkv_exp = (const float*)d_in[7];
    const float* bqkv_exp = (const float*)d_in[8];
    const float* Wo_exp   = (const float*)d_in[9];
    const float* bo_exp   = (const float*)d_in[10];
    const float* ln_g     = (const float*)d_in[11];
    const float* ln_b     = (const float*)d_in[12];
    const float* W1       = (const float*)d_in[13];
    const float* b1       = (const float*)d_in[14];
    const float* W2       = (const float*)d_in[15];
    const float* b2       = (const float*)d_in[16];

    char* wsp = (char*)d_ws;
    size_t off = 0;
    auto carve = [&](size_t bytes) -> void* {
        void* p = wsp + off;
        off += (bytes + 255) & ~(size_t)255;
        return p;
    };
    float* h_f   = (float*)carve((size_t)NNODES * 256 * 4);
    u16*   h_b   = (u16*)carve((size_t)MPAD * 256 * 2);     // fragment-major
    u16*   qkv   = (u16*)carve((size_t)NNODES * 1536 * 2);  // natural; aliased by FM mid
    u16*   araw  = (u16*)carve((size_t)MPAD * 256 * 2);     // fragment-major
    float* aloc  = (float*)carve((size_t)NNODES * 256 * 4); // natural f32 (loc + exp sum)
    u16*   wbf   = (u16*)carve((size_t)3 * 1048576 * 2);    // fragment-major weights
    float* bcat  = (float*)carve((size_t)3 * 1536 * 4);
    int*   cnt   = (int*)carve((size_t)NREAL * 4);
    int*   indptr= (int*)carve((size_t)(NREAL + 1) * 4);
    int*   fill  = (int*)carve((size_t)NREAL * 4);
    int*   srcs  = (int*)carve((size_t)E_EDGES * 4);
    int*   ecnt  = (int*)carve((size_t)NNODES * 4);
    int*   esrcs = (int*)carve((size_t)NNODES * 4 * 4);
    float* svn   = (float*)carve((size_t)NREAL * 4 * 4);
    u32*   menc  = (u32*)carve(4 * 4);
    float* vden  = (float*)carve(4 * 4);
    float* vnum  = (float*)carve(256 * 4);
    u16*   mid   = (u16*)qkv;  // FM(MPAD x 1024) = 41.2 MB fits in qkv's 61.4 MB

    hinit_kernel<<<(NNODES * 64 + 255) / 256, 256, 0, stream>>>(x, h_f, h_b);
    zero_csr_kernel<<<(NNODES + 255) / 256, 256, 0, stream>>>(cnt, fill, ecnt);
    csr_count_kernel<<<(E_EDGES + 255) / 256, 256, 0, stream>>>(ei, cnt);
    csr_scan_kernel<<<1, 256, 0, stream>>>(cnt, indptr);
    csr_scatter_kernel<<<(E_EDGES + 255) / 256, 256, 0, stream>>>(ei, indptr, fill, srcs);
    exp_scatter_kernel<<<(NEXP + 255) / 256, 256, 0, stream>>>(eei, ecnt, esrcs);

    wconv3_kernel<<<(3 * 196608 + 255) / 256, 256, 0, stream>>>(Wqkv_loc, wbf + 0,      256, 768, 1048576);
    wconv3_kernel<<<(3 * 196608 + 255) / 256, 256, 0, stream>>>(Wqkv_exp, wbf + 196608, 256, 768, 1048576);
    wconv3_kernel<<<(3 * 65536  + 255) / 256, 256, 0, stream>>>(Wo_loc,   wbf + 393216, 256, 256, 1048576);
    wconv3_kernel<<<(3 * 65536  + 255) / 256, 256, 0, stream>>>(Wo_exp,   wbf + 458752, 256, 256, 1048576);
    wconv3_kernel<<<(3 * 262144 + 255) / 256, 256, 0, stream>>>(W1,       wbf + 524288, 256, 1024, 1048576);
    wconv3_kernel<<<(3 * 262144 + 255) / 256, 256, 0, stream>>>(W2,       wbf + 786432, 1024, 256, 1048576);
    bcat_kernel<<<18, 256, 0, stream>>>(bqkv_loc, bqkv_exp, bcat);

    const int NBM128 = 160;  // ceil(20001/128)=157, padded to x8
    const int NBM64  = 320;  // ceil(20001/64)=313, padded to x8

    for (int l = 0; l < 3; l++) {
        const u16* wqkvC = wbf + (size_t)l * 1048576 + 0;
        const u16* woL   = wbf + (size_t)l * 1048576 + 393216;
        const u16* woE   = wbf + (size_t)l * 1048576 + 458752;
        const u16* w1T   = wbf + (size_t)l * 1048576 + 524288;
        const u16* w2T   = wbf + (size_t)l * 1048576 + 786432;

        // fused qkv (loc|exp) GEMM: Nout = 1536, natural bf16 output
        gemm_fm<0, 256, 128, 3><<<NBM128 * 12, 256, 0, stream>>>(
            h_b, wqkvC, bcat + l * 1536, qkv, nullptr, nullptr, NNODES, 1536, 12);

        // local attention branch (qkv stride 1536, loc block at +0)
        vn_zero_kernel<<<1, 256, 0, stream>>>(vnum, vden, menc);
        vn_score_kernel<<<80, 256, 0, stream>>>(qkv, 1536, svn, menc);
        vn_accum_kernel<<<80, 256, 0, stream>>>(qkv, 1536, svn, menc, vnum, vden);
        vn_final_kernel<<<1, 64, 0, stream>>>(vnum, vden, araw);
        attn_node_kernel<<<5000, 256, 0, stream>>>(qkv, 1536, indptr, srcs, 0, 1, NREAL, araw);
        gemm_fm<1, 256, 64, 4><<<NBM64 * 2, 256, 0, stream>>>(
            araw, woL, bo_loc + l * 256, nullptr, aloc, nullptr, NNODES, 256, 2);

        // expander attention branch (exp block at +768); WoE accumulates into aloc
        attn_node_kernel<<<5001, 256, 0, stream>>>(qkv + 768, 1536, nullptr, esrcs, 4, 0, NNODES, araw);
        gemm_fm<5, 256, 64, 4><<<NBM64 * 2, 256, 0, stream>>>(
            araw, woE, bo_exp + l * 256, nullptr, aloc, nullptr, NNODES, 256, 2);

        // layernorm(res + attn-sum) -> h_f natural + h_b FM
        ln_kernel<<<(NNODES + 3) / 4, 256, 0, stream>>>(
            h_f, aloc, ln_g + l * 256, ln_b + l * 256, h_f, h_b);

        // FFN: mid = gelu(h@W1+b1) [FM bf16, aliases qkv]; h += mid@W2+b2
        gemm_fm<2, 256, 128, 3><<<NBM128 * 8, 256, 0, stream>>>(
            h_b, w1T, b1 + l * 1024, mid, nullptr, nullptr, NNODES, 1024, 8);
        if (l < 2) {
            gemm_fm<3, 1024, 64, 4><<<NBM64 * 2, 256, 0, stream>>>(
                mid, w2T, b2 + l * 256, h_b, h_f, h_f, NNODES, 256, 2);
        } else {
            gemm_fm<4, 1024, 64, 4><<<NBM64 * 2, 256, 0, stream>>>(
                mid, w2T, b2 + l * 256, nullptr, (float*)d_out, h_f, NNODES, 256, 2);
        }
    }
}

// Round 7
// 1050.441 us; speedup vs baseline: 1.4729x; 1.0304x over previous
//
#include <hip/hip_runtime.h>
#include <stdint.h>

#define NREAL   20000
#define NNODES  20001
#define VN      20000
#define E_EDGES 320000
#define NEXP    80004
#define MPAD    20096   // rows padded to 157*128 for fragment-major buffers

typedef unsigned short u16;
typedef unsigned int   u32;
typedef __bf16 bf16x8 __attribute__((ext_vector_type(8)));
typedef float  f32x4  __attribute__((ext_vector_type(4)));

// fragment-major layout: element (row, col) of an LD-wide matrix lives at
// (row/16)*(16*LD) + (col/8)*128 + (row%16)*8 + (col%8).
__device__ __host__ __forceinline__ size_t fmoff(int row, int col, int LD) {
    return (size_t)(row >> 4) * ((size_t)LD * 16) + (size_t)((col >> 3) * 128)
         + (size_t)((row & 15) * 8) + (size_t)(col & 7);
}

__device__ __forceinline__ float bf2f(u16 v) {
    union { u32 u; float f; } x; x.u = ((u32)v) << 16; return x.f;
}
__device__ __forceinline__ u16 f2bf(float f) {
    union { float f; u32 u; } x; x.f = f;
    u32 r = (x.u + 0x7fffu + ((x.u >> 16) & 1u)) >> 16;
    return (u16)r;
}
__device__ __forceinline__ float4 cvt4(ushort4 u) {
    return make_float4(bf2f(u.x), bf2f(u.y), bf2f(u.z), bf2f(u.w));
}
__device__ __forceinline__ float4 ld4bf(const u16* p) { return cvt4(*(const ushort4*)p); }
__device__ __forceinline__ u32 enc_f(float f) {
    u32 u = __float_as_uint(f);
    return (u & 0x80000000u) ? ~u : (u | 0x80000000u);
}
__device__ __forceinline__ float dec_f(u32 u) {
    u32 v = (u & 0x80000000u) ? (u & 0x7fffffffu) : ~u;
    return __uint_as_float(v);
}

// ---------------- setup kernels ----------------

__global__ void hinit_kernel(const float* __restrict__ x, float* __restrict__ h,
                             u16* __restrict__ hb) {
    int idx = blockIdx.x * 256 + threadIdx.x;
    if (idx >= NNODES * 64) return;
    int row = idx >> 6, c0 = (idx & 63) * 4;
    float4 v = make_float4(0.f, 0.f, 0.f, 0.f);
    if (row < NREAL) v = *(const float4*)(x + (size_t)row * 256 + c0);
    *(float4*)(h + (size_t)row * 256 + c0) = v;
    ushort4 o;
    o.x = f2bf(v.x); o.y = f2bf(v.y); o.z = f2bf(v.z); o.w = f2bf(v.w);
    *(ushort4*)(hb + fmoff(row, c0, 256)) = o;
}

__global__ void zero_csr_kernel(int* cnt, int* fill, int* ecnt) {
    int i = blockIdx.x * 256 + threadIdx.x;
    if (i < NREAL) { cnt[i] = 0; fill[i] = 0; }
    if (i < NNODES) ecnt[i] = 0;
}

__global__ void csr_count_kernel(const int* __restrict__ ei, int* __restrict__ cnt) {
    int e = blockIdx.x * 256 + threadIdx.x;
    if (e < E_EDGES) atomicAdd(&cnt[ei[E_EDGES + e]], 1);
}

__global__ void csr_scan_kernel(const int* __restrict__ cnt, int* __restrict__ indptr) {
    __shared__ int ssum[256];
    int t = threadIdx.x;
    int c0 = t * 79;
    int s = 0;
    for (int j = 0; j < 79; j++) {
        int i = c0 + j;
        if (i < NREAL) s += cnt[i];
    }
    ssum[t] = s;
    __syncthreads();
    for (int d2 = 1; d2 < 256; d2 <<= 1) {
        int v = (t >= d2) ? ssum[t - d2] : 0;
        __syncthreads();
        ssum[t] += v;
        __syncthreads();
    }
    int run = (t == 0) ? 0 : ssum[t - 1];
    for (int j = 0; j < 79; j++) {
        int i = c0 + j;
        if (i < NREAL) { indptr[i] = run; run += cnt[i]; }
    }
    if (t == 255) indptr[NREAL] = run;
}

__global__ void csr_scatter_kernel(const int* __restrict__ ei, const int* __restrict__ indptr,
                                   int* __restrict__ fill, int* __restrict__ srcs) {
    int e = blockIdx.x * 256 + threadIdx.x;
    if (e < E_EDGES) {
        int d = ei[E_EDGES + e];
        int pos = indptr[d] + atomicAdd(&fill[d], 1);
        srcs[pos] = ei[e];
    }
}

__global__ void exp_scatter_kernel(const int* __restrict__ eei, int* __restrict__ ecnt,
                                   int* __restrict__ esrcs) {
    int e = blockIdx.x * 256 + threadIdx.x;
    if (e < NEXP) {
        int d = eei[NEXP + e];
        int pos = atomicAdd(&ecnt[d], 1);
        esrcs[d * 4 + pos] = eei[e];
    }
}

// transpose + bf16 + fragment-major: (L,K,N) float -> per-layer FM(N x K) slabs
__global__ void wconv3_kernel(const float* __restrict__ W, u16* __restrict__ out,
                              int K, int N, int lstride_out) {
    int i = blockIdx.x * 256 + threadIdx.x;
    int per = K * N;
    if (i >= 3 * per) return;
    int l = i / per, r = i - l * per;
    int k = r / N, n = r - k * N;
    out[(size_t)l * lstride_out + fmoff(n, k, K)] = f2bf(W[i]);
}

__global__ void bcat_kernel(const float* __restrict__ bl, const float* __restrict__ be,
                            float* __restrict__ bcat) {
    int i = blockIdx.x * 256 + threadIdx.x;
    if (i >= 3 * 1536) return;
    int l = i / 1536, c = i - l * 1536;
    bcat[i] = (c < 768) ? bl[l * 768 + c] : be[l * 768 + c - 768];
}

// ---------------- GEMM: LDS-free FM loads, transposed-accumulator epilogue ------
// A: FM(M x K); Bt: FM(Nout x K). Tile MT x 128, 4 waves; wave = (MT/2) x 64.
// mfma(weightFrag, actFrag, acc): D col(lane&15) = output ROW, row(q*4+reg) = 4
// consecutive output cols -> packed float4/ushort4 stores. XCD-pinned swizzle.
// EPI: 1 bias->f32 natural; 2 bias->gelu->bf16 FM; 3 bias+resid->f32 + bf16 FM;
//      4 bias+resid->f32 (rows<NREAL); 6 qkv split: q->Q*, k|v->KV* dense buffers

template <int EPI, int K, int MT, int OCC>
__global__ __launch_bounds__(256, OCC) void gemm_fm(
    const u16* __restrict__ A, const u16* __restrict__ Bt, const float* __restrict__ bias,
    u16* Cb, float* Cf, const float* resid,
    u16* Q0, u16* KV0, u16* Q1, u16* KV1,
    int M, int Nout, int nby) {
    constexpr int MFR = MT / 32;
    constexpr int NK = K / 32;
    const int lin = blockIdx.x;
    const int xcd = lin & 7, sub = lin >> 3;
    const int mtile = xcd + 8 * (sub / nby);
    const int ntile = sub - (sub / nby) * nby;
    const int tm = mtile * MT, tn = ntile * 128;
    if (tm >= M) return;

    const int tid = threadIdx.x;
    const int w = tid >> 6, lane = tid & 63;
    const int lm = lane & 15, q = lane >> 4;
    const int mo = (w >> 1) * (MT / 2), no = (w & 1) * 64;

    f32x4 acc[MFR][4];
#pragma unroll
    for (int a = 0; a < MFR; a++)
#pragma unroll
        for (int b = 0; b < 4; b++) acc[a][b] = (f32x4)0.0f;

    const u16* apf[MFR];
    const u16* bpf[4];
#pragma unroll
    for (int t = 0; t < MFR; t++) {
        int p = (tm + mo) / 16 + t;
        apf[t] = A + (size_t)p * (16 * K) + q * 128 + lm * 8;
    }
#pragma unroll
    for (int n = 0; n < 4; n++) {
        int c = (tn + no) / 16 + n;
        bpf[n] = Bt + (size_t)c * (16 * K) + q * 128 + lm * 8;
    }

    bf16x8 curA[MFR], curB[4], nxtA[MFR], nxtB[4];
#pragma unroll
    for (int t = 0; t < MFR; t++) curA[t] = *(const bf16x8*)(apf[t]);
#pragma unroll
    for (int n = 0; n < 4; n++) curB[n] = *(const bf16x8*)(bpf[n]);

#pragma unroll
    for (int i = 0; i < NK; i++) {
        if (i + 1 < NK) {
#pragma unroll
            for (int t = 0; t < MFR; t++) nxtA[t] = *(const bf16x8*)(apf[t] + (i + 1) * 512);
#pragma unroll
            for (int n = 0; n < 4; n++) nxtB[n] = *(const bf16x8*)(bpf[n] + (i + 1) * 512);
        }
#pragma unroll
        for (int mi = 0; mi < MFR; mi++)
#pragma unroll
            for (int ni = 0; ni < 4; ni++)
                acc[mi][ni] = __builtin_amdgcn_mfma_f32_16x16x32_bf16(
                    curB[ni], curA[mi], acc[mi][ni], 0, 0, 0);
        if (i + 1 < NK) {
#pragma unroll
            for (int t = 0; t < MFR; t++) curA[t] = nxtA[t];
#pragma unroll
            for (int n = 0; n < 4; n++) curB[n] = nxtB[n];
        }
    }

    float4 b4[4];
#pragma unroll
    for (int ni = 0; ni < 4; ni++)
        b4[ni] = *(const float4*)(bias + tn + no + ni * 16 + q * 4);

#pragma unroll
    for (int mi = 0; mi < MFR; mi++) {
        int grow = tm + mo + mi * 16 + lm;
        if constexpr (EPI == 4) { if (grow >= NREAL) continue; }
        else                    { if (grow >= M) continue; }
#pragma unroll
        for (int ni = 0; ni < 4; ni++) {
            int gcol = tn + no + ni * 16 + q * 4;
            float v0 = acc[mi][ni][0] + b4[ni].x;
            float v1 = acc[mi][ni][1] + b4[ni].y;
            float v2 = acc[mi][ni][2] + b4[ni].z;
            float v3 = acc[mi][ni][3] + b4[ni].w;
            size_t idx = (size_t)grow * Nout + gcol;
            if constexpr (EPI == 1) {
                *(float4*)(Cf + idx) = make_float4(v0, v1, v2, v3);
            } else if constexpr (EPI == 2) {
                float g0, g1, g2, g3;
                {
                    float u = 0.7978845608f * (v0 + 0.044715f * v0 * v0 * v0);
                    g0 = 0.5f * v0 * (2.0f - 2.0f / (__expf(2.0f * u) + 1.0f));
                }
                {
                    float u = 0.7978845608f * (v1 + 0.044715f * v1 * v1 * v1);
                    g1 = 0.5f * v1 * (2.0f - 2.0f / (__expf(2.0f * u) + 1.0f));
                }
                {
                    float u = 0.7978845608f * (v2 + 0.044715f * v2 * v2 * v2);
                    g2 = 0.5f * v2 * (2.0f - 2.0f / (__expf(2.0f * u) + 1.0f));
                }
                {
                    float u = 0.7978845608f * (v3 + 0.044715f * v3 * v3 * v3);
                    g3 = 0.5f * v3 * (2.0f - 2.0f / (__expf(2.0f * u) + 1.0f));
                }
                ushort4 o;
                o.x = f2bf(g0); o.y = f2bf(g1); o.z = f2bf(g2); o.w = f2bf(g3);
                *(ushort4*)(Cb + fmoff(grow, gcol, Nout)) = o;
            } else if constexpr (EPI == 3) {
                float4 rv = *(const float4*)(resid + idx);
                float o0 = rv.x + v0, o1 = rv.y + v1, o2 = rv.z + v2, o3 = rv.w + v3;
                *(float4*)(Cf + idx) = make_float4(o0, o1, o2, o3);
                ushort4 o;
                o.x = f2bf(o0); o.y = f2bf(o1); o.z = f2bf(o2); o.w = f2bf(o3);
                *(ushort4*)(Cb + fmoff(grow, gcol, Nout)) = o;
            } else if constexpr (EPI == 4) {
                float4 rv = *(const float4*)(resid + idx);
                *(float4*)(Cf + idx) = make_float4(rv.x + v0, rv.y + v1, rv.z + v2, rv.w + v3);
            } else {  // EPI == 6: qkv split-store (Nout = 1536)
                ushort4 o;
                o.x = f2bf(v0); o.y = f2bf(v1); o.z = f2bf(v2); o.w = f2bf(v3);
                u16* dst;
                if (gcol < 256)       dst = Q0  + (size_t)grow * 256 + gcol;
                else if (gcol < 768)  dst = KV0 + (size_t)grow * 512 + (gcol - 256);
                else if (gcol < 1024) dst = Q1  + (size_t)grow * 256 + (gcol - 768);
                else                  dst = KV1 + (size_t)grow * 512 + (gcol - 1024);
                *(ushort4*)dst = o;
            }
        }
    }
}

// ---------------- dual Wo GEMM: two 256x256 GEMMs in one dispatch ----------------
template <int K>
__global__ __launch_bounds__(256, 4) void gemm_wo(
    const u16* __restrict__ A0, const u16* __restrict__ A1,
    const u16* __restrict__ B0, const u16* __restrict__ B1,
    const float* __restrict__ bias0, const float* __restrict__ bias1,
    float* __restrict__ C0, float* __restrict__ C1, int M, int half) {
    constexpr int NK = K / 32;
    const bool second = (int)blockIdx.x >= half;
    const u16* A = second ? A1 : A0;
    const u16* Bt = second ? B1 : B0;
    const float* bias = second ? bias1 : bias0;
    float* Cf = second ? C1 : C0;
    const int lin = (int)blockIdx.x - (second ? half : 0);
    const int xcd = lin & 7, sub = lin >> 3;
    const int mtile = xcd + 8 * (sub >> 1);
    const int ntile = sub & 1;
    const int tm = mtile * 64, tn = ntile * 128;
    if (tm >= M) return;

    const int tid = threadIdx.x;
    const int w = tid >> 6, lane = tid & 63;
    const int lm = lane & 15, q = lane >> 4;
    const int mo = (w >> 1) * 32, no = (w & 1) * 64;

    f32x4 acc[2][4];
#pragma unroll
    for (int a = 0; a < 2; a++)
#pragma unroll
        for (int b = 0; b < 4; b++) acc[a][b] = (f32x4)0.0f;

    const u16* apf[2];
    const u16* bpf[4];
#pragma unroll
    for (int t = 0; t < 2; t++)
        apf[t] = A + (size_t)((tm + mo) / 16 + t) * (16 * K) + q * 128 + lm * 8;
#pragma unroll
    for (int n = 0; n < 4; n++)
        bpf[n] = Bt + (size_t)((tn + no) / 16 + n) * (16 * K) + q * 128 + lm * 8;

    bf16x8 curA[2], curB[4], nxtA[2], nxtB[4];
#pragma unroll
    for (int t = 0; t < 2; t++) curA[t] = *(const bf16x8*)(apf[t]);
#pragma unroll
    for (int n = 0; n < 4; n++) curB[n] = *(const bf16x8*)(bpf[n]);
#pragma unroll
    for (int i = 0; i < NK; i++) {
        if (i + 1 < NK) {
#pragma unroll
            for (int t = 0; t < 2; t++) nxtA[t] = *(const bf16x8*)(apf[t] + (i + 1) * 512);
#pragma unroll
            for (int n = 0; n < 4; n++) nxtB[n] = *(const bf16x8*)(bpf[n] + (i + 1) * 512);
        }
#pragma unroll
        for (int mi = 0; mi < 2; mi++)
#pragma unroll
            for (int ni = 0; ni < 4; ni++)
                acc[mi][ni] = __builtin_amdgcn_mfma_f32_16x16x32_bf16(
                    curB[ni], curA[mi], acc[mi][ni], 0, 0, 0);
        if (i + 1 < NK) {
#pragma unroll
            for (int t = 0; t < 2; t++) curA[t] = nxtA[t];
#pragma unroll
            for (int n = 0; n < 4; n++) curB[n] = nxtB[n];
        }
    }

    float4 b4[4];
#pragma unroll
    for (int ni = 0; ni < 4; ni++)
        b4[ni] = *(const float4*)(bias + tn + no + ni * 16 + q * 4);
#pragma unroll
    for (int mi = 0; mi < 2; mi++) {
        int grow = tm + mo + mi * 16 + lm;
        if (grow >= M) continue;
#pragma unroll
        for (int ni = 0; ni < 4; ni++) {
            int gcol = tn + no + ni * 16 + q * 4;
            size_t idx = (size_t)grow * 256 + gcol;
            *(float4*)(Cf + idx) = make_float4(
                acc[mi][ni][0] + b4[ni].x, acc[mi][ni][1] + b4[ni].y,
                acc[mi][ni][2] + b4[ni].z, acc[mi][ni][3] + b4[ni].w);
        }
    }
}

// ---------------- fused attention (local + expander) ----------------
// One wave per destination node. Blocks cover 20000 local waves then 20001 exp.
// q from dense 512B/row buffer; k|v from dense 1KB/row buffer (DRAM-page friendly).
// Chunk-8 masked online softmax: 16 loads in flight per lane, no tail loop.
__global__ void attn_fused_kernel(const u16* __restrict__ qb_loc, const u16* __restrict__ kv_loc,
                                  const u16* __restrict__ qb_exp, const u16* __restrict__ kv_exp,
                                  const int* __restrict__ indptr, const int* __restrict__ srcs,
                                  const int* __restrict__ esrcs,
                                  u16* __restrict__ araw, u16* __restrict__ araw2) {
    int gw = (int)((blockIdx.x * (size_t)blockDim.x + threadIdx.x) >> 6);
    int lane = threadIdx.x & 63;
    int off = ((lane >> 4) << 6) + (lane & 15) * 4;

    const u16 *qb, *kv;
    const int* sl;
    u16* out;
    int node, beg, deg, tot;
    if (gw < NREAL) {
        node = gw; qb = qb_loc; kv = kv_loc; sl = srcs; out = araw;
        beg = indptr[node]; deg = indptr[node + 1] - beg; tot = deg + 1;  // +vn edge
    } else {
        node = gw - NREAL;
        if (node >= NNODES) return;
        qb = qb_exp; kv = kv_exp; sl = esrcs; out = araw2;
        beg = node * 4; deg = 4; tot = 4;
    }

    float4 qv = ld4bf(qb + (size_t)node * 256 + off);
    float m = -1e30f, l = 0.0f;
    float ax = 0, ay = 0, az = 0, aw = 0;

    for (int e0 = 0; e0 < tot; e0 += 8) {
        ushort4 kraw[8], vraw[8];
#pragma unroll
        for (int j = 0; j < 8; j++) {
            int e = e0 + j;
            int s = (e < deg) ? sl[beg + e] : VN;
            const u16* p = kv + (size_t)s * 512 + off;
            kraw[j] = *(const ushort4*)p;
            vraw[j] = *(const ushort4*)(p + 256);
        }
        float sc[8];
#pragma unroll
        for (int j = 0; j < 8; j++) {
            float4 k4 = cvt4(kraw[j]);
            float p = qv.x * k4.x + qv.y * k4.y + qv.z * k4.z + qv.w * k4.w;
            p += __shfl_xor(p, 1); p += __shfl_xor(p, 2);
            p += __shfl_xor(p, 4); p += __shfl_xor(p, 8);
            sc[j] = (e0 + j < tot) ? p * 0.125f : -1e30f;
        }
        float cmax = fmaxf(fmaxf(fmaxf(sc[0], sc[1]), fmaxf(sc[2], sc[3])),
                           fmaxf(fmaxf(sc[4], sc[5]), fmaxf(sc[6], sc[7])));
        float mn = fmaxf(m, cmax);
        float fold = __expf(m - mn);
        ax *= fold; ay *= fold; az *= fold; aw *= fold; l *= fold;
#pragma unroll
        for (int j = 0; j < 8; j++) {
            float ee = __expf(sc[j] - mn);
            float4 v4 = cvt4(vraw[j]);
            ax += v4.x * ee; ay += v4.y * ee; az += v4.z * ee; aw += v4.w * ee;
            l += ee;
        }
        m = mn;
    }
    float inv = 1.0f / (l + 1e-16f);
    ushort4 o;
    o.x = f2bf(ax * inv); o.y = f2bf(ay * inv);
    o.z = f2bf(az * inv); o.w = f2bf(aw * inv);
    *(ushort4*)(out + fmoff(node, off, 256)) = o;
}

// virtual node (dst = VN), dense 3-phase
__global__ void vn_zero_kernel(float* vnum, float* vden, u32* menc) {
    int t = threadIdx.x;
    vnum[t] = 0.0f;
    if (t < 4) { vden[t] = 0.0f; menc[t] = enc_f(-1e30f); }
}

__global__ void vn_score_kernel(const u16* __restrict__ qb, const u16* __restrict__ kv,
                                float* __restrict__ svn, u32* __restrict__ menc) {
    int lane = threadIdx.x & 63;
    int h = lane >> 4, t = lane & 15;
    int off = h * 64 + t * 4;
    float4 qv = ld4bf(qb + (size_t)VN * 256 + off);
    int wid = (int)((blockIdx.x * (size_t)blockDim.x + threadIdx.x) >> 6);
    int nw = (gridDim.x * blockDim.x) >> 6;
    float wmax = -1e30f;
    for (int i = wid; i < NREAL; i += nw) {
        float4 kvv = ld4bf(kv + (size_t)i * 512 + off);
        float p = qv.x * kvv.x + qv.y * kvv.y + qv.z * kvv.z + qv.w * kvv.w;
        p += __shfl_xor(p, 1); p += __shfl_xor(p, 2);
        p += __shfl_xor(p, 4); p += __shfl_xor(p, 8);
        float sc = p * 0.125f;
        if (t == 0) svn[i * 4 + h] = sc;
        wmax = fmaxf(wmax, sc);
    }
    if (t == 0) atomicMax(&menc[h], enc_f(wmax));
}

__global__ void vn_accum_kernel(const u16* __restrict__ kv, const float* __restrict__ svn,
                                const u32* __restrict__ menc, float* __restrict__ vnum,
                                float* __restrict__ vden) {
    int lane = threadIdx.x & 63;
    int h = lane >> 4, t = lane & 15;
    int off = h * 64 + t * 4;
    float m = dec_f(menc[h]);
    int wid = (int)((blockIdx.x * (size_t)blockDim.x + threadIdx.x) >> 6);
    int nw = (gridDim.x * blockDim.x) >> 6;
    float ax = 0, ay = 0, az = 0, aw = 0, l = 0;
    for (int i = wid; i < NREAL; i += nw) {
        float e = __expf(svn[i * 4 + h] - m);
        float4 vv = ld4bf(kv + (size_t)i * 512 + 256 + off);
        ax += e * vv.x; ay += e * vv.y; az += e * vv.z; aw += e * vv.w;
        l += e;
    }
    atomicAdd(&vnum[off + 0], ax);
    atomicAdd(&vnum[off + 1], ay);
    atomicAdd(&vnum[off + 2], az);
    atomicAdd(&vnum[off + 3], aw);
    if (t == 0) atomicAdd(&vden[h], l);
}

__global__ void vn_final_kernel(const float* __restrict__ vnum, const float* __restrict__ vden,
                                u16* __restrict__ araw) {
    int lane = threadIdx.x;
    int h = lane >> 4;
    float inv = 1.0f / (vden[h] + 1e-16f);
    ushort4 o;
    o.x = f2bf(vnum[lane * 4 + 0] * inv);
    o.y = f2bf(vnum[lane * 4 + 1] * inv);
    o.z = f2bf(vnum[lane * 4 + 2] * inv);
    o.w = f2bf(vnum[lane * 4 + 3] * inv);
    *(ushort4*)(araw + fmoff(VN, lane * 4, 256)) = o;
}

// ---------------- layernorm (fused residual + loc + exp), FM bf16 out ----------------
__global__ void ln_kernel(const float* hin, const float* __restrict__ aloc,
                          const float* __restrict__ aexp, const float* __restrict__ g,
                          const float* __restrict__ b, float* hout, u16* __restrict__ hb) {
    int row = blockIdx.x * 4 + (threadIdx.x >> 6);
    if (row >= NNODES) return;
    int lane = threadIdx.x & 63;
    size_t base = (size_t)row * 256 + lane * 4;
    float4 xv = *(const float4*)(hin + base);
    float4 av = *(const float4*)(aloc + base);
    float4 ev = *(const float4*)(aexp + base);
    xv.x += av.x + ev.x; xv.y += av.y + ev.y;
    xv.z += av.z + ev.z; xv.w += av.w + ev.w;
    float s = xv.x + xv.y + xv.z + xv.w;
#pragma unroll
    for (int o = 1; o < 64; o <<= 1) s += __shfl_xor(s, o);
    float mu = s * (1.0f / 256.0f);
    float dx = xv.x - mu, dy = xv.y - mu, dz = xv.z - mu, dw = xv.w - mu;
    float ss = dx * dx + dy * dy + dz * dz + dw * dw;
#pragma unroll
    for (int o = 1; o < 64; o <<= 1) ss += __shfl_xor(ss, o);
    float var = ss * (1.0f / 256.0f);
    float inv = 1.0f / sqrtf(var + 1e-5f);
    float4 gv = *(const float4*)(g + lane * 4);
    float4 bv = *(const float4*)(b + lane * 4);
    float4 y;
    y.x = dx * inv * gv.x + bv.x;
    y.y = dy * inv * gv.y + bv.y;
    y.z = dz * inv * gv.z + bv.z;
    y.w = dw * inv * gv.w + bv.w;
    *(float4*)(hout + base) = y;
    ushort4 o4;
    o4.x = f2bf(y.x); o4.y = f2bf(y.y); o4.z = f2bf(y.z); o4.w = f2bf(y.w);
    *(ushort4*)(hb + fmoff(row, lane * 4, 256)) = o4;
}

// ---------------- host ----------------

extern "C" void kernel_launch(void* const* d_in, const int* in_sizes, int n_in,
                              void* d_out, int out_size, void* d_ws, size_t ws_size,
                              hipStream_t stream) {
    (void)in_sizes; (void)n_in; (void)out_size; (void)ws_size;
    const float* x        = (const float*)d_in[0];
    const int*   ei       = (const int*)d_in[1];
    const int*   eei      = (const int*)d_in[2];
    const float* Wqkv_loc = (const float*)d_in[3];
    const float* bqkv_loc = (const float*)d_in[4];
    const float* Wo_loc   = (const float*)d_in[5];
    const float* bo_loc   = (const float*)d_in[6];
    const float* Wqkv_exp = (const float*)d_in[7];
    const float* bqkv_exp = (const float*)d_in[8];
    const float* Wo_exp   = (const float*)d_in[9];
    const float* bo_exp   = (const float*)d_in[10];
    const float* ln_g     = (const float*)d_in[11];
    const float* ln_b     = (const float*)d_in[12];
    const float* W1       = (const float*)d_in[13];
    const float* b1       = (const float*)d_in[14];
    const float* W2       = (const float*)d_in[15];
    const float* b2       = (const float*)d_in[16];

    char* wsp = (char*)d_ws;
    size_t off = 0;
    auto carve = [&](size_t bytes) -> void* {
        void* p = wsp + off;
        off += (bytes + 255) & ~(size_t)255;
        return p;
    };
    float* h_f    = (float*)carve((size_t)NNODES * 256 * 4);
    u16*   h_b    = (u16*)carve((size_t)MPAD * 256 * 2);      // FM
    u16*   qb_loc = (u16*)carve((size_t)NNODES * 256 * 2);    // dense q, 512B/row
    u16*   kv_loc = (u16*)carve((size_t)NNODES * 512 * 2);    // dense k|v, 1KB/row
    u16*   qb_exp = (u16*)carve((size_t)NNODES * 256 * 2);
    u16*   kv_exp = (u16*)carve((size_t)NNODES * 512 * 2);
    u16*   araw   = (u16*)carve((size_t)MPAD * 256 * 2);      // FM
    u16*   araw2  = (u16*)carve((size_t)MPAD * 256 * 2);      // FM
    float* aloc   = (float*)carve((size_t)NNODES * 256 * 4);
    float* aexp   = (float*)carve((size_t)NNODES * 256 * 4);
    u16*   wbf    = (u16*)carve((size_t)3 * 1048576 * 2);     // FM weights
    float* bcat   = (float*)carve((size_t)3 * 1536 * 4);
    int*   cnt    = (int*)carve((size_t)NREAL * 4);
    int*   indptr = (int*)carve((size_t)(NREAL + 1) * 4);
    int*   fill   = (int*)carve((size_t)NREAL * 4);
    int*   srcs   = (int*)carve((size_t)E_EDGES * 4);
    int*   ecnt   = (int*)carve((size_t)NNODES * 4);
    int*   esrcs  = (int*)carve((size_t)NNODES * 4 * 4);
    float* svn    = (float*)carve((size_t)NREAL * 4 * 4);
    u32*   menc   = (u32*)carve(4 * 4);
    float* vden   = (float*)carve(4 * 4);
    float* vnum   = (float*)carve(256 * 4);
    u16*   mid    = qb_loc;  // FM(MPAD x 1024) = 41.2 MB aliases qb_loc..kv_exp (61.5 MB)

    hinit_kernel<<<(NNODES * 64 + 255) / 256, 256, 0, stream>>>(x, h_f, h_b);
    zero_csr_kernel<<<(NNODES + 255) / 256, 256, 0, stream>>>(cnt, fill, ecnt);
    csr_count_kernel<<<(E_EDGES + 255) / 256, 256, 0, stream>>>(ei, cnt);
    csr_scan_kernel<<<1, 256, 0, stream>>>(cnt, indptr);
    csr_scatter_kernel<<<(E_EDGES + 255) / 256, 256, 0, stream>>>(ei, indptr, fill, srcs);
    exp_scatter_kernel<<<(NEXP + 255) / 256, 256, 0, stream>>>(eei, ecnt, esrcs);

    wconv3_kernel<<<(3 * 196608 + 255) / 256, 256, 0, stream>>>(Wqkv_loc, wbf + 0,      256, 768, 1048576);
    wconv3_kernel<<<(3 * 196608 + 255) / 256, 256, 0, stream>>>(Wqkv_exp, wbf + 196608, 256, 768, 1048576);
    wconv3_kernel<<<(3 * 65536  + 255) / 256, 256, 0, stream>>>(Wo_loc,   wbf + 393216, 256, 256, 1048576);
    wconv3_kernel<<<(3 * 65536  + 255) / 256, 256, 0, stream>>>(Wo_exp,   wbf + 458752, 256, 256, 1048576);
    wconv3_kernel<<<(3 * 262144 + 255) / 256, 256, 0, stream>>>(W1,       wbf + 524288, 256, 1024, 1048576);
    wconv3_kernel<<<(3 * 262144 + 255) / 256, 256, 0, stream>>>(W2,       wbf + 786432, 1024, 256, 1048576);
    bcat_kernel<<<18, 256, 0, stream>>>(bqkv_loc, bqkv_exp, bcat);

    const int NBM128 = 160;  // ceil(20001/128) padded to x8
    const int NBM64  = 320;  // ceil(20001/64)  padded to x8

    for (int l = 0; l < 3; l++) {
        const u16* wqkvC = wbf + (size_t)l * 1048576 + 0;
        const u16* woL   = wbf + (size_t)l * 1048576 + 393216;
        const u16* woE   = wbf + (size_t)l * 1048576 + 458752;
        const u16* w1T   = wbf + (size_t)l * 1048576 + 524288;
        const u16* w2T   = wbf + (size_t)l * 1048576 + 786432;

        // fused qkv GEMM (loc|exp), split-store into dense q / k|v buffers
        gemm_fm<6, 256, 128, 3><<<NBM128 * 12, 256, 0, stream>>>(
            h_b, wqkvC, bcat + l * 1536, nullptr, nullptr, nullptr,
            qb_loc, kv_loc, qb_exp, kv_exp, NNODES, 1536, 12);

        // virtual-node dense attention (3-phase)
        vn_zero_kernel<<<1, 256, 0, stream>>>(vnum, vden, menc);
        vn_score_kernel<<<80, 256, 0, stream>>>(qb_loc, kv_loc, svn, menc);
        vn_accum_kernel<<<80, 256, 0, stream>>>(kv_loc, svn, menc, vnum, vden);
        vn_final_kernel<<<1, 64, 0, stream>>>(vnum, vden, araw);

        // fused local + expander edge attention
        attn_fused_kernel<<<10001, 256, 0, stream>>>(
            qb_loc, kv_loc, qb_exp, kv_exp, indptr, srcs, esrcs, araw, araw2);

        // dual Wo GEMM (loc -> aloc, exp -> aexp)
        gemm_wo<256><<<NBM64 * 2 * 2, 256, 0, stream>>>(
            araw, araw2, woL, woE, bo_loc + l * 256, bo_exp + l * 256,
            aloc, aexp, NNODES, NBM64 * 2);

        // layernorm(res + loc + exp) -> h_f natural + h_b FM
        ln_kernel<<<(NNODES + 3) / 4, 256, 0, stream>>>(
            h_f, aloc, aexp, ln_g + l * 256, ln_b + l * 256, h_f, h_b);

        // FFN: mid = gelu(h@W1+b1) [FM bf16, aliases q/kv bufs]; h += mid@W2+b2
        gemm_fm<2, 256, 128, 3><<<NBM128 * 8, 256, 0, stream>>>(
            h_b, w1T, b1 + l * 1024, mid, nullptr, nullptr,
            nullptr, nullptr, nullptr, nullptr, NNODES, 1024, 8);
        if (l < 2) {
            gemm_fm<3, 1024, 64, 4><<<NBM64 * 2, 256, 0, stream>>>(
                mid, w2T, b2 + l * 256, h_b, h_f, h_f,
                nullptr, nullptr, nullptr, nullptr, NNODES, 256, 2);
        } else {
            gemm_fm<4, 1024, 64, 4><<<NBM64 * 2, 256, 0, stream>>>(
                mid, w2T, b2 + l * 256, nullptr, (float*)d_out, h_f,
                nullptr, nullptr, nullptr, nullptr, NNODES, 256, 2);
        }
    }
}

// Round 8
// 1047.202 us; speedup vs baseline: 1.4775x; 1.0031x over previous
//
#include <hip/hip_runtime.h>
#include <stdint.h>

#define NREAL   20000
#define NNODES  20001
#define VN      20000
#define E_EDGES 320000
#define NEXP    80004
#define MPAD    20096   // rows padded to 157*128 for fragment-major buffers

typedef unsigned short u16;
typedef unsigned int   u32;
typedef __bf16 bf16x8 __attribute__((ext_vector_type(8)));
typedef float  f32x4  __attribute__((ext_vector_type(4)));

// fragment-major layout: element (row, col) of an LD-wide matrix lives at
// (row/16)*(16*LD) + (col/8)*128 + (row%16)*8 + (col%8).
__device__ __host__ __forceinline__ size_t fmoff(int row, int col, int LD) {
    return (size_t)(row >> 4) * ((size_t)LD * 16) + (size_t)((col >> 3) * 128)
         + (size_t)((row & 15) * 8) + (size_t)(col & 7);
}

__device__ __forceinline__ float bf2f(u16 v) {
    union { u32 u; float f; } x; x.u = ((u32)v) << 16; return x.f;
}
__device__ __forceinline__ u16 f2bf(float f) {
    union { float f; u32 u; } x; x.f = f;
    u32 r = (x.u + 0x7fffu + ((x.u >> 16) & 1u)) >> 16;
    return (u16)r;
}
__device__ __forceinline__ float4 cvt4(ushort4 u) {
    return make_float4(bf2f(u.x), bf2f(u.y), bf2f(u.z), bf2f(u.w));
}
__device__ __forceinline__ float4 ld4bf(const u16* p) { return cvt4(*(const ushort4*)p); }
__device__ __forceinline__ u32 enc_f(float f) {
    u32 u = __float_as_uint(f);
    return (u & 0x80000000u) ? ~u : (u | 0x80000000u);
}
__device__ __forceinline__ float dec_f(u32 u) {
    u32 v = (u & 0x80000000u) ? (u & 0x7fffffffu) : ~u;
    return __uint_as_float(v);
}

// ---------------- setup kernels ----------------

__global__ void hinit_kernel(const float* __restrict__ x, float* __restrict__ h,
                             u16* __restrict__ hb) {
    int idx = blockIdx.x * 256 + threadIdx.x;
    if (idx >= NNODES * 64) return;
    int row = idx >> 6, c0 = (idx & 63) * 4;
    float4 v = make_float4(0.f, 0.f, 0.f, 0.f);
    if (row < NREAL) v = *(const float4*)(x + (size_t)row * 256 + c0);
    *(float4*)(h + (size_t)row * 256 + c0) = v;
    ushort4 o;
    o.x = f2bf(v.x); o.y = f2bf(v.y); o.z = f2bf(v.z); o.w = f2bf(v.w);
    *(ushort4*)(hb + fmoff(row, c0, 256)) = o;
}

// zero CSR state + concat qkv biases + init vn accumulators (once per call)
__global__ void init_kernel(int* cnt, int* fill, int* ecnt,
                            const float* __restrict__ bl, const float* __restrict__ be,
                            float* __restrict__ bcat,
                            float* vnum, float* vden, u32* menc) {
    int i = blockIdx.x * 256 + threadIdx.x;
    if (i < NREAL) { cnt[i] = 0; fill[i] = 0; }
    if (i < NNODES) ecnt[i] = 0;
    if (i < 3 * 1536) {
        int l = i / 1536, c = i - l * 1536;
        bcat[i] = (c < 768) ? bl[l * 768 + c] : be[l * 768 + c - 768];
    }
    if (i < 256) vnum[i] = 0.0f;
    if (i < 4) { vden[i] = 0.0f; menc[i] = enc_f(-1e30f); }
}

__global__ void csr_count_kernel(const int* __restrict__ ei, int* __restrict__ cnt) {
    int e = blockIdx.x * 256 + threadIdx.x;
    if (e < E_EDGES) atomicAdd(&cnt[ei[E_EDGES + e]], 1);
}

__global__ void csr_scan_kernel(const int* __restrict__ cnt, int* __restrict__ indptr) {
    __shared__ int ssum[256];
    int t = threadIdx.x;
    int c0 = t * 79;
    int s = 0;
    for (int j = 0; j < 79; j++) {
        int i = c0 + j;
        if (i < NREAL) s += cnt[i];
    }
    ssum[t] = s;
    __syncthreads();
    for (int d2 = 1; d2 < 256; d2 <<= 1) {
        int v = (t >= d2) ? ssum[t - d2] : 0;
        __syncthreads();
        ssum[t] += v;
        __syncthreads();
    }
    int run = (t == 0) ? 0 : ssum[t - 1];
    for (int j = 0; j < 79; j++) {
        int i = c0 + j;
        if (i < NREAL) { indptr[i] = run; run += cnt[i]; }
    }
    if (t == 255) indptr[NREAL] = run;
}

__global__ void csr_scatter_kernel(const int* __restrict__ ei, const int* __restrict__ indptr,
                                   int* __restrict__ fill, int* __restrict__ srcs) {
    int e = blockIdx.x * 256 + threadIdx.x;
    if (e < E_EDGES) {
        int d = ei[E_EDGES + e];
        int pos = indptr[d] + atomicAdd(&fill[d], 1);
        srcs[pos] = ei[e];
    }
}

__global__ void exp_scatter_kernel(const int* __restrict__ eei, int* __restrict__ ecnt,
                                   int* __restrict__ esrcs) {
    int e = blockIdx.x * 256 + threadIdx.x;
    if (e < NEXP) {
        int d = eei[NEXP + e];
        int pos = atomicAdd(&ecnt[d], 1);
        esrcs[d * 4 + pos] = eei[e];
    }
}

// ALL weights -> bf16 fragment-major, one launch. Per-layer slab 1048576 u16:
// [0] WqkvL(256x768) [196608] WqkvE [393216] WoL(256x256) [458752] WoE
// [524288] W1(256x1024) [786432] W2(1024x256)
__global__ void wconv_all_kernel(const float* __restrict__ WqkvL, const float* __restrict__ WqkvE,
                                 const float* __restrict__ WoL, const float* __restrict__ WoE,
                                 const float* __restrict__ W1, const float* __restrict__ W2,
                                 u16* __restrict__ out) {
    int i = blockIdx.x * 256 + threadIdx.x;
    if (i >= 3 * 1048576) return;
    int l = i / 1048576, r = i - l * 1048576;
    const float* src; int K, N; int base;
    if (r < 196608)      { src = WqkvL; K = 256;  N = 768;  base = 0; }
    else if (r < 393216) { src = WqkvE; K = 256;  N = 768;  base = 196608; }
    else if (r < 458752) { src = WoL;   K = 256;  N = 256;  base = 393216; }
    else if (r < 524288) { src = WoE;   K = 256;  N = 256;  base = 458752; }
    else if (r < 786432) { src = W1;    K = 256;  N = 1024; base = 524288; }
    else                 { src = W2;    K = 1024; N = 256;  base = 786432; }
    int r2 = r - base;
    int k = r2 / N, n = r2 - k * N;
    out[(size_t)l * 1048576 + base + fmoff(n, k, K)] = f2bf(src[(size_t)l * K * N + r2]);
}

// ---------------- GEMM: LDS-free FM loads, distance-2 register pipeline ----------
// A: FM(M x K); Bt: FM(Nout x K). Tile MT x 128, 4 waves; wave = (MT/2) x 64.
// mfma(weightFrag, actFrag, acc): D col(lane&15) = output ROW, row(q*4+reg) = 4
// consecutive output cols -> packed float4/ushort4 stores. XCD-pinned swizzle.
// EPI: 1 bias->f32; 2 bias->gelu->bf16 FM; 3 bias+resid->f32 + bf16 FM;
//      4 bias+resid->f32 (rows<NREAL); 6 qkv split-store

template <int EPI, int K, int MT>
__global__ __launch_bounds__(256) void gemm_fm(
    const u16* __restrict__ A, const u16* __restrict__ Bt, const float* __restrict__ bias,
    u16* Cb, float* Cf, const float* resid,
    u16* Q0, u16* KV0, u16* Q1, u16* KV1,
    int M, int Nout, int nby) {
    constexpr int MFR = MT / 32;
    constexpr int NK = K / 32;
    const int lin = blockIdx.x;
    const int xcd = lin & 7, sub = lin >> 3;
    const int mtile = xcd + 8 * (sub / nby);
    const int ntile = sub - (sub / nby) * nby;
    const int tm = mtile * MT, tn = ntile * 128;
    if (tm >= M) return;

    const int tid = threadIdx.x;
    const int w = tid >> 6, lane = tid & 63;
    const int lm = lane & 15, q = lane >> 4;
    const int mo = (w >> 1) * (MT / 2), no = (w & 1) * 64;

    f32x4 acc[MFR][4];
#pragma unroll
    for (int a = 0; a < MFR; a++)
#pragma unroll
        for (int b = 0; b < 4; b++) acc[a][b] = (f32x4)0.0f;

    const u16* apf[MFR];
    const u16* bpf[4];
#pragma unroll
    for (int t = 0; t < MFR; t++) {
        int p = (tm + mo) / 16 + t;
        apf[t] = A + (size_t)p * (16 * K) + q * 128 + lm * 8;
    }
#pragma unroll
    for (int n = 0; n < 4; n++) {
        int c = (tn + no) / 16 + n;
        bpf[n] = Bt + (size_t)c * (16 * K) + q * 128 + lm * 8;
    }

    // distance-2 prefetch: 3-slot rotation, fully unrolled so slots become SSA
    bf16x8 sA[3][MFR], sB[3][4];
#pragma unroll
    for (int s = 0; s < 2 && s < NK; s++) {
#pragma unroll
        for (int t = 0; t < MFR; t++) sA[s][t] = *(const bf16x8*)(apf[t] + s * 512);
#pragma unroll
        for (int n = 0; n < 4; n++) sB[s][n] = *(const bf16x8*)(bpf[n] + s * 512);
    }
#pragma unroll
    for (int i = 0; i < NK; i++) {
        const int cu = i % 3, pf = (i + 2) % 3;
        if (i + 2 < NK) {
#pragma unroll
            for (int t = 0; t < MFR; t++) sA[pf][t] = *(const bf16x8*)(apf[t] + (i + 2) * 512);
#pragma unroll
            for (int n = 0; n < 4; n++) sB[pf][n] = *(const bf16x8*)(bpf[n] + (i + 2) * 512);
        }
#pragma unroll
        for (int mi = 0; mi < MFR; mi++)
#pragma unroll
            for (int ni = 0; ni < 4; ni++)
                acc[mi][ni] = __builtin_amdgcn_mfma_f32_16x16x32_bf16(
                    sB[cu][ni], sA[cu][mi], acc[mi][ni], 0, 0, 0);
    }

    float4 b4[4];
#pragma unroll
    for (int ni = 0; ni < 4; ni++)
        b4[ni] = *(const float4*)(bias + tn + no + ni * 16 + q * 4);

#pragma unroll
    for (int mi = 0; mi < MFR; mi++) {
        int grow = tm + mo + mi * 16 + lm;
        if constexpr (EPI == 4) { if (grow >= NREAL) continue; }
        else                    { if (grow >= M) continue; }
#pragma unroll
        for (int ni = 0; ni < 4; ni++) {
            int gcol = tn + no + ni * 16 + q * 4;
            float v0 = acc[mi][ni][0] + b4[ni].x;
            float v1 = acc[mi][ni][1] + b4[ni].y;
            float v2 = acc[mi][ni][2] + b4[ni].z;
            float v3 = acc[mi][ni][3] + b4[ni].w;
            size_t idx = (size_t)grow * Nout + gcol;
            if constexpr (EPI == 1) {
                *(float4*)(Cf + idx) = make_float4(v0, v1, v2, v3);
            } else if constexpr (EPI == 2) {
                float g0, g1, g2, g3;
                {
                    float u = 0.7978845608f * (v0 + 0.044715f * v0 * v0 * v0);
                    g0 = 0.5f * v0 * (2.0f - 2.0f / (__expf(2.0f * u) + 1.0f));
                }
                {
                    float u = 0.7978845608f * (v1 + 0.044715f * v1 * v1 * v1);
                    g1 = 0.5f * v1 * (2.0f - 2.0f / (__expf(2.0f * u) + 1.0f));
                }
                {
                    float u = 0.7978845608f * (v2 + 0.044715f * v2 * v2 * v2);
                    g2 = 0.5f * v2 * (2.0f - 2.0f / (__expf(2.0f * u) + 1.0f));
                }
                {
                    float u = 0.7978845608f * (v3 + 0.044715f * v3 * v3 * v3);
                    g3 = 0.5f * v3 * (2.0f - 2.0f / (__expf(2.0f * u) + 1.0f));
                }
                ushort4 o;
                o.x = f2bf(g0); o.y = f2bf(g1); o.z = f2bf(g2); o.w = f2bf(g3);
                *(ushort4*)(Cb + fmoff(grow, gcol, Nout)) = o;
            } else if constexpr (EPI == 3) {
                float4 rv = *(const float4*)(resid + idx);
                float o0 = rv.x + v0, o1 = rv.y + v1, o2 = rv.z + v2, o3 = rv.w + v3;
                *(float4*)(Cf + idx) = make_float4(o0, o1, o2, o3);
                ushort4 o;
                o.x = f2bf(o0); o.y = f2bf(o1); o.z = f2bf(o2); o.w = f2bf(o3);
                *(ushort4*)(Cb + fmoff(grow, gcol, Nout)) = o;
            } else if constexpr (EPI == 4) {
                float4 rv = *(const float4*)(resid + idx);
                *(float4*)(Cf + idx) = make_float4(rv.x + v0, rv.y + v1, rv.z + v2, rv.w + v3);
            } else {  // EPI == 6: qkv split-store (Nout = 1536)
                ushort4 o;
                o.x = f2bf(v0); o.y = f2bf(v1); o.z = f2bf(v2); o.w = f2bf(v3);
                u16* dst;
                if (gcol < 256)       dst = Q0  + (size_t)grow * 256 + gcol;
                else if (gcol < 768)  dst = KV0 + (size_t)grow * 512 + (gcol - 256);
                else if (gcol < 1024) dst = Q1  + (size_t)grow * 256 + (gcol - 768);
                else                  dst = KV1 + (size_t)grow * 512 + (gcol - 1024);
                *(ushort4*)dst = o;
            }
        }
    }
}

// ---------------- dual Wo GEMM: two 256x256 GEMMs in one dispatch ----------------
template <int K>
__global__ __launch_bounds__(256) void gemm_wo(
    const u16* __restrict__ A0, const u16* __restrict__ A1,
    const u16* __restrict__ B0, const u16* __restrict__ B1,
    const float* __restrict__ bias0, const float* __restrict__ bias1,
    float* __restrict__ C0, float* __restrict__ C1, int M, int half) {
    constexpr int NK = K / 32;
    const bool second = (int)blockIdx.x >= half;
    const u16* A = second ? A1 : A0;
    const u16* Bt = second ? B1 : B0;
    const float* bias = second ? bias1 : bias0;
    float* Cf = second ? C1 : C0;
    const int lin = (int)blockIdx.x - (second ? half : 0);
    const int xcd = lin & 7, sub = lin >> 3;
    const int mtile = xcd + 8 * (sub >> 1);
    const int ntile = sub & 1;
    const int tm = mtile * 64, tn = ntile * 128;
    if (tm >= M) return;

    const int tid = threadIdx.x;
    const int w = tid >> 6, lane = tid & 63;
    const int lm = lane & 15, q = lane >> 4;
    const int mo = (w >> 1) * 32, no = (w & 1) * 64;

    f32x4 acc[2][4];
#pragma unroll
    for (int a = 0; a < 2; a++)
#pragma unroll
        for (int b = 0; b < 4; b++) acc[a][b] = (f32x4)0.0f;

    const u16* apf[2];
    const u16* bpf[4];
#pragma unroll
    for (int t = 0; t < 2; t++)
        apf[t] = A + (size_t)((tm + mo) / 16 + t) * (16 * K) + q * 128 + lm * 8;
#pragma unroll
    for (int n = 0; n < 4; n++)
        bpf[n] = Bt + (size_t)((tn + no) / 16 + n) * (16 * K) + q * 128 + lm * 8;

    bf16x8 sA[3][2], sB[3][4];
#pragma unroll
    for (int s = 0; s < 2; s++) {
#pragma unroll
        for (int t = 0; t < 2; t++) sA[s][t] = *(const bf16x8*)(apf[t] + s * 512);
#pragma unroll
        for (int n = 0; n < 4; n++) sB[s][n] = *(const bf16x8*)(bpf[n] + s * 512);
    }
#pragma unroll
    for (int i = 0; i < NK; i++) {
        const int cu = i % 3, pf = (i + 2) % 3;
        if (i + 2 < NK) {
#pragma unroll
            for (int t = 0; t < 2; t++) sA[pf][t] = *(const bf16x8*)(apf[t] + (i + 2) * 512);
#pragma unroll
            for (int n = 0; n < 4; n++) sB[pf][n] = *(const bf16x8*)(bpf[n] + (i + 2) * 512);
        }
#pragma unroll
        for (int mi = 0; mi < 2; mi++)
#pragma unroll
            for (int ni = 0; ni < 4; ni++)
                acc[mi][ni] = __builtin_amdgcn_mfma_f32_16x16x32_bf16(
                    sB[cu][ni], sA[cu][mi], acc[mi][ni], 0, 0, 0);
    }

    float4 b4[4];
#pragma unroll
    for (int ni = 0; ni < 4; ni++)
        b4[ni] = *(const float4*)(bias + tn + no + ni * 16 + q * 4);
#pragma unroll
    for (int mi = 0; mi < 2; mi++) {
        int grow = tm + mo + mi * 16 + lm;
        if (grow >= M) continue;
#pragma unroll
        for (int ni = 0; ni < 4; ni++) {
            int gcol = tn + no + ni * 16 + q * 4;
            size_t idx = (size_t)grow * 256 + gcol;
            *(float4*)(Cf + idx) = make_float4(
                acc[mi][ni][0] + b4[ni].x, acc[mi][ni][1] + b4[ni].y,
                acc[mi][ni][2] + b4[ni].z, acc[mi][ni][3] + b4[ni].w);
        }
    }
}

// ---------------- fused attention (local + expander + vn-finalize) ----------------
// One wave per destination node. gw<NREAL: local; gw<NREAL+NNODES: expander;
// gw==NREAL+NNODES: vn-finalize wave (writes araw[VN], resets vn accumulators).
__global__ void attn_fused_kernel(const u16* __restrict__ qb_loc, const u16* __restrict__ kv_loc,
                                  const u16* __restrict__ qb_exp, const u16* __restrict__ kv_exp,
                                  const int* __restrict__ indptr, const int* __restrict__ srcs,
                                  const int* __restrict__ esrcs,
                                  float* __restrict__ vnum, float* __restrict__ vden,
                                  u32* __restrict__ menc,
                                  u16* __restrict__ araw, u16* __restrict__ araw2) {
    int gw = (int)((blockIdx.x * (size_t)blockDim.x + threadIdx.x) >> 6);
    int lane = threadIdx.x & 63;
    int off = ((lane >> 4) << 6) + (lane & 15) * 4;

    const u16 *qb, *kv;
    const int* sl;
    u16* out;
    int node, beg, deg, tot;
    if (gw < NREAL) {
        node = gw; qb = qb_loc; kv = kv_loc; sl = srcs; out = araw;
        beg = indptr[node]; deg = indptr[node + 1] - beg; tot = deg + 1;  // +vn edge
    } else if (gw < NREAL + NNODES) {
        node = gw - NREAL;
        qb = qb_exp; kv = kv_exp; sl = esrcs; out = araw2;
        beg = node * 4; deg = 4; tot = 4;
    } else if (gw == NREAL + NNODES) {
        // vn finalize + state reset for next layer
        int h = lane >> 4;
        float inv = 1.0f / (vden[h] + 1e-16f);
        ushort4 o;
        o.x = f2bf(vnum[lane * 4 + 0] * inv);
        o.y = f2bf(vnum[lane * 4 + 1] * inv);
        o.z = f2bf(vnum[lane * 4 + 2] * inv);
        o.w = f2bf(vnum[lane * 4 + 3] * inv);
        *(ushort4*)(araw + fmoff(VN, lane * 4, 256)) = o;
        vnum[lane * 4 + 0] = 0.0f; vnum[lane * 4 + 1] = 0.0f;
        vnum[lane * 4 + 2] = 0.0f; vnum[lane * 4 + 3] = 0.0f;
        if (lane < 4) { vden[lane] = 0.0f; menc[lane] = enc_f(-1e30f); }
        return;
    } else {
        return;
    }

    float4 qv = ld4bf(qb + (size_t)node * 256 + off);
    float m = -1e30f, l = 0.0f;
    float ax = 0, ay = 0, az = 0, aw = 0;

    if (tot <= 4) {
        ushort4 kraw[4], vraw[4];
#pragma unroll
        for (int j = 0; j < 4; j++) {
            int s = (j < deg) ? sl[beg + j] : VN;
            const u16* p = kv + (size_t)s * 512 + off;
            kraw[j] = *(const ushort4*)p;
            vraw[j] = *(const ushort4*)(p + 256);
        }
        float sc[4];
#pragma unroll
        for (int j = 0; j < 4; j++) {
            float4 k4 = cvt4(kraw[j]);
            float p = qv.x * k4.x + qv.y * k4.y + qv.z * k4.z + qv.w * k4.w;
            p += __shfl_xor(p, 1); p += __shfl_xor(p, 2);
            p += __shfl_xor(p, 4); p += __shfl_xor(p, 8);
            sc[j] = (j < tot) ? p * 0.125f : -1e30f;
        }
        float mn = fmaxf(fmaxf(sc[0], sc[1]), fmaxf(sc[2], sc[3]));
#pragma unroll
        for (int j = 0; j < 4; j++) {
            float ee = __expf(sc[j] - mn);
            float4 v4 = cvt4(vraw[j]);
            ax += v4.x * ee; ay += v4.y * ee; az += v4.z * ee; aw += v4.w * ee;
            l += ee;
        }
        m = mn;
    } else {
        for (int e0 = 0; e0 < tot; e0 += 8) {
            ushort4 kraw[8], vraw[8];
#pragma unroll
            for (int j = 0; j < 8; j++) {
                int e = e0 + j;
                int s = (e < deg) ? sl[beg + e] : VN;
                const u16* p = kv + (size_t)s * 512 + off;
                kraw[j] = *(const ushort4*)p;
                vraw[j] = *(const ushort4*)(p + 256);
            }
            float sc[8];
#pragma unroll
            for (int j = 0; j < 8; j++) {
                float4 k4 = cvt4(kraw[j]);
                float p = qv.x * k4.x + qv.y * k4.y + qv.z * k4.z + qv.w * k4.w;
                p += __shfl_xor(p, 1); p += __shfl_xor(p, 2);
                p += __shfl_xor(p, 4); p += __shfl_xor(p, 8);
                sc[j] = (e0 + j < tot) ? p * 0.125f : -1e30f;
            }
            float cmax = fmaxf(fmaxf(fmaxf(sc[0], sc[1]), fmaxf(sc[2], sc[3])),
                               fmaxf(fmaxf(sc[4], sc[5]), fmaxf(sc[6], sc[7])));
            float mn = fmaxf(m, cmax);
            float fold = __expf(m - mn);
            ax *= fold; ay *= fold; az *= fold; aw *= fold; l *= fold;
#pragma unroll
            for (int j = 0; j < 8; j++) {
                float ee = __expf(sc[j] - mn);
                float4 v4 = cvt4(vraw[j]);
                ax += v4.x * ee; ay += v4.y * ee; az += v4.z * ee; aw += v4.w * ee;
                l += ee;
            }
            m = mn;
        }
    }
    float inv = 1.0f / (l + 1e-16f);
    ushort4 o;
    o.x = f2bf(ax * inv); o.y = f2bf(ay * inv);
    o.z = f2bf(az * inv); o.w = f2bf(aw * inv);
    *(ushort4*)(out + fmoff(node, off, 256)) = o;
}

// virtual node (dst = VN), phases 1-2 (finalize lives in attn_fused)
__global__ void vn_score_kernel(const u16* __restrict__ qb, const u16* __restrict__ kv,
                                float* __restrict__ svn, u32* __restrict__ menc) {
    int lane = threadIdx.x & 63;
    int h = lane >> 4, t = lane & 15;
    int off = h * 64 + t * 4;
    float4 qv = ld4bf(qb + (size_t)VN * 256 + off);
    int wid = (int)((blockIdx.x * (size_t)blockDim.x + threadIdx.x) >> 6);
    int nw = (gridDim.x * blockDim.x) >> 6;
    float wmax = -1e30f;
    for (int i = wid; i < NREAL; i += nw) {
        float4 kvv = ld4bf(kv + (size_t)i * 512 + off);
        float p = qv.x * kvv.x + qv.y * kvv.y + qv.z * kvv.z + qv.w * kvv.w;
        p += __shfl_xor(p, 1); p += __shfl_xor(p, 2);
        p += __shfl_xor(p, 4); p += __shfl_xor(p, 8);
        float sc = p * 0.125f;
        if (t == 0) svn[i * 4 + h] = sc;
        wmax = fmaxf(wmax, sc);
    }
    if (t == 0) atomicMax(&menc[h], enc_f(wmax));
}

__global__ void vn_accum_kernel(const u16* __restrict__ kv, const float* __restrict__ svn,
                                const u32* __restrict__ menc, float* __restrict__ vnum,
                                float* __restrict__ vden) {
    int lane = threadIdx.x & 63;
    int h = lane >> 4, t = lane & 15;
    int off = h * 64 + t * 4;
    float m = dec_f(menc[h]);
    int wid = (int)((blockIdx.x * (size_t)blockDim.x + threadIdx.x) >> 6);
    int nw = (gridDim.x * blockDim.x) >> 6;
    float ax = 0, ay = 0, az = 0, aw = 0, l = 0;
    for (int i = wid; i < NREAL; i += nw) {
        float e = __expf(svn[i * 4 + h] - m);
        float4 vv = ld4bf(kv + (size_t)i * 512 + 256 + off);
        ax += e * vv.x; ay += e * vv.y; az += e * vv.z; aw += e * vv.w;
        l += e;
    }
    atomicAdd(&vnum[off + 0], ax);
    atomicAdd(&vnum[off + 1], ay);
    atomicAdd(&vnum[off + 2], az);
    atomicAdd(&vnum[off + 3], aw);
    if (t == 0) atomicAdd(&vden[h], l);
}

// ---------------- layernorm (fused residual + loc + exp), FM bf16 out ----------------
__global__ void ln_kernel(const float* hin, const float* __restrict__ aloc,
                          const float* __restrict__ aexp, const float* __restrict__ g,
                          const float* __restrict__ b, float* hout, u16* __restrict__ hb) {
    int row = blockIdx.x * 4 + (threadIdx.x >> 6);
    if (row >= NNODES) return;
    int lane = threadIdx.x & 63;
    size_t base = (size_t)row * 256 + lane * 4;
    float4 xv = *(const float4*)(hin + base);
    float4 av = *(const float4*)(aloc + base);
    float4 ev = *(const float4*)(aexp + base);
    xv.x += av.x + ev.x; xv.y += av.y + ev.y;
    xv.z += av.z + ev.z; xv.w += av.w + ev.w;
    float s = xv.x + xv.y + xv.z + xv.w;
#pragma unroll
    for (int o = 1; o < 64; o <<= 1) s += __shfl_xor(s, o);
    float mu = s * (1.0f / 256.0f);
    float dx = xv.x - mu, dy = xv.y - mu, dz = xv.z - mu, dw = xv.w - mu;
    float ss = dx * dx + dy * dy + dz * dz + dw * dw;
#pragma unroll
    for (int o = 1; o < 64; o <<= 1) ss += __shfl_xor(ss, o);
    float var = ss * (1.0f / 256.0f);
    float inv = 1.0f / sqrtf(var + 1e-5f);
    float4 gv = *(const float4*)(g + lane * 4);
    float4 bv = *(const float4*)(b + lane * 4);
    float4 y;
    y.x = dx * inv * gv.x + bv.x;
    y.y = dy * inv * gv.y + bv.y;
    y.z = dz * inv * gv.z + bv.z;
    y.w = dw * inv * gv.w + bv.w;
    *(float4*)(hout + base) = y;
    ushort4 o4;
    o4.x = f2bf(y.x); o4.y = f2bf(y.y); o4.z = f2bf(y.z); o4.w = f2bf(y.w);
    *(ushort4*)(hb + fmoff(row, lane * 4, 256)) = o4;
}

// ---------------- host ----------------

extern "C" void kernel_launch(void* const* d_in, const int* in_sizes, int n_in,
                              void* d_out, int out_size, void* d_ws, size_t ws_size,
                              hipStream_t stream) {
    (void)in_sizes; (void)n_in; (void)out_size; (void)ws_size;
    const float* x        = (const float*)d_in[0];
    const int*   ei       = (const int*)d_in[1];
    const int*   eei      = (const int*)d_in[2];
    const float* Wqkv_loc = (const float*)d_in[3];
    const float* bqkv_loc = (const float*)d_in[4];
    const float* Wo_loc   = (const float*)d_in[5];
    const float* bo_loc   = (const float*)d_in[6];
    const float* Wqkv_exp = (const float*)d_in[7];
    const float* bqkv_exp = (const float*)d_in[8];
    const float* Wo_exp   = (const float*)d_in[9];
    const float* bo_exp   = (const float*)d_in[10];
    const float* ln_g     = (const float*)d_in[11];
    const float* ln_b     = (const float*)d_in[12];
    const float* W1       = (const float*)d_in[13];
    const float* b1       = (const float*)d_in[14];
    const float* W2       = (const float*)d_in[15];
    const float* b2       = (const float*)d_in[16];

    char* wsp = (char*)d_ws;
    size_t off = 0;
    auto carve = [&](size_t bytes) -> void* {
        void* p = wsp + off;
        off += (bytes + 255) & ~(size_t)255;
        return p;
    };
    float* h_f    = (float*)carve((size_t)NNODES * 256 * 4);
    u16*   h_b    = (u16*)carve((size_t)MPAD * 256 * 2);      // FM
    u16*   qb_loc = (u16*)carve((size_t)NNODES * 256 * 2);    // dense q, 512B/row
    u16*   kv_loc = (u16*)carve((size_t)NNODES * 512 * 2);    // dense k|v, 1KB/row
    u16*   qb_exp = (u16*)carve((size_t)NNODES * 256 * 2);
    u16*   kv_exp = (u16*)carve((size_t)NNODES * 512 * 2);
    u16*   araw   = (u16*)carve((size_t)MPAD * 256 * 2);      // FM
    u16*   araw2  = (u16*)carve((size_t)MPAD * 256 * 2);      // FM
    float* aloc   = (float*)carve((size_t)NNODES * 256 * 4);
    float* aexp   = (float*)carve((size_t)NNODES * 256 * 4);
    u16*   wbf    = (u16*)carve((size_t)3 * 1048576 * 2);     // FM weights
    float* bcat   = (float*)carve((size_t)3 * 1536 * 4);
    int*   cnt    = (int*)carve((size_t)NREAL * 4);
    int*   indptr = (int*)carve((size_t)(NREAL + 1) * 4);
    int*   fill   = (int*)carve((size_t)NREAL * 4);
    int*   srcs   = (int*)carve((size_t)E_EDGES * 4);
    int*   ecnt   = (int*)carve((size_t)NNODES * 4);
    int*   esrcs  = (int*)carve((size_t)NNODES * 4 * 4);
    float* svn    = (float*)carve((size_t)NREAL * 4 * 4);
    u32*   menc   = (u32*)carve(4 * 4);
    float* vden   = (float*)carve(4 * 4);
    float* vnum   = (float*)carve(256 * 4);
    u16*   mid    = qb_loc;  // FM(MPAD x 1024) = 41.2 MB aliases qb_loc..kv_exp (61.5 MB)

    hinit_kernel<<<(NNODES * 64 + 255) / 256, 256, 0, stream>>>(x, h_f, h_b);
    init_kernel<<<(NNODES + 255) / 256, 256, 0, stream>>>(
        cnt, fill, ecnt, bqkv_loc, bqkv_exp, bcat, vnum, vden, menc);
    csr_count_kernel<<<(E_EDGES + 255) / 256, 256, 0, stream>>>(ei, cnt);
    csr_scan_kernel<<<1, 256, 0, stream>>>(cnt, indptr);
    csr_scatter_kernel<<<(E_EDGES + 255) / 256, 256, 0, stream>>>(ei, indptr, fill, srcs);
    exp_scatter_kernel<<<(NEXP + 255) / 256, 256, 0, stream>>>(eei, ecnt, esrcs);
    wconv_all_kernel<<<(3 * 1048576 + 255) / 256, 256, 0, stream>>>(
        Wqkv_loc, Wqkv_exp, Wo_loc, Wo_exp, W1, W2, wbf);

    const int NBM128 = 160;  // ceil(20001/128) padded to x8
    const int NBM64  = 320;  // ceil(20001/64)  padded to x8

    for (int l = 0; l < 3; l++) {
        const u16* wqkvC = wbf + (size_t)l * 1048576 + 0;
        const u16* woL   = wbf + (size_t)l * 1048576 + 393216;
        const u16* woE   = wbf + (size_t)l * 1048576 + 458752;
        const u16* w1T   = wbf + (size_t)l * 1048576 + 524288;
        const u16* w2T   = wbf + (size_t)l * 1048576 + 786432;

        // fused qkv GEMM (loc|exp), split-store into dense q / k|v buffers
        gemm_fm<6, 256, 128><<<NBM128 * 12, 256, 0, stream>>>(
            h_b, wqkvC, bcat + l * 1536, nullptr, nullptr, nullptr,
            qb_loc, kv_loc, qb_exp, kv_exp, NNODES, 1536, 12);

        // virtual-node dense attention (score + accum; finalize in attn_fused)
        vn_score_kernel<<<80, 256, 0, stream>>>(qb_loc, kv_loc, svn, menc);
        vn_accum_kernel<<<80, 256, 0, stream>>>(kv_loc, svn, menc, vnum, vden);

        // fused local + expander edge attention + vn finalize/reset
        attn_fused_kernel<<<10001, 256, 0, stream>>>(
            qb_loc, kv_loc, qb_exp, kv_exp, indptr, srcs, esrcs,
            vnum, vden, menc, araw, araw2);

        // dual Wo GEMM (loc -> aloc, exp -> aexp)
        gemm_wo<256><<<NBM64 * 2 * 2, 256, 0, stream>>>(
            araw, araw2, woL, woE, bo_loc + l * 256, bo_exp + l * 256,
            aloc, aexp, NNODES, NBM64 * 2);

        // layernorm(res + loc + exp) -> h_f natural + h_b FM
        ln_kernel<<<(NNODES + 3) / 4, 256, 0, stream>>>(
            h_f, aloc, aexp, ln_g + l * 256, ln_b + l * 256, h_f, h_b);

        // FFN: mid = gelu(h@W1+b1) [FM bf16, aliases q/kv bufs]; h += mid@W2+b2
        gemm_fm<2, 256, 128><<<NBM128 * 8, 256, 0, stream>>>(
            h_b, w1T, b1 + l * 1024, mid, nullptr, nullptr,
            nullptr, nullptr, nullptr, nullptr, NNODES, 1024, 8);
        if (l < 2) {
            gemm_fm<3, 1024, 64><<<NBM64 * 2, 256, 0, stream>>>(
                mid, w2T, b2 + l * 256, h_b, h_f, h_f,
                nullptr, nullptr, nullptr, nullptr, NNODES, 256, 2);
        } else {
            gemm_fm<4, 1024, 64><<<NBM64 * 2, 256, 0, stream>>>(
                mid, w2T, b2 + l * 256, nullptr, (float*)d_out, h_f,
                nullptr, nullptr, nullptr, nullptr, NNODES, 256, 2);
        }
    }
}

// Round 9
// 972.259 us; speedup vs baseline: 1.5914x; 1.0771x over previous
//
#include <hip/hip_runtime.h>
#include <stdint.h>

#define NREAL   20000
#define NNODES  20001
#define VN      20000
#define E_EDGES 320000
#define NEXP    80004
#define MPAD    20096   // rows padded to 157*128 for fragment-major buffers
#define NVNW    320     // vn online waves (80 blocks x 4)

typedef unsigned short u16;
typedef unsigned int   u32;
typedef __bf16 bf16x8 __attribute__((ext_vector_type(8)));
typedef float  f32x4  __attribute__((ext_vector_type(4)));

// fragment-major layout: element (row, col) of an LD-wide matrix lives at
// (row/16)*(16*LD) + (col/8)*128 + (row%16)*8 + (col%8).
__device__ __host__ __forceinline__ size_t fmoff(int row, int col, int LD) {
    return (size_t)(row >> 4) * ((size_t)LD * 16) + (size_t)((col >> 3) * 128)
         + (size_t)((row & 15) * 8) + (size_t)(col & 7);
}

__device__ __forceinline__ float bf2f(u16 v) {
    union { u32 u; float f; } x; x.u = ((u32)v) << 16; return x.f;
}
__device__ __forceinline__ u16 f2bf(float f) {
    union { float f; u32 u; } x; x.f = f;
    u32 r = (x.u + 0x7fffu + ((x.u >> 16) & 1u)) >> 16;
    return (u16)r;
}
__device__ __forceinline__ float4 cvt4(ushort4 u) {
    return make_float4(bf2f(u.x), bf2f(u.y), bf2f(u.z), bf2f(u.w));
}
__device__ __forceinline__ float4 ld4bf(const u16* p) { return cvt4(*(const ushort4*)p); }

// ---------------- setup kernels ----------------

__global__ void hinit_kernel(const float* __restrict__ x, float* __restrict__ h,
                             u16* __restrict__ hb) {
    int idx = blockIdx.x * 256 + threadIdx.x;
    if (idx >= NNODES * 64) return;
    int row = idx >> 6, c0 = (idx & 63) * 4;
    float4 v = make_float4(0.f, 0.f, 0.f, 0.f);
    if (row < NREAL) v = *(const float4*)(x + (size_t)row * 256 + c0);
    *(float4*)(h + (size_t)row * 256 + c0) = v;
    ushort4 o;
    o.x = f2bf(v.x); o.y = f2bf(v.y); o.z = f2bf(v.z); o.w = f2bf(v.w);
    *(ushort4*)(hb + fmoff(row, c0, 256)) = o;
}

__global__ void init_kernel(int* cnt, int* fill, int* ecnt,
                            const float* __restrict__ bl, const float* __restrict__ be,
                            float* __restrict__ bcat) {
    int i = blockIdx.x * 256 + threadIdx.x;
    if (i < NREAL) { cnt[i] = 0; fill[i] = 0; }
    if (i < NNODES) ecnt[i] = 0;
    if (i < 3 * 1536) {
        int l = i / 1536, c = i - l * 1536;
        bcat[i] = (c < 768) ? bl[l * 768 + c] : be[l * 768 + c - 768];
    }
}

__global__ void csr_count_kernel(const int* __restrict__ ei, int* __restrict__ cnt) {
    int e = blockIdx.x * 256 + threadIdx.x;
    if (e < E_EDGES) atomicAdd(&cnt[ei[E_EDGES + e]], 1);
}

__global__ void csr_scan_kernel(const int* __restrict__ cnt, int* __restrict__ indptr) {
    __shared__ int ssum[256];
    int t = threadIdx.x;
    int c0 = t * 79;
    int s = 0;
    for (int j = 0; j < 79; j++) {
        int i = c0 + j;
        if (i < NREAL) s += cnt[i];
    }
    ssum[t] = s;
    __syncthreads();
    for (int d2 = 1; d2 < 256; d2 <<= 1) {
        int v = (t >= d2) ? ssum[t - d2] : 0;
        __syncthreads();
        ssum[t] += v;
        __syncthreads();
    }
    int run = (t == 0) ? 0 : ssum[t - 1];
    for (int j = 0; j < 79; j++) {
        int i = c0 + j;
        if (i < NREAL) { indptr[i] = run; run += cnt[i]; }
    }
    if (t == 255) indptr[NREAL] = run;
}

__global__ void csr_scatter_kernel(const int* __restrict__ ei, const int* __restrict__ indptr,
                                   int* __restrict__ fill, int* __restrict__ srcs) {
    int e = blockIdx.x * 256 + threadIdx.x;
    if (e < E_EDGES) {
        int d = ei[E_EDGES + e];
        int pos = indptr[d] + atomicAdd(&fill[d], 1);
        srcs[pos] = ei[e];
    }
}

__global__ void exp_scatter_kernel(const int* __restrict__ eei, int* __restrict__ ecnt,
                                   int* __restrict__ esrcs) {
    int e = blockIdx.x * 256 + threadIdx.x;
    if (e < NEXP) {
        int d = eei[NEXP + e];
        int pos = atomicAdd(&ecnt[d], 1);
        esrcs[d * 4 + pos] = eei[e];
    }
}

// ALL weights -> bf16 fragment-major, one launch. Per-layer slab 1048576 u16:
// [0] WqkvL(256x768) [196608] WqkvE [393216] WoL [458752] WoE
// [524288] W1(256x1024) [786432] W2(1024x256)
__global__ void wconv_all_kernel(const float* __restrict__ WqkvL, const float* __restrict__ WqkvE,
                                 const float* __restrict__ WoL, const float* __restrict__ WoE,
                                 const float* __restrict__ W1, const float* __restrict__ W2,
                                 u16* __restrict__ out) {
    int i = blockIdx.x * 256 + threadIdx.x;
    if (i >= 3 * 1048576) return;
    int l = i / 1048576, r = i - l * 1048576;
    const float* src; int K, N; int base;
    if (r < 196608)      { src = WqkvL; K = 256;  N = 768;  base = 0; }
    else if (r < 393216) { src = WqkvE; K = 256;  N = 768;  base = 196608; }
    else if (r < 458752) { src = WoL;   K = 256;  N = 256;  base = 393216; }
    else if (r < 524288) { src = WoE;   K = 256;  N = 256;  base = 458752; }
    else if (r < 786432) { src = W1;    K = 256;  N = 1024; base = 524288; }
    else                 { src = W2;    K = 1024; N = 256;  base = 786432; }
    int r2 = r - base;
    int k = r2 / N, n = r2 - k * N;
    out[(size_t)l * 1048576 + base + fmoff(n, k, K)] = f2bf(src[(size_t)l * K * N + r2]);
}

// ---------------- B-stationary GEMM (K=256): B n-tile in LDS, 4 m-tiles/block ----
// A: FM(M x 256); Bt: FM(Nout x 256). Block = one 128-col n-tile x 4 m-tiles.
// Wave w owns rows [w*32, w*32+32) of each m-tile x all 128 cols (no dup A loads).
// Flattened 32-iteration (mt,kk) loop, A prefetch distance 2, B from LDS dist 1.
// Swizzle: all n-tiles of an m-chunk share blockIdx%8 -> same XCD (A L2-resident).
// EPI: 2 bias->gelu->bf16 FM; 6 qkv split-store

template <int EPI>
__global__ __launch_bounds__(256) void gemm_bn(
    const u16* __restrict__ A, const u16* __restrict__ Bt, const float* __restrict__ bias,
    u16* Cb, u16* Q0, u16* KV0, u16* Q1, u16* KV1, int M, int Nout, int nbn) {
    __shared__ u16 lB[128 * 256];   // 64 KB
    const int lin = blockIdx.x;
    const int xcd = lin & 7, rest = lin >> 3;
    const int nt = rest % nbn, mc = xcd + 8 * (rest / nbn);
    const int tn = nt * 128;
    const int tid = threadIdx.x;
    const int w = tid >> 6, lane = tid & 63;
    const int lm = lane & 15, q = lane >> 4;

    // stage B n-tile: 64 KB contiguous in FM
    {
        const u16* bsrc = Bt + (size_t)(tn >> 4) * 4096;
#pragma unroll
        for (int r = 0; r < 16; r++) {
            int o = (r * 256 + tid) * 8;
            *(bf16x8*)&lB[o] = *(const bf16x8*)&bsrc[o];
        }
    }
    __syncthreads();

    f32x4 acc[2][8];
#pragma unroll
    for (int a = 0; a < 2; a++)
#pragma unroll
        for (int b = 0; b < 8; b++) acc[a][b] = (f32x4)0.0f;

    const int lbo = q * 128 + lm * 8;   // u16 offset within a (panel,kk) chunk
    const int maxp = MPAD / 16 - 1;

    bf16x8 aS[3][2], bS[2][8];
    // prime t = 0,1 (mt = 0, kk = 0/1)
#pragma unroll
    for (int s = 0; s < 2; s++) {
        int p0 = (mc * 4) * 8 + w * 2;
#pragma unroll
        for (int f = 0; f < 2; f++) {
            int p = p0 + f; if (p > maxp) p = maxp;
            aS[s][f] = *(const bf16x8*)(A + (size_t)p * 4096 + s * 512 + lbo);
        }
#pragma unroll
        for (int n = 0; n < 8; n++)
            bS[s][n] = *(const bf16x8*)&lB[n * 4096 + s * 512 + lbo];
    }

#pragma unroll
    for (int t = 0; t < 32; t++) {
        const int mt = t >> 3, kk = t & 7;
        if (t + 2 < 32) {
            const int t2 = t + 2, mt2 = t2 >> 3, kk2 = t2 & 7;
            int p0 = (mc * 4 + mt2) * 8 + w * 2;
#pragma unroll
            for (int f = 0; f < 2; f++) {
                int p = p0 + f; if (p > maxp) p = maxp;
                aS[t2 % 3][f] = *(const bf16x8*)(A + (size_t)p * 4096 + kk2 * 512 + lbo);
            }
        }
        if (t >= 1 && t + 1 < 32) {
            const int kk1 = (t + 1) & 7;
#pragma unroll
            for (int n = 0; n < 8; n++)
                bS[(t + 1) & 1][n] = *(const bf16x8*)&lB[n * 4096 + kk1 * 512 + lbo];
        }
#pragma unroll
        for (int mi = 0; mi < 2; mi++)
#pragma unroll
            for (int ni = 0; ni < 8; ni++)
                acc[mi][ni] = __builtin_amdgcn_mfma_f32_16x16x32_bf16(
                    bS[t & 1][ni], aS[t % 3][mi], acc[mi][ni], 0, 0, 0);

        if (kk == 7) {
            const int tmg = (mc * 4 + mt) * 128;
#pragma unroll
            for (int mi = 0; mi < 2; mi++) {
                int grow = tmg + w * 32 + mi * 16 + lm;
                if (grow < M) {
#pragma unroll
                    for (int ni = 0; ni < 8; ni++) {
                        int gcol = tn + ni * 16 + q * 4;
                        float4 b4 = *(const float4*)(bias + gcol);
                        float v0 = acc[mi][ni][0] + b4.x;
                        float v1 = acc[mi][ni][1] + b4.y;
                        float v2 = acc[mi][ni][2] + b4.z;
                        float v3 = acc[mi][ni][3] + b4.w;
                        if constexpr (EPI == 6) {
                            ushort4 o;
                            o.x = f2bf(v0); o.y = f2bf(v1); o.z = f2bf(v2); o.w = f2bf(v3);
                            u16* dst;
                            if (gcol < 256)       dst = Q0  + (size_t)grow * 256 + gcol;
                            else if (gcol < 768)  dst = KV0 + (size_t)grow * 512 + (gcol - 256);
                            else if (gcol < 1024) dst = Q1  + (size_t)grow * 256 + (gcol - 768);
                            else                  dst = KV1 + (size_t)grow * 512 + (gcol - 1024);
                            *(ushort4*)dst = o;
                        } else {  // EPI == 2: gelu -> bf16 FM
                            float g0, g1, g2, g3;
                            {
                                float u = 0.7978845608f * (v0 + 0.044715f * v0 * v0 * v0);
                                g0 = 0.5f * v0 * (2.0f - 2.0f / (__expf(2.0f * u) + 1.0f));
                            }
                            {
                                float u = 0.7978845608f * (v1 + 0.044715f * v1 * v1 * v1);
                                g1 = 0.5f * v1 * (2.0f - 2.0f / (__expf(2.0f * u) + 1.0f));
                            }
                            {
                                float u = 0.7978845608f * (v2 + 0.044715f * v2 * v2 * v2);
                                g2 = 0.5f * v2 * (2.0f - 2.0f / (__expf(2.0f * u) + 1.0f));
                            }
                            {
                                float u = 0.7978845608f * (v3 + 0.044715f * v3 * v3 * v3);
                                g3 = 0.5f * v3 * (2.0f - 2.0f / (__expf(2.0f * u) + 1.0f));
                            }
                            ushort4 o;
                            o.x = f2bf(g0); o.y = f2bf(g1); o.z = f2bf(g2); o.w = f2bf(g3);
                            *(ushort4*)(Cb + fmoff(grow, gcol, Nout)) = o;
                        }
                    }
                }
#pragma unroll
                for (int ni = 0; ni < 8; ni++) acc[mi][ni] = (f32x4)0.0f;
            }
        }
    }
}

// ---------------- streamed GEMM (kept for Wo / W2) ------------------------------
// EPI: 3 bias+resid->f32 + bf16 FM; 4 bias+resid->f32 (rows<NREAL)
template <int EPI, int K, int MT>
__global__ __launch_bounds__(256) void gemm_fm(
    const u16* __restrict__ A, const u16* __restrict__ Bt, const float* __restrict__ bias,
    u16* Cb, float* Cf, const float* resid, int M, int Nout, int nby) {
    constexpr int MFR = MT / 32;
    constexpr int NK = K / 32;
    const int lin = blockIdx.x;
    const int xcd = lin & 7, sub = lin >> 3;
    const int mtile = xcd + 8 * (sub / nby);
    const int ntile = sub - (sub / nby) * nby;
    const int tm = mtile * MT, tn = ntile * 128;
    if (tm >= M) return;

    const int tid = threadIdx.x;
    const int w = tid >> 6, lane = tid & 63;
    const int lm = lane & 15, q = lane >> 4;
    const int mo = (w >> 1) * (MT / 2), no = (w & 1) * 64;

    f32x4 acc[MFR][4];
#pragma unroll
    for (int a = 0; a < MFR; a++)
#pragma unroll
        for (int b = 0; b < 4; b++) acc[a][b] = (f32x4)0.0f;

    const u16* apf[MFR];
    const u16* bpf[4];
#pragma unroll
    for (int t = 0; t < MFR; t++) {
        int p = (tm + mo) / 16 + t;
        apf[t] = A + (size_t)p * (16 * K) + q * 128 + lm * 8;
    }
#pragma unroll
    for (int n = 0; n < 4; n++) {
        int c = (tn + no) / 16 + n;
        bpf[n] = Bt + (size_t)c * (16 * K) + q * 128 + lm * 8;
    }

    bf16x8 sA[3][MFR], sB[3][4];
#pragma unroll
    for (int s = 0; s < 2 && s < NK; s++) {
#pragma unroll
        for (int t = 0; t < MFR; t++) sA[s][t] = *(const bf16x8*)(apf[t] + s * 512);
#pragma unroll
        for (int n = 0; n < 4; n++) sB[s][n] = *(const bf16x8*)(bpf[n] + s * 512);
    }
#pragma unroll
    for (int i = 0; i < NK; i++) {
        const int cu = i % 3, pf = (i + 2) % 3;
        if (i + 2 < NK) {
#pragma unroll
            for (int t = 0; t < MFR; t++) sA[pf][t] = *(const bf16x8*)(apf[t] + (i + 2) * 512);
#pragma unroll
            for (int n = 0; n < 4; n++) sB[pf][n] = *(const bf16x8*)(bpf[n] + (i + 2) * 512);
        }
#pragma unroll
        for (int mi = 0; mi < MFR; mi++)
#pragma unroll
            for (int ni = 0; ni < 4; ni++)
                acc[mi][ni] = __builtin_amdgcn_mfma_f32_16x16x32_bf16(
                    sB[cu][ni], sA[cu][mi], acc[mi][ni], 0, 0, 0);
    }

    float4 b4[4];
#pragma unroll
    for (int ni = 0; ni < 4; ni++)
        b4[ni] = *(const float4*)(bias + tn + no + ni * 16 + q * 4);

#pragma unroll
    for (int mi = 0; mi < MFR; mi++) {
        int grow = tm + mo + mi * 16 + lm;
        if constexpr (EPI == 4) { if (grow >= NREAL) continue; }
        else                    { if (grow >= M) continue; }
#pragma unroll
        for (int ni = 0; ni < 4; ni++) {
            int gcol = tn + no + ni * 16 + q * 4;
            float v0 = acc[mi][ni][0] + b4[ni].x;
            float v1 = acc[mi][ni][1] + b4[ni].y;
            float v2 = acc[mi][ni][2] + b4[ni].z;
            float v3 = acc[mi][ni][3] + b4[ni].w;
            size_t idx = (size_t)grow * Nout + gcol;
            if constexpr (EPI == 3) {
                float4 rv = *(const float4*)(resid + idx);
                float o0 = rv.x + v0, o1 = rv.y + v1, o2 = rv.z + v2, o3 = rv.w + v3;
                *(float4*)(Cf + idx) = make_float4(o0, o1, o2, o3);
                ushort4 o;
                o.x = f2bf(o0); o.y = f2bf(o1); o.z = f2bf(o2); o.w = f2bf(o3);
                *(ushort4*)(Cb + fmoff(grow, gcol, Nout)) = o;
            } else {
                float4 rv = *(const float4*)(resid + idx);
                *(float4*)(Cf + idx) = make_float4(rv.x + v0, rv.y + v1, rv.z + v2, rv.w + v3);
            }
        }
    }
}

// ---------------- dual Wo GEMM: two 256x256 GEMMs in one dispatch ----------------
template <int K>
__global__ __launch_bounds__(256) void gemm_wo(
    const u16* __restrict__ A0, const u16* __restrict__ A1,
    const u16* __restrict__ B0, const u16* __restrict__ B1,
    const float* __restrict__ bias0, const float* __restrict__ bias1,
    float* __restrict__ C0, float* __restrict__ C1, int M, int half) {
    constexpr int NK = K / 32;
    const bool second = (int)blockIdx.x >= half;
    const u16* A = second ? A1 : A0;
    const u16* Bt = second ? B1 : B0;
    const float* bias = second ? bias1 : bias0;
    float* Cf = second ? C1 : C0;
    const int lin = (int)blockIdx.x - (second ? half : 0);
    const int xcd = lin & 7, sub = lin >> 3;
    const int mtile = xcd + 8 * (sub >> 1);
    const int ntile = sub & 1;
    const int tm = mtile * 64, tn = ntile * 128;
    if (tm >= M) return;

    const int tid = threadIdx.x;
    const int w = tid >> 6, lane = tid & 63;
    const int lm = lane & 15, q = lane >> 4;
    const int mo = (w >> 1) * 32, no = (w & 1) * 64;

    f32x4 acc[2][4];
#pragma unroll
    for (int a = 0; a < 2; a++)
#pragma unroll
        for (int b = 0; b < 4; b++) acc[a][b] = (f32x4)0.0f;

    const u16* apf[2];
    const u16* bpf[4];
#pragma unroll
    for (int t = 0; t < 2; t++)
        apf[t] = A + (size_t)((tm + mo) / 16 + t) * (16 * K) + q * 128 + lm * 8;
#pragma unroll
    for (int n = 0; n < 4; n++)
        bpf[n] = Bt + (size_t)((tn + no) / 16 + n) * (16 * K) + q * 128 + lm * 8;

    bf16x8 sA[3][2], sB[3][4];
#pragma unroll
    for (int s = 0; s < 2; s++) {
#pragma unroll
        for (int t = 0; t < 2; t++) sA[s][t] = *(const bf16x8*)(apf[t] + s * 512);
#pragma unroll
        for (int n = 0; n < 4; n++) sB[s][n] = *(const bf16x8*)(bpf[n] + s * 512);
    }
#pragma unroll
    for (int i = 0; i < NK; i++) {
        const int cu = i % 3, pf = (i + 2) % 3;
        if (i + 2 < NK) {
#pragma unroll
            for (int t = 0; t < 2; t++) sA[pf][t] = *(const bf16x8*)(apf[t] + (i + 2) * 512);
#pragma unroll
            for (int n = 0; n < 4; n++) sB[pf][n] = *(const bf16x8*)(bpf[n] + (i + 2) * 512);
        }
#pragma unroll
        for (int mi = 0; mi < 2; mi++)
#pragma unroll
            for (int ni = 0; ni < 4; ni++)
                acc[mi][ni] = __builtin_amdgcn_mfma_f32_16x16x32_bf16(
                    sB[cu][ni], sA[cu][mi], acc[mi][ni], 0, 0, 0);
    }

    float4 b4[4];
#pragma unroll
    for (int ni = 0; ni < 4; ni++)
        b4[ni] = *(const float4*)(bias + tn + no + ni * 16 + q * 4);
#pragma unroll
    for (int mi = 0; mi < 2; mi++) {
        int grow = tm + mo + mi * 16 + lm;
        if (grow >= M) continue;
#pragma unroll
        for (int ni = 0; ni < 4; ni++) {
            int gcol = tn + no + ni * 16 + q * 4;
            size_t idx = (size_t)grow * 256 + gcol;
            *(float4*)(Cf + idx) = make_float4(
                acc[mi][ni][0] + b4[ni].x, acc[mi][ni][1] + b4[ni].y,
                acc[mi][ni][2] + b4[ni].z, acc[mi][ni][3] + b4[ni].w);
        }
    }
}

// ---------------- vn dense attention: single-pass online softmax ----------------
// NVNW waves; each strides over real nodes with online (m, l, num) in registers,
// writes one partial per wave. Merged by attn_fused's extra wave.
// partial layout (stride 264 floats): [0..3] m per head, [4..7] l per head, [8..263] num.
__global__ void vn_online_kernel(const u16* __restrict__ qb, const u16* __restrict__ kv,
                                 float* __restrict__ part) {
    int lane = threadIdx.x & 63;
    int h = lane >> 4;
    int off = (h << 6) + (lane & 15) * 4;
    float4 qv = ld4bf(qb + (size_t)VN * 256 + off);
    int wv = (int)((blockIdx.x * (size_t)blockDim.x + threadIdx.x) >> 6);
    float m = -1e30f, l = 0.0f;
    float ax = 0, ay = 0, az = 0, aw = 0;
    for (int i = wv; i < NREAL; i += NVNW) {
        const u16* p = kv + (size_t)i * 512 + off;
        float4 k4 = ld4bf(p);
        float4 v4 = ld4bf(p + 256);
        float s = qv.x * k4.x + qv.y * k4.y + qv.z * k4.z + qv.w * k4.w;
        s += __shfl_xor(s, 1); s += __shfl_xor(s, 2);
        s += __shfl_xor(s, 4); s += __shfl_xor(s, 8);
        float sc = s * 0.125f;
        float mn = fmaxf(m, sc);
        float fold = __expf(m - mn);
        float ee = __expf(sc - mn);
        ax = ax * fold + v4.x * ee;
        ay = ay * fold + v4.y * ee;
        az = az * fold + v4.z * ee;
        aw = aw * fold + v4.w * ee;
        l = l * fold + ee;
        m = mn;
    }
    float* pp = part + (size_t)wv * 264;
    if ((lane & 15) == 0) { pp[h] = m; pp[4 + h] = l; }
    *(float4*)(pp + 8 + off) = make_float4(ax, ay, az, aw);
}

// ---------------- fused attention (local + expander + vn-merge) -----------------
__global__ void attn_fused_kernel(const u16* __restrict__ qb_loc, const u16* __restrict__ kv_loc,
                                  const u16* __restrict__ qb_exp, const u16* __restrict__ kv_exp,
                                  const int* __restrict__ indptr, const int* __restrict__ srcs,
                                  const int* __restrict__ esrcs,
                                  const float* __restrict__ part,
                                  u16* __restrict__ araw, u16* __restrict__ araw2) {
    int gw = (int)((blockIdx.x * (size_t)blockDim.x + threadIdx.x) >> 6);
    int lane = threadIdx.x & 63;
    int h = lane >> 4;
    int off = (h << 6) + (lane & 15) * 4;

    const u16 *qb, *kv;
    const int* sl;
    u16* out;
    int node, beg, deg, tot;
    if (gw < NREAL) {
        node = gw; qb = qb_loc; kv = kv_loc; sl = srcs; out = araw;
        beg = indptr[node]; deg = indptr[node + 1] - beg; tot = deg + 1;  // +vn edge
    } else if (gw < NREAL + NNODES) {
        node = gw - NREAL;
        qb = qb_exp; kv = kv_exp; sl = esrcs; out = araw2;
        beg = node * 4; deg = 4; tot = 4;
    } else if (gw == NREAL + NNODES) {
        // merge vn partials -> araw[VN]
        float M = -1e30f, L = 0.0f;
        float ax = 0, ay = 0, az = 0, aw = 0;
        for (int p = 0; p < NVNW; p++) {
            const float* pp = part + (size_t)p * 264;
            float pm = pp[h], pl = pp[4 + h];
            float4 nm = *(const float4*)(pp + 8 + off);
            float Mn = fmaxf(M, pm);
            float s0 = __expf(M - Mn);
            float s1 = __expf(pm - Mn);
            ax = ax * s0 + nm.x * s1;
            ay = ay * s0 + nm.y * s1;
            az = az * s0 + nm.z * s1;
            aw = aw * s0 + nm.w * s1;
            L = L * s0 + pl * s1;
            M = Mn;
        }
        float inv = 1.0f / (L + 1e-16f);
        ushort4 o;
        o.x = f2bf(ax * inv); o.y = f2bf(ay * inv);
        o.z = f2bf(az * inv); o.w = f2bf(aw * inv);
        *(ushort4*)(araw + fmoff(VN, off, 256)) = o;
        return;
    } else {
        return;
    }

    float4 qv = ld4bf(qb + (size_t)node * 256 + off);
    float m = -1e30f, l = 0.0f;
    float ax = 0, ay = 0, az = 0, aw = 0;

    if (tot <= 4) {
        ushort4 kraw[4], vraw[4];
#pragma unroll
        for (int j = 0; j < 4; j++) {
            int s = (j < deg) ? sl[beg + j] : VN;
            const u16* p = kv + (size_t)s * 512 + off;
            kraw[j] = *(const ushort4*)p;
            vraw[j] = *(const ushort4*)(p + 256);
        }
        float sc[4];
#pragma unroll
        for (int j = 0; j < 4; j++) {
            float4 k4 = cvt4(kraw[j]);
            float p = qv.x * k4.x + qv.y * k4.y + qv.z * k4.z + qv.w * k4.w;
            p += __shfl_xor(p, 1); p += __shfl_xor(p, 2);
            p += __shfl_xor(p, 4); p += __shfl_xor(p, 8);
            sc[j] = (j < tot) ? p * 0.125f : -1e30f;
        }
        float mn = fmaxf(fmaxf(sc[0], sc[1]), fmaxf(sc[2], sc[3]));
#pragma unroll
        for (int j = 0; j < 4; j++) {
            float ee = __expf(sc[j] - mn);
            float4 v4 = cvt4(vraw[j]);
            ax += v4.x * ee; ay += v4.y * ee; az += v4.z * ee; aw += v4.w * ee;
            l += ee;
        }
        m = mn;
    } else {
        for (int e0 = 0; e0 < tot; e0 += 8) {
            ushort4 kraw[8], vraw[8];
#pragma unroll
            for (int j = 0; j < 8; j++) {
                int e = e0 + j;
                int s = (e < deg) ? sl[beg + e] : VN;
                const u16* p = kv + (size_t)s * 512 + off;
                kraw[j] = *(const ushort4*)p;
                vraw[j] = *(const ushort4*)(p + 256);
            }
            float sc[8];
#pragma unroll
            for (int j = 0; j < 8; j++) {
                float4 k4 = cvt4(kraw[j]);
                float p = qv.x * k4.x + qv.y * k4.y + qv.z * k4.z + qv.w * k4.w;
                p += __shfl_xor(p, 1); p += __shfl_xor(p, 2);
                p += __shfl_xor(p, 4); p += __shfl_xor(p, 8);
                sc[j] = (e0 + j < tot) ? p * 0.125f : -1e30f;
            }
            float cmax = fmaxf(fmaxf(fmaxf(sc[0], sc[1]), fmaxf(sc[2], sc[3])),
                               fmaxf(fmaxf(sc[4], sc[5]), fmaxf(sc[6], sc[7])));
            float mn = fmaxf(m, cmax);
            float fold = __expf(m - mn);
            ax *= fold; ay *= fold; az *= fold; aw *= fold; l *= fold;
#pragma unroll
            for (int j = 0; j < 8; j++) {
                float ee = __expf(sc[j] - mn);
                float4 v4 = cvt4(vraw[j]);
                ax += v4.x * ee; ay += v4.y * ee; az += v4.z * ee; aw += v4.w * ee;
                l += ee;
            }
            m = mn;
        }
    }
    float inv = 1.0f / (l + 1e-16f);
    ushort4 o;
    o.x = f2bf(ax * inv); o.y = f2bf(ay * inv);
    o.z = f2bf(az * inv); o.w = f2bf(aw * inv);
    *(ushort4*)(out + fmoff(node, off, 256)) = o;
}

// ---------------- layernorm (fused residual + loc + exp), FM bf16 out ----------------
__global__ void ln_kernel(const float* hin, const float* __restrict__ aloc,
                          const float* __restrict__ aexp, const float* __restrict__ g,
                          const float* __restrict__ b, float* hout, u16* __restrict__ hb) {
    int row = blockIdx.x * 4 + (threadIdx.x >> 6);
    if (row >= NNODES) return;
    int lane = threadIdx.x & 63;
    size_t base = (size_t)row * 256 + lane * 4;
    float4 xv = *(const float4*)(hin + base);
    float4 av = *(const float4*)(aloc + base);
    float4 ev = *(const float4*)(aexp + base);
    xv.x += av.x + ev.x; xv.y += av.y + ev.y;
    xv.z += av.z + ev.z; xv.w += av.w + ev.w;
    float s = xv.x + xv.y + xv.z + xv.w;
#pragma unroll
    for (int o = 1; o < 64; o <<= 1) s += __shfl_xor(s, o);
    float mu = s * (1.0f / 256.0f);
    float dx = xv.x - mu, dy = xv.y - mu, dz = xv.z - mu, dw = xv.w - mu;
    float ss = dx * dx + dy * dy + dz * dz + dw * dw;
#pragma unroll
    for (int o = 1; o < 64; o <<= 1) ss += __shfl_xor(ss, o);
    float var = ss * (1.0f / 256.0f);
    float inv = 1.0f / sqrtf(var + 1e-5f);
    float4 gv = *(const float4*)(g + lane * 4);
    float4 bv = *(const float4*)(b + lane * 4);
    float4 y;
    y.x = dx * inv * gv.x + bv.x;
    y.y = dy * inv * gv.y + bv.y;
    y.z = dz * inv * gv.z + bv.z;
    y.w = dw * inv * gv.w + bv.w;
    *(float4*)(hout + base) = y;
    ushort4 o4;
    o4.x = f2bf(y.x); o4.y = f2bf(y.y); o4.z = f2bf(y.z); o4.w = f2bf(y.w);
    *(ushort4*)(hb + fmoff(row, lane * 4, 256)) = o4;
}

// ---------------- host ----------------

extern "C" void kernel_launch(void* const* d_in, const int* in_sizes, int n_in,
                              void* d_out, int out_size, void* d_ws, size_t ws_size,
                              hipStream_t stream) {
    (void)in_sizes; (void)n_in; (void)out_size; (void)ws_size;
    const float* x        = (const float*)d_in[0];
    const int*   ei       = (const int*)d_in[1];
    const int*   eei      = (const int*)d_in[2];
    const float* Wqkv_loc = (const float*)d_in[3];
    const float* bqkv_loc = (const float*)d_in[4];
    const float* Wo_loc   = (const float*)d_in[5];
    const float* bo_loc   = (const float*)d_in[6];
    const float* Wqkv_exp = (const float*)d_in[7];
    const float* bqkv_exp = (const float*)d_in[8];
    const float* Wo_exp   = (const float*)d_in[9];
    const float* bo_exp   = (const float*)d_in[10];
    const float* ln_g     = (const float*)d_in[11];
    const float* ln_b     = (const float*)d_in[12];
    const float* W1       = (const float*)d_in[13];
    const float* b1       = (const float*)d_in[14];
    const float* W2       = (const float*)d_in[15];
    const float* b2       = (const float*)d_in[16];

    char* wsp = (char*)d_ws;
    size_t off = 0;
    auto carve = [&](size_t bytes) -> void* {
        void* p = wsp + off;
        off += (bytes + 255) & ~(size_t)255;
        return p;
    };
    float* h_f    = (float*)carve((size_t)NNODES * 256 * 4);
    u16*   h_b    = (u16*)carve((size_t)MPAD * 256 * 2);      // FM
    u16*   qb_loc = (u16*)carve((size_t)NNODES * 256 * 2);    // dense q, 512B/row
    u16*   kv_loc = (u16*)carve((size_t)NNODES * 512 * 2);    // dense k|v, 1KB/row
    u16*   qb_exp = (u16*)carve((size_t)NNODES * 256 * 2);
    u16*   kv_exp = (u16*)carve((size_t)NNODES * 512 * 2);
    u16*   araw   = (u16*)carve((size_t)MPAD * 256 * 2);      // FM
    u16*   araw2  = (u16*)carve((size_t)MPAD * 256 * 2);      // FM
    float* aloc   = (float*)carve((size_t)NNODES * 256 * 4);
    float* aexp   = (float*)carve((size_t)NNODES * 256 * 4);
    u16*   wbf    = (u16*)carve((size_t)3 * 1048576 * 2);     // FM weights
    float* bcat   = (float*)carve((size_t)3 * 1536 * 4);
    int*   cnt    = (int*)carve((size_t)NREAL * 4);
    int*   indptr = (int*)carve((size_t)(NREAL + 1) * 4);
    int*   fill   = (int*)carve((size_t)NREAL * 4);
    int*   srcs   = (int*)carve((size_t)E_EDGES * 4);
    int*   ecnt   = (int*)carve((size_t)NNODES * 4);
    int*   esrcs  = (int*)carve((size_t)NNODES * 4 * 4);
    float* part   = (float*)carve((size_t)NVNW * 264 * 4);
    u16*   mid    = qb_loc;  // FM(MPAD x 1024) = 41.2 MB aliases qb_loc..kv_exp

    hinit_kernel<<<(NNODES * 64 + 255) / 256, 256, 0, stream>>>(x, h_f, h_b);
    init_kernel<<<(NNODES + 255) / 256, 256, 0, stream>>>(
        cnt, fill, ecnt, bqkv_loc, bqkv_exp, bcat);
    csr_count_kernel<<<(E_EDGES + 255) / 256, 256, 0, stream>>>(ei, cnt);
    csr_scan_kernel<<<1, 256, 0, stream>>>(cnt, indptr);
    csr_scatter_kernel<<<(E_EDGES + 255) / 256, 256, 0, stream>>>(ei, indptr, fill, srcs);
    exp_scatter_kernel<<<(NEXP + 255) / 256, 256, 0, stream>>>(eei, ecnt, esrcs);
    wconv_all_kernel<<<(3 * 1048576 + 255) / 256, 256, 0, stream>>>(
        Wqkv_loc, Wqkv_exp, Wo_loc, Wo_exp, W1, W2, wbf);

    const int NBM64 = 320;   // ceil(20001/64) padded to x8 (for gemm_fm/gemm_wo)

    for (int l = 0; l < 3; l++) {
        const u16* wqkvC = wbf + (size_t)l * 1048576 + 0;
        const u16* woL   = wbf + (size_t)l * 1048576 + 393216;
        const u16* woE   = wbf + (size_t)l * 1048576 + 458752;
        const u16* w1T   = wbf + (size_t)l * 1048576 + 524288;
        const u16* w2T   = wbf + (size_t)l * 1048576 + 786432;

        // fused qkv GEMM (loc|exp), B-stationary, split-store q / k|v
        // grid = 8 * nbn * ceil(40 m-chunks / 8) = 8*12*5 = 480
        gemm_bn<6><<<480, 256, 0, stream>>>(
            h_b, wqkvC, bcat + l * 1536, nullptr,
            qb_loc, kv_loc, qb_exp, kv_exp, NNODES, 1536, 12);

        // vn dense attention: single-pass online partials
        vn_online_kernel<<<NVNW / 4, 256, 0, stream>>>(qb_loc, kv_loc, part);

        // fused local + expander edge attention + vn partial merge
        attn_fused_kernel<<<10001, 256, 0, stream>>>(
            qb_loc, kv_loc, qb_exp, kv_exp, indptr, srcs, esrcs, part, araw, araw2);

        // dual Wo GEMM (loc -> aloc, exp -> aexp)
        gemm_wo<256><<<NBM64 * 2 * 2, 256, 0, stream>>>(
            araw, araw2, woL, woE, bo_loc + l * 256, bo_exp + l * 256,
            aloc, aexp, NNODES, NBM64 * 2);

        // layernorm(res + loc + exp) -> h_f natural + h_b FM
        ln_kernel<<<(NNODES + 3) / 4, 256, 0, stream>>>(
            h_f, aloc, aexp, ln_g + l * 256, ln_b + l * 256, h_f, h_b);

        // FFN: mid = gelu(h@W1+b1), B-stationary (grid 8*8*5 = 320); h += mid@W2+b2
        gemm_bn<2><<<320, 256, 0, stream>>>(
            h_b, w1T, b1 + l * 1024, mid,
            nullptr, nullptr, nullptr, nullptr, NNODES, 1024, 8);
        if (l < 2) {
            gemm_fm<3, 1024, 64><<<NBM64 * 2, 256, 0, stream>>>(
                mid, w2T, b2 + l * 256, h_b, h_f, h_f, NNODES, 256, 2);
        } else {
            gemm_fm<4, 1024, 64><<<NBM64 * 2, 256, 0, stream>>>(
                mid, w2T, b2 + l * 256, nullptr, (float*)d_out, h_f, NNODES, 256, 2);
        }
    }
}

// Round 10
// 905.041 us; speedup vs baseline: 1.7096x; 1.0743x over previous
//
#include <hip/hip_runtime.h>
#include <stdint.h>

#define NREAL   20000
#define NNODES  20001
#define VN      20000
#define E_EDGES 320000
#define NEXP    80004
#define MPAD    20096   // rows padded to 157*128 for fragment-major buffers
#define NVNW    320     // vn online waves (80 blocks x 4)

typedef unsigned short u16;
typedef unsigned int   u32;
typedef __bf16 bf16x8 __attribute__((ext_vector_type(8)));
typedef float  f32x4  __attribute__((ext_vector_type(4)));

// fragment-major layout: element (row, col) of an LD-wide matrix lives at
// (row/16)*(16*LD) + (col/8)*128 + (row%16)*8 + (col%8).
__device__ __host__ __forceinline__ size_t fmoff(int row, int col, int LD) {
    return (size_t)(row >> 4) * ((size_t)LD * 16) + (size_t)((col >> 3) * 128)
         + (size_t)((row & 15) * 8) + (size_t)(col & 7);
}

__device__ __forceinline__ float bf2f(u16 v) {
    union { u32 u; float f; } x; x.u = ((u32)v) << 16; return x.f;
}
__device__ __forceinline__ u16 f2bf(float f) {
    union { float f; u32 u; } x; x.f = f;
    u32 r = (x.u + 0x7fffu + ((x.u >> 16) & 1u)) >> 16;
    return (u16)r;
}
__device__ __forceinline__ float4 cvt4(ushort4 u) {
    return make_float4(bf2f(u.x), bf2f(u.y), bf2f(u.z), bf2f(u.w));
}
__device__ __forceinline__ float4 ld4bf(const u16* p) { return cvt4(*(const ushort4*)p); }

// ---------------- setup kernels ----------------

__global__ void hinit_kernel(const float* __restrict__ x, float* __restrict__ h,
                             u16* __restrict__ hb) {
    int idx = blockIdx.x * 256 + threadIdx.x;
    if (idx >= NNODES * 64) return;
    int row = idx >> 6, c0 = (idx & 63) * 4;
    float4 v = make_float4(0.f, 0.f, 0.f, 0.f);
    if (row < NREAL) v = *(const float4*)(x + (size_t)row * 256 + c0);
    *(float4*)(h + (size_t)row * 256 + c0) = v;
    ushort4 o;
    o.x = f2bf(v.x); o.y = f2bf(v.y); o.z = f2bf(v.z); o.w = f2bf(v.w);
    *(ushort4*)(hb + fmoff(row, c0, 256)) = o;
}

__global__ void init_kernel(int* cnt, int* fill, int* ecnt,
                            const float* __restrict__ bl, const float* __restrict__ be,
                            float* __restrict__ bcat,
                            const float* __restrict__ bol, const float* __restrict__ boe,
                            float* __restrict__ bsum) {
    int i = blockIdx.x * 256 + threadIdx.x;
    if (i < NREAL) { cnt[i] = 0; fill[i] = 0; }
    if (i < NNODES) ecnt[i] = 0;
    if (i < 3 * 1536) {
        int l = i / 1536, c = i - l * 1536;
        bcat[i] = (c < 768) ? bl[l * 768 + c] : be[l * 768 + c - 768];
    }
    if (i < 3 * 256) bsum[i] = bol[i] + boe[i];
}

__global__ void csr_count_kernel(const int* __restrict__ ei, int* __restrict__ cnt) {
    int e = blockIdx.x * 256 + threadIdx.x;
    if (e < E_EDGES) atomicAdd(&cnt[ei[E_EDGES + e]], 1);
}

__global__ void csr_scan_kernel(const int* __restrict__ cnt, int* __restrict__ indptr) {
    __shared__ int ssum[256];
    int t = threadIdx.x;
    int c0 = t * 79;
    int s = 0;
    for (int j = 0; j < 79; j++) {
        int i = c0 + j;
        if (i < NREAL) s += cnt[i];
    }
    ssum[t] = s;
    __syncthreads();
    for (int d2 = 1; d2 < 256; d2 <<= 1) {
        int v = (t >= d2) ? ssum[t - d2] : 0;
        __syncthreads();
        ssum[t] += v;
        __syncthreads();
    }
    int run = (t == 0) ? 0 : ssum[t - 1];
    for (int j = 0; j < 79; j++) {
        int i = c0 + j;
        if (i < NREAL) { indptr[i] = run; run += cnt[i]; }
    }
    if (t == 255) indptr[NREAL] = run;
}

__global__ void csr_scatter_kernel(const int* __restrict__ ei, const int* __restrict__ indptr,
                                   int* __restrict__ fill, int* __restrict__ srcs) {
    int e = blockIdx.x * 256 + threadIdx.x;
    if (e < E_EDGES) {
        int d = ei[E_EDGES + e];
        int pos = indptr[d] + atomicAdd(&fill[d], 1);
        srcs[pos] = ei[e];
    }
}

__global__ void exp_scatter_kernel(const int* __restrict__ eei, int* __restrict__ ecnt,
                                   int* __restrict__ esrcs) {
    int e = blockIdx.x * 256 + threadIdx.x;
    if (e < NEXP) {
        int d = eei[NEXP + e];
        int pos = atomicAdd(&ecnt[d], 1);
        esrcs[d * 4 + pos] = eei[e];
    }
}

// ALL weights -> bf16 fragment-major, one launch. Per-layer slab 1048576 u16:
// [0] WqkvL(FM 768x256) [196608] WqkvE [393216] Wo-cat FM(256 x 512) (K-stacked WoL;WoE)
// [524288] W1 FM(1024x256) [786432] W2 FM(256x1024)
__global__ void wconv_all_kernel(const float* __restrict__ WqkvL, const float* __restrict__ WqkvE,
                                 const float* __restrict__ WoL, const float* __restrict__ WoE,
                                 const float* __restrict__ W1, const float* __restrict__ W2,
                                 u16* __restrict__ out) {
    int i = blockIdx.x * 256 + threadIdx.x;
    if (i >= 3 * 1048576) return;
    int l = i / 1048576, r = i - l * 1048576;
    if (r >= 393216 && r < 524288) {
        // Wo-cat: r2 = k*256 + n, k in [0,512), n in [0,256)
        int r2 = r - 393216;
        int k = r2 >> 8, n = r2 & 255;
        float v = (k < 256) ? WoL[(size_t)l * 65536 + k * 256 + n]
                            : WoE[(size_t)l * 65536 + (k - 256) * 256 + n];
        out[(size_t)l * 1048576 + 393216 + fmoff(n, k, 512)] = f2bf(v);
        return;
    }
    const float* src; int K, N; int base;
    if (r < 196608)      { src = WqkvL; K = 256;  N = 768;  base = 0; }
    else if (r < 393216) { src = WqkvE; K = 256;  N = 768;  base = 196608; }
    else if (r < 786432) { src = W1;    K = 256;  N = 1024; base = 524288; }
    else                 { src = W2;    K = 1024; N = 256;  base = 786432; }
    int r2 = r - base;
    int k = r2 / N, n = r2 - k * N;
    out[(size_t)l * 1048576 + base + fmoff(n, k, K)] = f2bf(src[(size_t)l * K * N + r2]);
}

// ---------------- B-stationary GEMM (K=256): B n-tile in LDS, 4 m-tiles/block ----
// EPI: 2 bias->gelu->bf16 FM; 6 qkv split-store
template <int EPI>
__global__ __launch_bounds__(256) void gemm_bn(
    const u16* __restrict__ A, const u16* __restrict__ Bt, const float* __restrict__ bias,
    u16* Cb, u16* Q0, u16* KV0, u16* Q1, u16* KV1, int M, int Nout, int nbn) {
    __shared__ u16 lB[128 * 256];   // 64 KB
    const int lin = blockIdx.x;
    const int xcd = lin & 7, rest = lin >> 3;
    const int nt = rest % nbn, mc = xcd + 8 * (rest / nbn);
    const int tn = nt * 128;
    const int tid = threadIdx.x;
    const int w = tid >> 6, lane = tid & 63;
    const int lm = lane & 15, q = lane >> 4;

    {
        const u16* bsrc = Bt + (size_t)(tn >> 4) * 4096;
#pragma unroll
        for (int r = 0; r < 16; r++) {
            int o = (r * 256 + tid) * 8;
            *(bf16x8*)&lB[o] = *(const bf16x8*)&bsrc[o];
        }
    }
    __syncthreads();

    f32x4 acc[2][8];
#pragma unroll
    for (int a = 0; a < 2; a++)
#pragma unroll
        for (int b = 0; b < 8; b++) acc[a][b] = (f32x4)0.0f;

    const int lbo = q * 128 + lm * 8;
    const int maxp = MPAD / 16 - 1;

    bf16x8 aS[3][2], bS[2][8];
#pragma unroll
    for (int s = 0; s < 2; s++) {
        int p0 = (mc * 4) * 8 + w * 2;
#pragma unroll
        for (int f = 0; f < 2; f++) {
            int p = p0 + f; if (p > maxp) p = maxp;
            aS[s][f] = *(const bf16x8*)(A + (size_t)p * 4096 + s * 512 + lbo);
        }
#pragma unroll
        for (int n = 0; n < 8; n++)
            bS[s][n] = *(const bf16x8*)&lB[n * 4096 + s * 512 + lbo];
    }

#pragma unroll
    for (int t = 0; t < 32; t++) {
        const int mt = t >> 3, kk = t & 7;
        if (t + 2 < 32) {
            const int t2 = t + 2, mt2 = t2 >> 3, kk2 = t2 & 7;
            int p0 = (mc * 4 + mt2) * 8 + w * 2;
#pragma unroll
            for (int f = 0; f < 2; f++) {
                int p = p0 + f; if (p > maxp) p = maxp;
                aS[t2 % 3][f] = *(const bf16x8*)(A + (size_t)p * 4096 + kk2 * 512 + lbo);
            }
        }
        if (t >= 1 && t + 1 < 32) {
            const int kk1 = (t + 1) & 7;
#pragma unroll
            for (int n = 0; n < 8; n++)
                bS[(t + 1) & 1][n] = *(const bf16x8*)&lB[n * 4096 + kk1 * 512 + lbo];
        }
#pragma unroll
        for (int mi = 0; mi < 2; mi++)
#pragma unroll
            for (int ni = 0; ni < 8; ni++)
                acc[mi][ni] = __builtin_amdgcn_mfma_f32_16x16x32_bf16(
                    bS[t & 1][ni], aS[t % 3][mi], acc[mi][ni], 0, 0, 0);

        if (kk == 7) {
            const int tmg = (mc * 4 + mt) * 128;
#pragma unroll
            for (int mi = 0; mi < 2; mi++) {
                int grow = tmg + w * 32 + mi * 16 + lm;
                if (grow < M) {
#pragma unroll
                    for (int ni = 0; ni < 8; ni++) {
                        int gcol = tn + ni * 16 + q * 4;
                        float4 b4 = *(const float4*)(bias + gcol);
                        float v0 = acc[mi][ni][0] + b4.x;
                        float v1 = acc[mi][ni][1] + b4.y;
                        float v2 = acc[mi][ni][2] + b4.z;
                        float v3 = acc[mi][ni][3] + b4.w;
                        if constexpr (EPI == 6) {
                            ushort4 o;
                            o.x = f2bf(v0); o.y = f2bf(v1); o.z = f2bf(v2); o.w = f2bf(v3);
                            u16* dst;
                            if (gcol < 256)       dst = Q0  + (size_t)grow * 256 + gcol;
                            else if (gcol < 768)  dst = KV0 + (size_t)grow * 512 + (gcol - 256);
                            else if (gcol < 1024) dst = Q1  + (size_t)grow * 256 + (gcol - 768);
                            else                  dst = KV1 + (size_t)grow * 512 + (gcol - 1024);
                            *(ushort4*)dst = o;
                        } else {  // EPI == 2: gelu -> bf16 FM
                            float g0, g1, g2, g3;
                            {
                                float u = 0.7978845608f * (v0 + 0.044715f * v0 * v0 * v0);
                                g0 = 0.5f * v0 * (2.0f - 2.0f / (__expf(2.0f * u) + 1.0f));
                            }
                            {
                                float u = 0.7978845608f * (v1 + 0.044715f * v1 * v1 * v1);
                                g1 = 0.5f * v1 * (2.0f - 2.0f / (__expf(2.0f * u) + 1.0f));
                            }
                            {
                                float u = 0.7978845608f * (v2 + 0.044715f * v2 * v2 * v2);
                                g2 = 0.5f * v2 * (2.0f - 2.0f / (__expf(2.0f * u) + 1.0f));
                            }
                            {
                                float u = 0.7978845608f * (v3 + 0.044715f * v3 * v3 * v3);
                                g3 = 0.5f * v3 * (2.0f - 2.0f / (__expf(2.0f * u) + 1.0f));
                            }
                            ushort4 o;
                            o.x = f2bf(g0); o.y = f2bf(g1); o.z = f2bf(g2); o.w = f2bf(g3);
                            *(ushort4*)(Cb + fmoff(grow, gcol, Nout)) = o;
                        }
                    }
                }
#pragma unroll
                for (int ni = 0; ni < 8; ni++) acc[mi][ni] = (f32x4)0.0f;
            }
        }
    }
}

// ---------------- streamed GEMM (Wo-cat K=512 / W2 K=1024) ----------------------
// EPI: 1 bias->f32; 3 bias+resid->f32 + bf16 FM; 4 bias+resid->f32 (rows<NREAL)
template <int EPI, int K, int MT>
__global__ __launch_bounds__(256) void gemm_fm(
    const u16* __restrict__ A, const u16* __restrict__ Bt, const float* __restrict__ bias,
    u16* Cb, float* Cf, const float* resid, int M, int Nout, int nby) {
    constexpr int MFR = MT / 32;
    constexpr int NK = K / 32;
    const int lin = blockIdx.x;
    const int xcd = lin & 7, sub = lin >> 3;
    const int mtile = xcd + 8 * (sub / nby);
    const int ntile = sub - (sub / nby) * nby;
    const int tm = mtile * MT, tn = ntile * 128;
    if (tm >= M) return;

    const int tid = threadIdx.x;
    const int w = tid >> 6, lane = tid & 63;
    const int lm = lane & 15, q = lane >> 4;
    const int mo = (w >> 1) * (MT / 2), no = (w & 1) * 64;

    f32x4 acc[MFR][4];
#pragma unroll
    for (int a = 0; a < MFR; a++)
#pragma unroll
        for (int b = 0; b < 4; b++) acc[a][b] = (f32x4)0.0f;

    const u16* apf[MFR];
    const u16* bpf[4];
#pragma unroll
    for (int t = 0; t < MFR; t++) {
        int p = (tm + mo) / 16 + t;
        apf[t] = A + (size_t)p * (16 * K) + q * 128 + lm * 8;
    }
#pragma unroll
    for (int n = 0; n < 4; n++) {
        int c = (tn + no) / 16 + n;
        bpf[n] = Bt + (size_t)c * (16 * K) + q * 128 + lm * 8;
    }

    bf16x8 sA[3][MFR], sB[3][4];
#pragma unroll
    for (int s = 0; s < 2 && s < NK; s++) {
#pragma unroll
        for (int t = 0; t < MFR; t++) sA[s][t] = *(const bf16x8*)(apf[t] + s * 512);
#pragma unroll
        for (int n = 0; n < 4; n++) sB[s][n] = *(const bf16x8*)(bpf[n] + s * 512);
    }
#pragma unroll
    for (int i = 0; i < NK; i++) {
        const int cu = i % 3, pf = (i + 2) % 3;
        if (i + 2 < NK) {
#pragma unroll
            for (int t = 0; t < MFR; t++) sA[pf][t] = *(const bf16x8*)(apf[t] + (i + 2) * 512);
#pragma unroll
            for (int n = 0; n < 4; n++) sB[pf][n] = *(const bf16x8*)(bpf[n] + (i + 2) * 512);
        }
#pragma unroll
        for (int mi = 0; mi < MFR; mi++)
#pragma unroll
            for (int ni = 0; ni < 4; ni++)
                acc[mi][ni] = __builtin_amdgcn_mfma_f32_16x16x32_bf16(
                    sB[cu][ni], sA[cu][mi], acc[mi][ni], 0, 0, 0);
    }

    float4 b4[4];
#pragma unroll
    for (int ni = 0; ni < 4; ni++)
        b4[ni] = *(const float4*)(bias + tn + no + ni * 16 + q * 4);

#pragma unroll
    for (int mi = 0; mi < MFR; mi++) {
        int grow = tm + mo + mi * 16 + lm;
        if constexpr (EPI == 4) { if (grow >= NREAL) continue; }
        else                    { if (grow >= M) continue; }
#pragma unroll
        for (int ni = 0; ni < 4; ni++) {
            int gcol = tn + no + ni * 16 + q * 4;
            float v0 = acc[mi][ni][0] + b4[ni].x;
            float v1 = acc[mi][ni][1] + b4[ni].y;
            float v2 = acc[mi][ni][2] + b4[ni].z;
            float v3 = acc[mi][ni][3] + b4[ni].w;
            size_t idx = (size_t)grow * Nout + gcol;
            if constexpr (EPI == 1) {
                *(float4*)(Cf + idx) = make_float4(v0, v1, v2, v3);
            } else if constexpr (EPI == 3) {
                float4 rv = *(const float4*)(resid + idx);
                float o0 = rv.x + v0, o1 = rv.y + v1, o2 = rv.z + v2, o3 = rv.w + v3;
                *(float4*)(Cf + idx) = make_float4(o0, o1, o2, o3);
                ushort4 o;
                o.x = f2bf(o0); o.y = f2bf(o1); o.z = f2bf(o2); o.w = f2bf(o3);
                *(ushort4*)(Cb + fmoff(grow, gcol, Nout)) = o;
            } else {
                float4 rv = *(const float4*)(resid + idx);
                *(float4*)(Cf + idx) = make_float4(rv.x + v0, rv.y + v1, rv.z + v2, rv.w + v3);
            }
        }
    }
}

// ---------------- vn dense attention: single-pass online partials ----------------
__global__ void vn_online_kernel(const u16* __restrict__ qb, const u16* __restrict__ kv,
                                 float* __restrict__ part) {
    int lane = threadIdx.x & 63;
    int h = lane >> 4;
    int off = (h << 6) + (lane & 15) * 4;
    float4 qv = ld4bf(qb + (size_t)VN * 256 + off);
    int wv = (int)((blockIdx.x * (size_t)blockDim.x + threadIdx.x) >> 6);
    float m = -1e30f, l = 0.0f;
    float ax = 0, ay = 0, az = 0, aw = 0;
    for (int i = wv; i < NREAL; i += NVNW) {
        const u16* p = kv + (size_t)i * 512 + off;
        float4 k4 = ld4bf(p);
        float4 v4 = ld4bf(p + 256);
        float s = qv.x * k4.x + qv.y * k4.y + qv.z * k4.z + qv.w * k4.w;
        s += __shfl_xor(s, 1); s += __shfl_xor(s, 2);
        s += __shfl_xor(s, 4); s += __shfl_xor(s, 8);
        float sc = s * 0.125f;
        float mn = fmaxf(m, sc);
        float fold = __expf(m - mn);
        float ee = __expf(sc - mn);
        ax = ax * fold + v4.x * ee;
        ay = ay * fold + v4.y * ee;
        az = az * fold + v4.z * ee;
        aw = aw * fold + v4.w * ee;
        l = l * fold + ee;
        m = mn;
    }
    float* pp = part + (size_t)wv * 264;
    if ((lane & 15) == 0) { pp[h] = m; pp[4 + h] = l; }
    *(float4*)(pp + 8 + off) = make_float4(ax, ay, az, aw);
}

// parallel merge: 4 waves x 80 partials + LDS cross-wave combine -> acat[VN] (local cols)
__global__ void vn_merge_kernel(const float* __restrict__ part, u16* __restrict__ acat) {
    __shared__ float sm[4][64][6];
    int w = threadIdx.x >> 6, lane = threadIdx.x & 63;
    int h = lane >> 4;
    int off = (h << 6) + (lane & 15) * 4;
    float M = -1e30f, L = 0.0f;
    float ax = 0, ay = 0, az = 0, aw = 0;
    for (int p = w * 80; p < w * 80 + 80; p++) {
        const float* pp = part + (size_t)p * 264;
        float pm = pp[h], pl = pp[4 + h];
        float4 nm = *(const float4*)(pp + 8 + off);
        float Mn = fmaxf(M, pm);
        float s0 = __expf(M - Mn);
        float s1 = __expf(pm - Mn);
        ax = ax * s0 + nm.x * s1;
        ay = ay * s0 + nm.y * s1;
        az = az * s0 + nm.z * s1;
        aw = aw * s0 + nm.w * s1;
        L = L * s0 + pl * s1;
        M = Mn;
    }
    sm[w][lane][0] = M; sm[w][lane][1] = L;
    sm[w][lane][2] = ax; sm[w][lane][3] = ay;
    sm[w][lane][4] = az; sm[w][lane][5] = aw;
    __syncthreads();
    if (w == 0) {
        float M2 = -1e30f, L2 = 0.0f;
        float bx = 0, by = 0, bz = 0, bw = 0;
#pragma unroll
        for (int p = 0; p < 4; p++) {
            float pm = sm[p][lane][0], pl = sm[p][lane][1];
            float Mn = fmaxf(M2, pm);
            float s0 = __expf(M2 - Mn);
            float s1 = __expf(pm - Mn);
            bx = bx * s0 + sm[p][lane][2] * s1;
            by = by * s0 + sm[p][lane][3] * s1;
            bz = bz * s0 + sm[p][lane][4] * s1;
            bw = bw * s0 + sm[p][lane][5] * s1;
            L2 = L2 * s0 + pl * s1;
            M2 = Mn;
        }
        float inv = 1.0f / (L2 + 1e-16f);
        ushort4 o;
        o.x = f2bf(bx * inv); o.y = f2bf(by * inv);
        o.z = f2bf(bz * inv); o.w = f2bf(bw * inv);
        *(ushort4*)(acat + fmoff(VN, off, 512)) = o;
    }
}

// ---------------- fused attention (local + expander) -> acat FM(M x 512) --------
__global__ void attn_fused_kernel(const u16* __restrict__ qb_loc, const u16* __restrict__ kv_loc,
                                  const u16* __restrict__ qb_exp, const u16* __restrict__ kv_exp,
                                  const int* __restrict__ indptr, const int* __restrict__ srcs,
                                  const int* __restrict__ esrcs,
                                  u16* __restrict__ acat) {
    int gw = (int)((blockIdx.x * (size_t)blockDim.x + threadIdx.x) >> 6);
    int lane = threadIdx.x & 63;
    int off = ((lane >> 4) << 6) + (lane & 15) * 4;

    const u16 *qb, *kv;
    const int* sl;
    int node, beg, deg, tot, cbase;
    if (gw < NREAL) {
        node = gw; qb = qb_loc; kv = kv_loc; sl = srcs; cbase = 0;
        beg = indptr[node]; deg = indptr[node + 1] - beg; tot = deg + 1;  // +vn edge
    } else if (gw < NREAL + NNODES) {
        node = gw - NREAL;
        qb = qb_exp; kv = kv_exp; sl = esrcs; cbase = 256;
        beg = node * 4; deg = 4; tot = 4;
    } else {
        return;
    }

    float4 qv = ld4bf(qb + (size_t)node * 256 + off);
    float m = -1e30f, l = 0.0f;
    float ax = 0, ay = 0, az = 0, aw = 0;

    if (tot <= 4) {
        ushort4 kraw[4], vraw[4];
#pragma unroll
        for (int j = 0; j < 4; j++) {
            int s = (j < deg) ? sl[beg + j] : VN;
            const u16* p = kv + (size_t)s * 512 + off;
            kraw[j] = *(const ushort4*)p;
            vraw[j] = *(const ushort4*)(p + 256);
        }
        float sc[4];
#pragma unroll
        for (int j = 0; j < 4; j++) {
            float4 k4 = cvt4(kraw[j]);
            float p = qv.x * k4.x + qv.y * k4.y + qv.z * k4.z + qv.w * k4.w;
            p += __shfl_xor(p, 1); p += __shfl_xor(p, 2);
            p += __shfl_xor(p, 4); p += __shfl_xor(p, 8);
            sc[j] = (j < tot) ? p * 0.125f : -1e30f;
        }
        float mn = fmaxf(fmaxf(sc[0], sc[1]), fmaxf(sc[2], sc[3]));
#pragma unroll
        for (int j = 0; j < 4; j++) {
            float ee = __expf(sc[j] - mn);
            float4 v4 = cvt4(vraw[j]);
            ax += v4.x * ee; ay += v4.y * ee; az += v4.z * ee; aw += v4.w * ee;
            l += ee;
        }
        m = mn;
    } else {
        for (int e0 = 0; e0 < tot; e0 += 8) {
            ushort4 kraw[8], vraw[8];
#pragma unroll
            for (int j = 0; j < 8; j++) {
                int e = e0 + j;
                int s = (e < deg) ? sl[beg + e] : VN;
                const u16* p = kv + (size_t)s * 512 + off;
                kraw[j] = *(const ushort4*)p;
                vraw[j] = *(const ushort4*)(p + 256);
            }
            float sc[8];
#pragma unroll
            for (int j = 0; j < 8; j++) {
                float4 k4 = cvt4(kraw[j]);
                float p = qv.x * k4.x + qv.y * k4.y + qv.z * k4.z + qv.w * k4.w;
                p += __shfl_xor(p, 1); p += __shfl_xor(p, 2);
                p += __shfl_xor(p, 4); p += __shfl_xor(p, 8);
                sc[j] = (e0 + j < tot) ? p * 0.125f : -1e30f;
            }
            float cmax = fmaxf(fmaxf(fmaxf(sc[0], sc[1]), fmaxf(sc[2], sc[3])),
                               fmaxf(fmaxf(sc[4], sc[5]), fmaxf(sc[6], sc[7])));
            float mn = fmaxf(m, cmax);
            float fold = __expf(m - mn);
            ax *= fold; ay *= fold; az *= fold; aw *= fold; l *= fold;
#pragma unroll
            for (int j = 0; j < 8; j++) {
                float ee = __expf(sc[j] - mn);
                float4 v4 = cvt4(vraw[j]);
                ax += v4.x * ee; ay += v4.y * ee; az += v4.z * ee; aw += v4.w * ee;
                l += ee;
            }
            m = mn;
        }
    }
    float inv = 1.0f / (l + 1e-16f);
    ushort4 o;
    o.x = f2bf(ax * inv); o.y = f2bf(ay * inv);
    o.z = f2bf(az * inv); o.w = f2bf(aw * inv);
    *(ushort4*)(acat + fmoff(node, cbase + off, 512)) = o;
}

// ---------------- layernorm (fused residual + attn-sum), FM bf16 out ----------------
__global__ void ln_kernel(const float* hin, const float* __restrict__ asum,
                          const float* __restrict__ g, const float* __restrict__ b,
                          float* hout, u16* __restrict__ hb) {
    int row = blockIdx.x * 4 + (threadIdx.x >> 6);
    if (row >= NNODES) return;
    int lane = threadIdx.x & 63;
    size_t base = (size_t)row * 256 + lane * 4;
    float4 xv = *(const float4*)(hin + base);
    float4 av = *(const float4*)(asum + base);
    xv.x += av.x; xv.y += av.y; xv.z += av.z; xv.w += av.w;
    float s = xv.x + xv.y + xv.z + xv.w;
#pragma unroll
    for (int o = 1; o < 64; o <<= 1) s += __shfl_xor(s, o);
    float mu = s * (1.0f / 256.0f);
    float dx = xv.x - mu, dy = xv.y - mu, dz = xv.z - mu, dw = xv.w - mu;
    float ss = dx * dx + dy * dy + dz * dz + dw * dw;
#pragma unroll
    for (int o = 1; o < 64; o <<= 1) ss += __shfl_xor(ss, o);
    float var = ss * (1.0f / 256.0f);
    float inv = 1.0f / sqrtf(var + 1e-5f);
    float4 gv = *(const float4*)(g + lane * 4);
    float4 bv = *(const float4*)(b + lane * 4);
    float4 y;
    y.x = dx * inv * gv.x + bv.x;
    y.y = dy * inv * gv.y + bv.y;
    y.z = dz * inv * gv.z + bv.z;
    y.w = dw * inv * gv.w + bv.w;
    *(float4*)(hout + base) = y;
    ushort4 o4;
    o4.x = f2bf(y.x); o4.y = f2bf(y.y); o4.z = f2bf(y.z); o4.w = f2bf(y.w);
    *(ushort4*)(hb + fmoff(row, lane * 4, 256)) = o4;
}

// ---------------- host ----------------

extern "C" void kernel_launch(void* const* d_in, const int* in_sizes, int n_in,
                              void* d_out, int out_size, void* d_ws, size_t ws_size,
                              hipStream_t stream) {
    (void)in_sizes; (void)n_in; (void)out_size; (void)ws_size;
    const float* x        = (const float*)d_in[0];
    const int*   ei       = (const int*)d_in[1];
    const int*   eei      = (const int*)d_in[2];
    const float* Wqkv_loc = (const float*)d_in[3];
    const float* bqkv_loc = (const float*)d_in[4];
    const float* Wo_loc   = (const float*)d_in[5];
    const float* bo_loc   = (const float*)d_in[6];
    const float* Wqkv_exp = (const float*)d_in[7];
    const float* bqkv_exp = (const float*)d_in[8];
    const float* Wo_exp   = (const float*)d_in[9];
    const float* bo_exp   = (const float*)d_in[10];
    const float* ln_g     = (const float*)d_in[11];
    const float* ln_b     = (const float*)d_in[12];
    const float* W1       = (const float*)d_in[13];
    const float* b1       = (const float*)d_in[14];
    const float* W2       = (const float*)d_in[15];
    const float* b2       = (const float*)d_in[16];

    char* wsp = (char*)d_ws;
    size_t off = 0;
    auto carve = [&](size_t bytes) -> void* {
        void* p = wsp + off;
        off += (bytes + 255) & ~(size_t)255;
        return p;
    };
    float* h_f    = (float*)carve((size_t)NNODES * 256 * 4);
    u16*   h_b    = (u16*)carve((size_t)MPAD * 256 * 2);      // FM
    u16*   qb_loc = (u16*)carve((size_t)NNODES * 256 * 2);    // dense q, 512B/row
    u16*   kv_loc = (u16*)carve((size_t)NNODES * 512 * 2);    // dense k|v, 1KB/row
    u16*   qb_exp = (u16*)carve((size_t)NNODES * 256 * 2);
    u16*   kv_exp = (u16*)carve((size_t)NNODES * 512 * 2);
    u16*   acat   = (u16*)carve((size_t)MPAD * 512 * 2);      // FM(M x 512): loc|exp attn out
    float* asum   = (float*)carve((size_t)NNODES * 256 * 4);  // aloc+aexp (f32)
    u16*   wbf    = (u16*)carve((size_t)3 * 1048576 * 2);     // FM weights
    float* bcat   = (float*)carve((size_t)3 * 1536 * 4);
    float* bsum   = (float*)carve((size_t)3 * 256 * 4);
    int*   cnt    = (int*)carve((size_t)NREAL * 4);
    int*   indptr = (int*)carve((size_t)(NREAL + 1) * 4);
    int*   fill   = (int*)carve((size_t)NREAL * 4);
    int*   srcs   = (int*)carve((size_t)E_EDGES * 4);
    int*   ecnt   = (int*)carve((size_t)NNODES * 4);
    int*   esrcs  = (int*)carve((size_t)NNODES * 4 * 4);
    float* part   = (float*)carve((size_t)NVNW * 264 * 4);
    u16*   mid    = qb_loc;  // FM(MPAD x 1024) = 41.2 MB aliases qb_loc..kv_exp

    hinit_kernel<<<(NNODES * 64 + 255) / 256, 256, 0, stream>>>(x, h_f, h_b);
    init_kernel<<<(NNODES + 255) / 256, 256, 0, stream>>>(
        cnt, fill, ecnt, bqkv_loc, bqkv_exp, bcat, bo_loc, bo_exp, bsum);
    csr_count_kernel<<<(E_EDGES + 255) / 256, 256, 0, stream>>>(ei, cnt);
    csr_scan_kernel<<<1, 256, 0, stream>>>(cnt, indptr);
    csr_scatter_kernel<<<(E_EDGES + 255) / 256, 256, 0, stream>>>(ei, indptr, fill, srcs);
    exp_scatter_kernel<<<(NEXP + 255) / 256, 256, 0, stream>>>(eei, ecnt, esrcs);
    wconv_all_kernel<<<(3 * 1048576 + 255) / 256, 256, 0, stream>>>(
        Wqkv_loc, Wqkv_exp, Wo_loc, Wo_exp, W1, W2, wbf);

    const int NBM64 = 320;   // ceil(20001/64) padded to x8

    for (int l = 0; l < 3; l++) {
        const u16* wqkvC = wbf + (size_t)l * 1048576 + 0;
        const u16* wocat = wbf + (size_t)l * 1048576 + 393216;
        const u16* w1T   = wbf + (size_t)l * 1048576 + 524288;
        const u16* w2T   = wbf + (size_t)l * 1048576 + 786432;

        // fused qkv GEMM (loc|exp), B-stationary, split-store q / k|v
        gemm_bn<6><<<480, 256, 0, stream>>>(
            h_b, wqkvC, bcat + l * 1536, nullptr,
            qb_loc, kv_loc, qb_exp, kv_exp, NNODES, 1536, 12);

        // vn dense attention: single-pass online partials + parallel merge
        vn_online_kernel<<<NVNW / 4, 256, 0, stream>>>(qb_loc, kv_loc, part);
        vn_merge_kernel<<<1, 256, 0, stream>>>(part, acat);

        // fused local + expander edge attention -> acat
        attn_fused_kernel<<<10001, 256, 0, stream>>>(
            qb_loc, kv_loc, qb_exp, kv_exp, indptr, srcs, esrcs, acat);

        // Wo-cat GEMM: asum = acat(K=512) @ [WoL;WoE] + (bo_loc+bo_exp)
        gemm_fm<1, 512, 64><<<NBM64 * 2, 256, 0, stream>>>(
            acat, wocat, bsum + l * 256, nullptr, asum, nullptr, NNODES, 256, 2);

        // layernorm(res + asum) -> h_f natural + h_b FM
        ln_kernel<<<(NNODES + 3) / 4, 256, 0, stream>>>(
            h_f, asum, ln_g + l * 256, ln_b + l * 256, h_f, h_b);

        // FFN: mid = gelu(h@W1+b1), B-stationary; h += mid@W2+b2
        gemm_bn<2><<<320, 256, 0, stream>>>(
            h_b, w1T, b1 + l * 1024, mid,
            nullptr, nullptr, nullptr, nullptr, NNODES, 1024, 8);
        if (l < 2) {
            gemm_fm<3, 1024, 64><<<NBM64 * 2, 256, 0, stream>>>(
                mid, w2T, b2 + l * 256, h_b, h_f, h_f, NNODES, 256, 2);
        } else {
            gemm_fm<4, 1024, 64><<<NBM64 * 2, 256, 0, stream>>>(
                mid, w2T, b2 + l * 256, nullptr, (float*)d_out, h_f, NNODES, 256, 2);
        }
    }
}